// Round 2
// baseline (2336.997 us; speedup 1.0000x reference)
//
#include <hip/hip_runtime.h>
#include <cstdint>
#include <cstddef>

// ---------------- problem constants ----------------
constexpr int B_  = 2;
constexpr int L_  = 2048;
constexpr int DM  = 2048;
constexpr int DI  = 4096;
constexpr int DXB = 1024;
constexpr int SN  = 16;     // state dim N
constexpr int DTR = 128;
constexpr int H_  = DI / SN;        // 256 heads
constexpr int NZ  = 2*DXB + 2*DI;   // 10240 (zxbc width)
constexpr int MT  = B_ * L_;        // 4096 rows

typedef __attribute__((ext_vector_type(4))) float f32x4;
typedef __attribute__((ext_vector_type(8))) short s16x8;

__device__ __forceinline__ unsigned short f2bf(float f) {
  union { float f; unsigned u; } v; v.f = f;
  unsigned r = v.u + 0x7fff + ((v.u >> 16) & 1);   // RNE
  return (unsigned short)(r >> 16);
}
__device__ __forceinline__ float bf2f(unsigned short u) {
  union { unsigned u; float f; } v; v.u = ((unsigned)u) << 16; return v.f;
}

// ---------------- bf16 NT GEMM: C[m,n] = sum_k A[m,k] * W[n,k] ----------------
// AT/WT = float (converted to bf16 during staging) or unsigned short (bf16 bits).
// 128x128 tile, BK=32, 4 waves (2x2), each wave 64x64 via 4x4 16x16x32 MFMA frags.
// Reg-staged LDS (no global_load_lds this round). M,N mult of 128; K mult of 32.
template<typename AT, typename WT, bool BF16OUT>
__global__ __launch_bounds__(256) void gemm_nt(const AT* __restrict__ A,
                                               const WT* __restrict__ W,
                                               void* __restrict__ Cout,
                                               int M, int N, int K) {
  __shared__ alignas(16) unsigned short sA[128 * 32];
  __shared__ alignas(16) unsigned short sB[128 * 32];
  const int tid  = threadIdx.x;
  const int lane = tid & 63;
  const int wave = tid >> 6;
  const int m0 = blockIdx.y * 128, n0 = blockIdx.x * 128;
  const int wr = wave >> 1, wc = wave & 1;
  const int r16 = lane & 15, g = lane >> 4;
  f32x4 acc[4][4] = {};

  for (int k0 = 0; k0 < K; k0 += 32) {
    __syncthreads();   // previous iteration's LDS reads complete
    // ---- stage A tile (128 rows x 32 cols bf16) ----
    if constexpr (sizeof(AT) == 4) {
#pragma unroll
      for (int s = 0; s < 4; ++s) {
        const int slot = tid + s * 256;            // 1024 float4-slots
        const int row = slot >> 3, c4 = slot & 7;
        const float4 v = *(const float4*)((const float*)A + (size_t)(m0 + row) * K + k0 + c4 * 4);
        ushort4 o; o.x = f2bf(v.x); o.y = f2bf(v.y); o.z = f2bf(v.z); o.w = f2bf(v.w);
        *(ushort4*)&sA[row * 32 + c4 * 4] = o;
      }
    } else {
#pragma unroll
      for (int s = 0; s < 2; ++s) {
        const int slot = tid + s * 256;            // 512 ushort8-slots
        const int row = slot >> 2, c8 = slot & 3;
        *(s16x8*)&sA[row * 32 + c8 * 8] =
            *(const s16x8*)((const unsigned short*)A + (size_t)(m0 + row) * K + k0 + c8 * 8);
      }
    }
    // ---- stage W tile ----
    if constexpr (sizeof(WT) == 4) {
#pragma unroll
      for (int s = 0; s < 4; ++s) {
        const int slot = tid + s * 256;
        const int row = slot >> 3, c4 = slot & 7;
        const float4 v = *(const float4*)((const float*)W + (size_t)(n0 + row) * K + k0 + c4 * 4);
        ushort4 o; o.x = f2bf(v.x); o.y = f2bf(v.y); o.z = f2bf(v.z); o.w = f2bf(v.w);
        *(ushort4*)&sB[row * 32 + c4 * 4] = o;
      }
    } else {
#pragma unroll
      for (int s = 0; s < 2; ++s) {
        const int slot = tid + s * 256;
        const int row = slot >> 2, c8 = slot & 3;
        *(s16x8*)&sB[row * 32 + c8 * 8] =
            *(const s16x8*)((const unsigned short*)W + (size_t)(n0 + row) * K + k0 + c8 * 8);
      }
    }
    __syncthreads();

    s16x8 af[4], bfr[4];
#pragma unroll
    for (int f = 0; f < 4; ++f) {
      af[f]  = *(const s16x8*)&sA[(wr * 64 + f * 16 + r16) * 32 + g * 8];
      bfr[f] = *(const s16x8*)&sB[(wc * 64 + f * 16 + r16) * 32 + g * 8];
    }
#pragma unroll
    for (int i = 0; i < 4; ++i)
#pragma unroll
      for (int j = 0; j < 4; ++j)
        acc[i][j] = __builtin_amdgcn_mfma_f32_16x16x32_bf16(af[i], bfr[j], acc[i][j], 0, 0, 0);
  }

  // C/D layout: col = lane&15, row = (lane>>4)*4 + e   [m89-verified]
#pragma unroll
  for (int i = 0; i < 4; ++i)
#pragma unroll
    for (int j = 0; j < 4; ++j) {
      const int row0 = m0 + wr * 64 + i * 16 + g * 4;
      const int col  = n0 + wc * 64 + j * 16 + r16;
#pragma unroll
      for (int e = 0; e < 4; ++e) {
        float v = acc[i][j][e];
        if constexpr (BF16OUT) ((unsigned short*)Cout)[(size_t)(row0 + e) * N + col] = f2bf(v);
        else                   ((float*)Cout)[(size_t)(row0 + e) * N + col] = v;
      }
    }
}

// ---------------- fused conv1d+SiLU + selective scan + gated epilogue ----------------
// block = (b,h); thread = (p = tid>>4, n = tid&15). Scalar recurrence over t.
// Conv is recomputed per-lane from the raw x columns of zxbc (4-tap rolling window).
__global__ __launch_bounds__(256) void scan_kernel(const unsigned short* __restrict__ zxbc,
                                                   const unsigned short* __restrict__ dtw,
                                                   const float* __restrict__ dt_b,
                                                   const float* __restrict__ conv_w,
                                                   const float* __restrict__ conv_b,
                                                   const float* __restrict__ A_log,
                                                   const float* __restrict__ Dv,
                                                   unsigned short* __restrict__ yf) {
  const int bh = blockIdx.x;           // 0..511
  const int b = bh >> 8, h = bh & (H_ - 1);
  const int tid = threadIdx.x;
  const int p = tid >> 4, n = tid & 15;
  const int d = h * 16 + p;

  const float bias  = dt_b[d];
  const float acoef = -expf(A_log[d * SN + n]);   // = -(n+1)
  const float Dd    = Dv[d];
  const float cw0 = conv_w[d * 4 + 0], cw1 = conv_w[d * 4 + 1];
  const float cw2 = conv_w[d * 4 + 2], cw3 = conv_w[d * 4 + 3];
  const float cb  = conv_b[d];

  const unsigned short* rp = zxbc + (size_t)b * L_ * NZ;
  const int oz = d;                                  // z column
  const int ox = DI + ((h >> 2) << 4) + p;           // raw x column (pre-repeat)
  const int oB = DI + DXB + ((h >> 2) << 4) + n;     // B column
  const int oC = DI + 2 * DXB + h * 16 + n;          // C column
  const unsigned short* pdt = dtw + (size_t)b * L_ * DI + d;
  unsigned short* py = yf + (size_t)b * L_ * DI + d;

  float h_state = 0.f;
  float xm3 = 0.f, xm2 = 0.f, xm1 = 0.f;             // conv window (zero left-pad)
  float zv = bf2f(rp[oz]), xv = bf2f(rp[ox]);
  float Bv = bf2f(rp[oB]), Cv = bf2f(rp[oC]);
  float dr = bf2f(pdt[0]);

  for (int t = 0; t < L_; ++t) {
    const size_t tn = (size_t)((t + 1 < L_) ? t + 1 : t);   // prefetch next step
    float zn = bf2f(rp[tn * NZ + oz]), xn = bf2f(rp[tn * NZ + ox]);
    float Bn = bf2f(rp[tn * NZ + oB]), Cn = bf2f(rp[tn * NZ + oC]);
    float dn = bf2f(pdt[tn * DI]);

    float cs = cb + cw0 * xm3 + cw1 * xm2 + cw2 * xm1 + cw3 * xv;
    float xa = cs / (1.f + expf(-cs));               // silu(conv)
    float xs = dr + bias;
    float dtv = (xs > 20.f) ? xs : log1pf(expf(xs)); // softplus
    float a   = expf(dtv * acoef);
    h_state   = h_state * a + dtv * xa * Bv;
    float yp  = h_state * Cv;
    yp += __shfl_xor(yp, 1);
    yp += __shfl_xor(yp, 2);
    yp += __shfl_xor(yp, 4);
    yp += __shfl_xor(yp, 8);
    if (n == 0) {
      float sz  = zv / (1.f + expf(-zv));
      py[(size_t)t * DI] = f2bf((yp + Dd * xa) * sz);
    }
    xm3 = xm2; xm2 = xm1; xm1 = xv;
    zv = zn; xv = xn; Bv = Bn; Cv = Cn; dr = dn;
  }
}

// ---------------- launch ----------------
extern "C" void kernel_launch(void* const* d_in, const int* in_sizes, int n_in,
                              void* d_out, int out_size, void* d_ws, size_t ws_size,
                              hipStream_t stream) {
  const float* hs     = (const float*)d_in[0];
  const float* w_in   = (const float*)d_in[1];
  const float* w_dti  = (const float*)d_in[2];
  const float* w_dtp  = (const float*)d_in[3];
  const float* dt_b   = (const float*)d_in[4];
  const float* conv_w = (const float*)d_in[5];
  const float* conv_b = (const float*)d_in[6];
  const float* A_log  = (const float*)d_in[7];
  const float* Dv     = (const float*)d_in[8];
  const float* w_out  = (const float*)d_in[9];
  float* out = (float*)d_out;

  char* ws = (char*)d_ws;
  size_t off = 0;
  auto take = [&](size_t bytes) -> void* {
    void* p = ws + off;
    off += (bytes + 255) & ~(size_t)255;
    return p;
  };
  // total workspace: ~152 MB
  unsigned short* zxbc  = (unsigned short*)take((size_t)MT * NZ * 2);
  unsigned short* t1b   = (unsigned short*)take((size_t)MT * DTR * 2);
  unsigned short* dtraw = (unsigned short*)take((size_t)MT * DI * 2);
  unsigned short* yfb   = (unsigned short*)take((size_t)MT * DI * 2);

  // zxbc = hs @ in_proj_w.T   (4096 x 10240, K=2048) -> bf16
  gemm_nt<float, float, true><<<dim3(NZ / 128, MT / 128), 256, 0, stream>>>(hs, w_in, zxbc, MT, NZ, DM);
  // t1 = hs @ dt_in_proj_w.T  (4096 x 128, K=2048) -> bf16
  gemm_nt<float, float, true><<<dim3(DTR / 128, MT / 128), 256, 0, stream>>>(hs, w_dti, t1b, MT, DTR, DM);
  // dtraw = t1 @ dt_proj_w.T  (4096 x 4096, K=128) -> bf16
  gemm_nt<unsigned short, float, true><<<dim3(DI / 128, MT / 128), 256, 0, stream>>>(t1b, w_dtp, dtraw, MT, DI, DTR);
  // fused conv+silu + selective scan + epilogue -> yf (bf16)
  scan_kernel<<<dim3(B_ * H_), 256, 0, stream>>>(zxbc, dtraw, dt_b, conv_w, conv_b, A_log, Dv, yfb);
  // out = yf @ out_proj_w.T   (4096 x 2048, K=4096) -> f32
  gemm_nt<unsigned short, float, false><<<dim3(DM / 128, MT / 128), 256, 0, stream>>>(yfb, w_out, out, MT, DM, DI);
}

// Round 4
// 877.419 us; speedup vs baseline: 2.6635x; 2.6635x over previous
//
#include <hip/hip_runtime.h>
#include <cstdint>
#include <cstddef>

// ---------------- problem constants ----------------
constexpr int B_  = 2;
constexpr int L_  = 2048;
constexpr int DM  = 2048;
constexpr int DI  = 4096;
constexpr int DXB = 1024;
constexpr int SN  = 16;     // state dim N
constexpr int DTR = 128;
constexpr int H_  = DI / SN;        // 256 heads
constexpr int NZ  = 2*DXB + 2*DI;   // 10240 (zxbc width)
constexpr int MT  = B_ * L_;        // 4096 rows
constexpr int CCH = 32;             // scan chunks
constexpr int TCH = L_ / CCH;       // 64 steps per chunk

constexpr float LOG2E = 1.4426950408889634f;
constexpr float LN2   = 0.6931471805599453f;

typedef __attribute__((ext_vector_type(4))) float f32x4;
typedef __attribute__((ext_vector_type(8))) short s16x8;

__device__ __forceinline__ unsigned short f2bf(float f) {
  union { float f; unsigned u; } v; v.f = f;
  unsigned r = v.u + 0x7fff + ((v.u >> 16) & 1);   // RNE
  return (unsigned short)(r >> 16);
}
__device__ __forceinline__ float bf2f(unsigned short u) {
  union { unsigned u; float f; } v; v.u = ((unsigned)u) << 16; return v.f;
}
__device__ __forceinline__ float fexp(float x)  { return __builtin_amdgcn_exp2f(x * LOG2E); }
__device__ __forceinline__ float fsilu(float x) { return x * __builtin_amdgcn_rcpf(1.f + fexp(-x)); }
__device__ __forceinline__ float fsoftplus(float x) {
  // __builtin_amdgcn_logf == v_log_f32 == log2
  return (x > 20.f) ? x : __builtin_amdgcn_logf(1.f + fexp(x)) * LN2;
}

// ---------------- bf16 NT GEMM: C[m,n] = sum_k A[m,k] * W[n,k] ----------------
// (unchanged from round 2 — reg-staged, 128x128 tile, BK=32, 4 waves 2x2)
template<typename AT, typename WT, bool BF16OUT>
__global__ __launch_bounds__(256) void gemm_nt(const AT* __restrict__ A,
                                               const WT* __restrict__ W,
                                               void* __restrict__ Cout,
                                               int M, int N, int K) {
  __shared__ alignas(16) unsigned short sA[128 * 32];
  __shared__ alignas(16) unsigned short sB[128 * 32];
  const int tid  = threadIdx.x;
  const int lane = tid & 63;
  const int wave = tid >> 6;
  const int m0 = blockIdx.y * 128, n0 = blockIdx.x * 128;
  const int wr = wave >> 1, wc = wave & 1;
  const int r16 = lane & 15, g = lane >> 4;
  f32x4 acc[4][4] = {};

  for (int k0 = 0; k0 < K; k0 += 32) {
    __syncthreads();
    if constexpr (sizeof(AT) == 4) {
#pragma unroll
      for (int s = 0; s < 4; ++s) {
        const int slot = tid + s * 256;
        const int row = slot >> 3, c4 = slot & 7;
        const float4 v = *(const float4*)((const float*)A + (size_t)(m0 + row) * K + k0 + c4 * 4);
        ushort4 o; o.x = f2bf(v.x); o.y = f2bf(v.y); o.z = f2bf(v.z); o.w = f2bf(v.w);
        *(ushort4*)&sA[row * 32 + c4 * 4] = o;
      }
    } else {
#pragma unroll
      for (int s = 0; s < 2; ++s) {
        const int slot = tid + s * 256;
        const int row = slot >> 2, c8 = slot & 3;
        *(s16x8*)&sA[row * 32 + c8 * 8] =
            *(const s16x8*)((const unsigned short*)A + (size_t)(m0 + row) * K + k0 + c8 * 8);
      }
    }
    if constexpr (sizeof(WT) == 4) {
#pragma unroll
      for (int s = 0; s < 4; ++s) {
        const int slot = tid + s * 256;
        const int row = slot >> 3, c4 = slot & 7;
        const float4 v = *(const float4*)((const float*)W + (size_t)(n0 + row) * K + k0 + c4 * 4);
        ushort4 o; o.x = f2bf(v.x); o.y = f2bf(v.y); o.z = f2bf(v.z); o.w = f2bf(v.w);
        *(ushort4*)&sB[row * 32 + c4 * 4] = o;
      }
    } else {
#pragma unroll
      for (int s = 0; s < 2; ++s) {
        const int slot = tid + s * 256;
        const int row = slot >> 2, c8 = slot & 3;
        *(s16x8*)&sB[row * 32 + c8 * 8] =
            *(const s16x8*)((const unsigned short*)W + (size_t)(n0 + row) * K + k0 + c8 * 8);
      }
    }
    __syncthreads();

    s16x8 af[4], bfr[4];
#pragma unroll
    for (int f = 0; f < 4; ++f) {
      af[f]  = *(const s16x8*)&sA[(wr * 64 + f * 16 + r16) * 32 + g * 8];
      bfr[f] = *(const s16x8*)&sB[(wc * 64 + f * 16 + r16) * 32 + g * 8];
    }
#pragma unroll
    for (int i = 0; i < 4; ++i)
#pragma unroll
      for (int j = 0; j < 4; ++j)
        acc[i][j] = __builtin_amdgcn_mfma_f32_16x16x32_bf16(af[i], bfr[j], acc[i][j], 0, 0, 0);
  }

#pragma unroll
  for (int i = 0; i < 4; ++i)
#pragma unroll
    for (int j = 0; j < 4; ++j) {
      const int row0 = m0 + wr * 64 + i * 16 + g * 4;
      const int col  = n0 + wc * 64 + j * 16 + r16;
#pragma unroll
      for (int e = 0; e < 4; ++e) {
        float v = acc[i][j][e];
        if constexpr (BF16OUT) ((unsigned short*)Cout)[(size_t)(row0 + e) * N + col] = f2bf(v);
        else                   ((float*)Cout)[(size_t)(row0 + e) * N + col] = v;
      }
    }
}

// ================= chunked selective scan =================
// thread = (b, d, chunk); 16 n-states in registers; conv recomputed per pass.

// ---- pass 1: per-chunk (S = sum dtv, Bacc[16]) with h_in = 0 ----
__global__ __launch_bounds__(256) void scan_p1(const unsigned short* __restrict__ zxbc,
                                               const unsigned short* __restrict__ dtw,
                                               const float* __restrict__ dt_b,
                                               const float* __restrict__ conv_w,
                                               const float* __restrict__ conv_b,
                                               const float* __restrict__ A_log,
                                               float* __restrict__ Sws,
                                               float* __restrict__ Bws) {
  const int d = blockIdx.x * 256 + threadIdx.x;  // channel
  const int c = blockIdx.y;                      // chunk
  const int b = blockIdx.z;
  const int h = d >> 4, p = d & 15;

  const float bias = dt_b[d];
  const float cw0 = conv_w[d*4+0], cw1 = conv_w[d*4+1], cw2 = conv_w[d*4+2], cw3 = conv_w[d*4+3];
  const float cb  = conv_b[d];
  float nacK[16];
#pragma unroll
  for (int n = 0; n < 16; ++n) nacK[n] = -fexp(A_log[d * SN + n]) * LOG2E;  // a = exp2(dtv*nacK)

  const unsigned short* rp  = zxbc + (size_t)b * L_ * NZ;
  const unsigned short* pdt = dtw  + (size_t)b * L_ * DI + d;
  const int ox = DI + ((h >> 2) << 4) + p;
  const int oB = DI + DXB + ((h >> 2) << 4);
  const int t0 = c * TCH;

  float xm1 = (t0 >= 1) ? bf2f(rp[(size_t)(t0-1)*NZ + ox]) : 0.f;
  float xm2 = (t0 >= 2) ? bf2f(rp[(size_t)(t0-2)*NZ + ox]) : 0.f;
  float xm3 = (t0 >= 3) ? bf2f(rp[(size_t)(t0-3)*NZ + ox]) : 0.f;

  float S = 0.f;
  float Bacc[16] = {};

  for (int t = t0; t < t0 + TCH; ++t) {
    const size_t row = (size_t)t * NZ;
    const float xv = bf2f(rp[row + ox]);
    const s16x8 bv0 = *(const s16x8*)&rp[row + oB];
    const s16x8 bv1 = *(const s16x8*)&rp[row + oB + 8];
    const float dr = bf2f(pdt[(size_t)t * DI]);

    const float cs  = cb + cw0*xm3 + cw1*xm2 + cw2*xm1 + cw3*xv;
    const float xa  = fsilu(cs);
    const float dtv = fsoftplus(dr + bias);
    S += dtv;
    const float g = dtv * xa;
#pragma unroll
    for (int n = 0; n < 16; ++n) {
      const float Bn = bf2f((unsigned short)(n < 8 ? bv0[n] : bv1[n-8]));
      const float a  = __builtin_amdgcn_exp2f(dtv * nacK[n]);
      Bacc[n] = Bacc[n] * a + g * Bn;
    }
    xm3 = xm2; xm2 = xm1; xm1 = xv;
  }

  Sws[((size_t)b * CCH + c) * DI + d] = S;
  float* Bo = Bws + (((size_t)b * CCH + c) * DI + d) * 16;
#pragma unroll
  for (int q = 0; q < 4; ++q)
    *(float4*)&Bo[q*4] = make_float4(Bacc[q*4], Bacc[q*4+1], Bacc[q*4+2], Bacc[q*4+3]);
}

// ---- combine: sequential over 32 chunks, parallel over (b,d,n) ----
__global__ __launch_bounds__(256) void scan_comb(const float* __restrict__ Sws,
                                                 const float* __restrict__ Bws,
                                                 const float* __restrict__ A_log,
                                                 float* __restrict__ Hin) {
  const int idx = blockIdx.x * 256 + threadIdx.x;  // d*16+n
  const int b = blockIdx.y;
  const int d = idx >> 4;
  const float nacK = -fexp(A_log[idx]) * LOG2E;
  float hcur = 0.f;
  for (int c = 0; c < CCH; ++c) {
    const size_t cell = ((size_t)b * CCH + c) * DI;
    Hin[(cell + d) * 16 + (idx & 15)] = hcur;
    const float S  = Sws[cell + d];
    const float Ba = Bws[(cell + d) * 16 + (idx & 15)];
    hcur = hcur * __builtin_amdgcn_exp2f(S * nacK) + Ba;
  }
}

// ---- pass 2: rerun local scan from Hin, emit gated y (bf16) ----
__global__ __launch_bounds__(256) void scan_p2(const unsigned short* __restrict__ zxbc,
                                               const unsigned short* __restrict__ dtw,
                                               const float* __restrict__ dt_b,
                                               const float* __restrict__ conv_w,
                                               const float* __restrict__ conv_b,
                                               const float* __restrict__ A_log,
                                               const float* __restrict__ Dv,
                                               const float* __restrict__ Hin,
                                               unsigned short* __restrict__ yf) {
  const int d = blockIdx.x * 256 + threadIdx.x;
  const int c = blockIdx.y;
  const int b = blockIdx.z;
  const int h = d >> 4, p = d & 15;

  const float bias = dt_b[d];
  const float Dd   = Dv[d];
  const float cw0 = conv_w[d*4+0], cw1 = conv_w[d*4+1], cw2 = conv_w[d*4+2], cw3 = conv_w[d*4+3];
  const float cb  = conv_b[d];
  float nacK[16];
#pragma unroll
  for (int n = 0; n < 16; ++n) nacK[n] = -fexp(A_log[d * SN + n]) * LOG2E;

  float hst[16];
  const float* Hi = Hin + (((size_t)b * CCH + c) * DI + d) * 16;
#pragma unroll
  for (int q = 0; q < 4; ++q) {
    const float4 v = *(const float4*)&Hi[q*4];
    hst[q*4] = v.x; hst[q*4+1] = v.y; hst[q*4+2] = v.z; hst[q*4+3] = v.w;
  }

  const unsigned short* rp  = zxbc + (size_t)b * L_ * NZ;
  const unsigned short* pdt = dtw  + (size_t)b * L_ * DI + d;
  unsigned short* py = yf + (size_t)b * L_ * DI + d;
  const int oz = d;
  const int ox = DI + ((h >> 2) << 4) + p;
  const int oB = DI + DXB + ((h >> 2) << 4);
  const int oC = DI + 2*DXB + (h << 4);
  const int t0 = c * TCH;

  float xm1 = (t0 >= 1) ? bf2f(rp[(size_t)(t0-1)*NZ + ox]) : 0.f;
  float xm2 = (t0 >= 2) ? bf2f(rp[(size_t)(t0-2)*NZ + ox]) : 0.f;
  float xm3 = (t0 >= 3) ? bf2f(rp[(size_t)(t0-3)*NZ + ox]) : 0.f;

  for (int t = t0; t < t0 + TCH; ++t) {
    const size_t row = (size_t)t * NZ;
    const float xv = bf2f(rp[row + ox]);
    const float zv = bf2f(rp[row + oz]);
    const s16x8 bv0 = *(const s16x8*)&rp[row + oB];
    const s16x8 bv1 = *(const s16x8*)&rp[row + oB + 8];
    const s16x8 cv0 = *(const s16x8*)&rp[row + oC];
    const s16x8 cv1 = *(const s16x8*)&rp[row + oC + 8];
    const float dr = bf2f(pdt[(size_t)t * DI]);

    const float cs  = cb + cw0*xm3 + cw1*xm2 + cw2*xm1 + cw3*xv;
    const float xa  = fsilu(cs);
    const float dtv = fsoftplus(dr + bias);
    const float g = dtv * xa;
    float y = 0.f;
#pragma unroll
    for (int n = 0; n < 16; ++n) {
      const float Bn = bf2f((unsigned short)(n < 8 ? bv0[n] : bv1[n-8]));
      const float Cn = bf2f((unsigned short)(n < 8 ? cv0[n] : cv1[n-8]));
      const float a  = __builtin_amdgcn_exp2f(dtv * nacK[n]);
      hst[n] = hst[n] * a + g * Bn;
      y += hst[n] * Cn;
    }
    py[(size_t)t * DI] = f2bf((y + Dd * xa) * fsilu(zv));
    xm3 = xm2; xm2 = xm1; xm1 = xv;
  }
}

// ---------------- launch ----------------
extern "C" void kernel_launch(void* const* d_in, const int* in_sizes, int n_in,
                              void* d_out, int out_size, void* d_ws, size_t ws_size,
                              hipStream_t stream) {
  const float* hs     = (const float*)d_in[0];
  const float* w_in   = (const float*)d_in[1];
  const float* w_dti  = (const float*)d_in[2];
  const float* w_dtp  = (const float*)d_in[3];
  const float* dt_b   = (const float*)d_in[4];
  const float* conv_w = (const float*)d_in[5];
  const float* conv_b = (const float*)d_in[6];
  const float* A_log  = (const float*)d_in[7];
  const float* Dv     = (const float*)d_in[8];
  const float* w_out  = (const float*)d_in[9];
  float* out = (float*)d_out;

  char* ws = (char*)d_ws;
  size_t off = 0;
  auto take = [&](size_t bytes) -> void* {
    void* p = ws + off;
    off += (bytes + 255) & ~(size_t)255;
    return p;
  };
  // total workspace ~187 MB
  unsigned short* zxbc  = (unsigned short*)take((size_t)MT * NZ * 2);
  unsigned short* t1b   = (unsigned short*)take((size_t)MT * DTR * 2);
  unsigned short* dtraw = (unsigned short*)take((size_t)MT * DI * 2);
  unsigned short* yfb   = (unsigned short*)take((size_t)MT * DI * 2);
  float*          Sws   = (float*)take((size_t)B_ * CCH * DI * 4);
  float*          Bws   = (float*)take((size_t)B_ * CCH * DI * 16 * 4);
  float*          Hin   = (float*)take((size_t)B_ * CCH * DI * 16 * 4);

  // zxbc = hs @ in_proj_w.T   (4096 x 10240, K=2048) -> bf16
  gemm_nt<float, float, true><<<dim3(NZ / 128, MT / 128), 256, 0, stream>>>(hs, w_in, zxbc, MT, NZ, DM);
  // t1 = hs @ dt_in_proj_w.T  (4096 x 128, K=2048) -> bf16
  gemm_nt<float, float, true><<<dim3(DTR / 128, MT / 128), 256, 0, stream>>>(hs, w_dti, t1b, MT, DTR, DM);
  // dtraw = t1 @ dt_proj_w.T  (4096 x 4096, K=128) -> bf16
  gemm_nt<unsigned short, float, true><<<dim3(DI / 128, MT / 128), 256, 0, stream>>>(t1b, w_dtp, dtraw, MT, DI, DTR);

  // chunked selective scan (conv fused, recomputed in both passes)
  scan_p1  <<<dim3(DI/256, CCH, B_), 256, 0, stream>>>(zxbc, dtraw, dt_b, conv_w, conv_b, A_log, Sws, Bws);
  scan_comb<<<dim3(DI*SN/256, B_),  256, 0, stream>>>(Sws, Bws, A_log, Hin);
  scan_p2  <<<dim3(DI/256, CCH, B_), 256, 0, stream>>>(zxbc, dtraw, dt_b, conv_w, conv_b, A_log, Dv, Hin, yfb);

  // out = yf @ out_proj_w.T   (4096 x 2048, K=4096) -> f32
  gemm_nt<unsigned short, float, false><<<dim3(DM / 128, MT / 128), 256, 0, stream>>>(yfb, w_out, out, MT, DM, DI);
}

// Round 5
// 642.751 us; speedup vs baseline: 3.6359x; 1.3651x over previous
//
#include <hip/hip_runtime.h>
#include <cstdint>
#include <cstddef>

// ---------------- problem constants ----------------
constexpr int B_  = 2;
constexpr int L_  = 2048;
constexpr int DM  = 2048;
constexpr int DI  = 4096;
constexpr int DXB = 1024;
constexpr int SN  = 16;     // state dim N
constexpr int DTR = 128;
constexpr int H_  = DI / SN;        // 256 heads
constexpr int NZ  = 2*DXB + 2*DI;   // 10240 (zxbc width)
constexpr int MT  = B_ * L_;        // 4096 rows
constexpr int CCH = 32;             // scan chunks
constexpr int TCH = L_ / CCH;       // 64 steps per chunk

constexpr float LOG2E = 1.4426950408889634f;
constexpr float LN2   = 0.6931471805599453f;

typedef __attribute__((ext_vector_type(4))) float f32x4;
typedef __attribute__((ext_vector_type(8))) short s16x8;

__device__ __forceinline__ unsigned short f2bf(float f) {
  union { float f; unsigned u; } v; v.f = f;
  unsigned r = v.u + 0x7fff + ((v.u >> 16) & 1);   // RNE
  return (unsigned short)(r >> 16);
}
__device__ __forceinline__ float bf2f(unsigned short u) {
  union { unsigned u; float f; } v; v.u = ((unsigned)u) << 16; return v.f;
}
__device__ __forceinline__ float fexp(float x)  { return __builtin_amdgcn_exp2f(x * LOG2E); }
__device__ __forceinline__ float fsilu(float x) { return x * __builtin_amdgcn_rcpf(1.f + fexp(-x)); }
__device__ __forceinline__ float fsoftplus(float x) {
  // __builtin_amdgcn_logf == v_log_f32 == log2
  return (x > 20.f) ? x : __builtin_amdgcn_logf(1.f + fexp(x)) * LN2;
}

// ---------------- f32 -> bf16 cast ----------------
__global__ __launch_bounds__(256) void cast_kernel(const float4* __restrict__ in,
                                                   ushort4* __restrict__ out, int n4) {
  int stride = gridDim.x * blockDim.x;
  for (int i = blockIdx.x * blockDim.x + threadIdx.x; i < n4; i += stride) {
    float4 v = in[i];
    ushort4 o;
    o.x = f2bf(v.x); o.y = f2bf(v.y); o.z = f2bf(v.z); o.w = f2bf(v.w);
    out[i] = o;
  }
}

// ---------------- bf16 NT GEMM, global_load_lds staging (m97 structure) ----------------
// C[m,n] = sum_k A[m,k]*W[n,k]; A:(M,K) W:(N,K) bf16 bits; 128x128 tile, BK=32.
template<bool BF16OUT>
__global__ __launch_bounds__(256) void gemm_g16(const unsigned short* __restrict__ A,
                                                const unsigned short* __restrict__ W,
                                                void* __restrict__ Cout,
                                                int M, int N, int K) {
  __shared__ alignas(16) unsigned short sA[128 * 32];
  __shared__ alignas(16) unsigned short sB[128 * 32];
  const int tid  = threadIdx.x;
  const int lane = tid & 63;
  const int wave = tid >> 6;
  const int m0 = blockIdx.y * 128, n0 = blockIdx.x * 128;
  const int wr = wave >> 1, wc = wave & 1;
  const int r16 = lane & 15, g = lane >> 4;
  f32x4 acc[4][4] = {};

  for (int k0 = 0; k0 < K; k0 += 32) {
    __syncthreads();   // previous iteration's LDS reads complete
#pragma unroll
    for (int it = 0; it < 2; ++it) {
      const int base = wave * 128 + it * 64;     // wave-uniform 16B-slot base
      const int slot = base + lane;
      const int r = slot >> 2, c8 = slot & 3;
      const unsigned short* ga = A + (size_t)(m0 + r) * K + k0 + c8 * 8;
      const unsigned short* gb = W + (size_t)(n0 + r) * K + k0 + c8 * 8;
      __builtin_amdgcn_global_load_lds((const __attribute__((address_space(1))) void*)ga,
                                       (__attribute__((address_space(3))) void*)(sA + base * 8), 16, 0, 0);
      __builtin_amdgcn_global_load_lds((const __attribute__((address_space(1))) void*)gb,
                                       (__attribute__((address_space(3))) void*)(sB + base * 8), 16, 0, 0);
    }
    __syncthreads();   // compiler drains vmcnt before barrier: staged data visible

    s16x8 af[4], bfr[4];
#pragma unroll
    for (int f = 0; f < 4; ++f) {
      af[f]  = *(const s16x8*)&sA[(wr * 64 + f * 16 + r16) * 32 + g * 8];
      bfr[f] = *(const s16x8*)&sB[(wc * 64 + f * 16 + r16) * 32 + g * 8];
    }
#pragma unroll
    for (int i = 0; i < 4; ++i)
#pragma unroll
      for (int j = 0; j < 4; ++j)
        acc[i][j] = __builtin_amdgcn_mfma_f32_16x16x32_bf16(af[i], bfr[j], acc[i][j], 0, 0, 0);
  }

#pragma unroll
  for (int i = 0; i < 4; ++i)
#pragma unroll
    for (int j = 0; j < 4; ++j) {
      const int row0 = m0 + wr * 64 + i * 16 + g * 4;
      const int col  = n0 + wc * 64 + j * 16 + r16;
#pragma unroll
      for (int e = 0; e < 4; ++e) {
        float v = acc[i][j][e];
        if constexpr (BF16OUT) ((unsigned short*)Cout)[(size_t)(row0 + e) * N + col] = f2bf(v);
        else                   ((float*)Cout)[(size_t)(row0 + e) * N + col] = v;
      }
    }
}

// ---------------- fallback GEMM (reg-staged, f32-or-bf16 inputs) — round-4 proven ----------------
template<typename AT, typename WT, bool BF16OUT>
__global__ __launch_bounds__(256) void gemm_nt(const AT* __restrict__ A,
                                               const WT* __restrict__ W,
                                               void* __restrict__ Cout,
                                               int M, int N, int K) {
  __shared__ alignas(16) unsigned short sA[128 * 32];
  __shared__ alignas(16) unsigned short sB[128 * 32];
  const int tid  = threadIdx.x;
  const int lane = tid & 63;
  const int wave = tid >> 6;
  const int m0 = blockIdx.y * 128, n0 = blockIdx.x * 128;
  const int wr = wave >> 1, wc = wave & 1;
  const int r16 = lane & 15, g = lane >> 4;
  f32x4 acc[4][4] = {};

  for (int k0 = 0; k0 < K; k0 += 32) {
    __syncthreads();
    if constexpr (sizeof(AT) == 4) {
#pragma unroll
      for (int s = 0; s < 4; ++s) {
        const int slot = tid + s * 256;
        const int row = slot >> 3, c4 = slot & 7;
        const float4 v = *(const float4*)((const float*)A + (size_t)(m0 + row) * K + k0 + c4 * 4);
        ushort4 o; o.x = f2bf(v.x); o.y = f2bf(v.y); o.z = f2bf(v.z); o.w = f2bf(v.w);
        *(ushort4*)&sA[row * 32 + c4 * 4] = o;
      }
    } else {
#pragma unroll
      for (int s = 0; s < 2; ++s) {
        const int slot = tid + s * 256;
        const int row = slot >> 2, c8 = slot & 3;
        *(s16x8*)&sA[row * 32 + c8 * 8] =
            *(const s16x8*)((const unsigned short*)A + (size_t)(m0 + row) * K + k0 + c8 * 8);
      }
    }
    if constexpr (sizeof(WT) == 4) {
#pragma unroll
      for (int s = 0; s < 4; ++s) {
        const int slot = tid + s * 256;
        const int row = slot >> 3, c4 = slot & 7;
        const float4 v = *(const float4*)((const float*)W + (size_t)(n0 + row) * K + k0 + c4 * 4);
        ushort4 o; o.x = f2bf(v.x); o.y = f2bf(v.y); o.z = f2bf(v.z); o.w = f2bf(v.w);
        *(ushort4*)&sB[row * 32 + c4 * 4] = o;
      }
    } else {
#pragma unroll
      for (int s = 0; s < 2; ++s) {
        const int slot = tid + s * 256;
        const int row = slot >> 2, c8 = slot & 3;
        *(s16x8*)&sB[row * 32 + c8 * 8] =
            *(const s16x8*)((const unsigned short*)W + (size_t)(n0 + row) * K + k0 + c8 * 8);
      }
    }
    __syncthreads();

    s16x8 af[4], bfr[4];
#pragma unroll
    for (int f = 0; f < 4; ++f) {
      af[f]  = *(const s16x8*)&sA[(wr * 64 + f * 16 + r16) * 32 + g * 8];
      bfr[f] = *(const s16x8*)&sB[(wc * 64 + f * 16 + r16) * 32 + g * 8];
    }
#pragma unroll
    for (int i = 0; i < 4; ++i)
#pragma unroll
      for (int j = 0; j < 4; ++j)
        acc[i][j] = __builtin_amdgcn_mfma_f32_16x16x32_bf16(af[i], bfr[j], acc[i][j], 0, 0, 0);
  }

#pragma unroll
  for (int i = 0; i < 4; ++i)
#pragma unroll
    for (int j = 0; j < 4; ++j) {
      const int row0 = m0 + wr * 64 + i * 16 + g * 4;
      const int col  = n0 + wc * 64 + j * 16 + r16;
#pragma unroll
      for (int e = 0; e < 4; ++e) {
        float v = acc[i][j][e];
        if constexpr (BF16OUT) ((unsigned short*)Cout)[(size_t)(row0 + e) * N + col] = f2bf(v);
        else                   ((float*)Cout)[(size_t)(row0 + e) * N + col] = v;
      }
    }
}

// ================= chunked selective scan =================
// thread = (b, d, chunk); 16 n-states in registers; conv recomputed per pass.

// ---- pass 1: per-chunk (S = sum dtv, Bacc[16]) with h_in = 0 ----
__global__ __launch_bounds__(256) void scan_p1(const unsigned short* __restrict__ zxbc,
                                               const unsigned short* __restrict__ dtw,
                                               const float* __restrict__ dt_b,
                                               const float* __restrict__ conv_w,
                                               const float* __restrict__ conv_b,
                                               const float* __restrict__ A_log,
                                               float* __restrict__ Sws,
                                               float* __restrict__ Bws) {
  const int d = blockIdx.x * 256 + threadIdx.x;  // channel
  const int c = blockIdx.y;                      // chunk
  const int b = blockIdx.z;
  const int h = d >> 4, p = d & 15;

  const float bias = dt_b[d];
  const float cw0 = conv_w[d*4+0], cw1 = conv_w[d*4+1], cw2 = conv_w[d*4+2], cw3 = conv_w[d*4+3];
  const float cb  = conv_b[d];
  float nacK[16];
#pragma unroll
  for (int n = 0; n < 16; ++n) nacK[n] = -fexp(A_log[d * SN + n]) * LOG2E;  // a = exp2(dtv*nacK)

  const unsigned short* rp  = zxbc + (size_t)b * L_ * NZ;
  const unsigned short* pdt = dtw  + (size_t)b * L_ * DI + d;
  const int ox = DI + ((h >> 2) << 4) + p;
  const int oB = DI + DXB + ((h >> 2) << 4);
  const int t0 = c * TCH;

  float xm1 = (t0 >= 1) ? bf2f(rp[(size_t)(t0-1)*NZ + ox]) : 0.f;
  float xm2 = (t0 >= 2) ? bf2f(rp[(size_t)(t0-2)*NZ + ox]) : 0.f;
  float xm3 = (t0 >= 3) ? bf2f(rp[(size_t)(t0-3)*NZ + ox]) : 0.f;

  float S = 0.f;
  float Bacc[16] = {};

  for (int t = t0; t < t0 + TCH; ++t) {
    const size_t row = (size_t)t * NZ;
    const float xv = bf2f(rp[row + ox]);
    const s16x8 bv0 = *(const s16x8*)&rp[row + oB];
    const s16x8 bv1 = *(const s16x8*)&rp[row + oB + 8];
    const float dr = bf2f(pdt[(size_t)t * DI]);

    const float cs  = cb + cw0*xm3 + cw1*xm2 + cw2*xm1 + cw3*xv;
    const float xa  = fsilu(cs);
    const float dtv = fsoftplus(dr + bias);
    S += dtv;
    const float g = dtv * xa;
#pragma unroll
    for (int n = 0; n < 16; ++n) {
      const float Bn = bf2f((unsigned short)(n < 8 ? bv0[n] : bv1[n-8]));
      const float a  = __builtin_amdgcn_exp2f(dtv * nacK[n]);
      Bacc[n] = Bacc[n] * a + g * Bn;
    }
    xm3 = xm2; xm2 = xm1; xm1 = xv;
  }

  Sws[((size_t)b * CCH + c) * DI + d] = S;
  float* Bo = Bws + (((size_t)b * CCH + c) * DI + d) * 16;
#pragma unroll
  for (int q = 0; q < 4; ++q)
    *(float4*)&Bo[q*4] = make_float4(Bacc[q*4], Bacc[q*4+1], Bacc[q*4+2], Bacc[q*4+3]);
}

// ---- combine (IN-PLACE): Bws[c] becomes h_in for chunk c ----
__global__ __launch_bounds__(256) void scan_comb(const float* __restrict__ Sws,
                                                 float* __restrict__ Bws,
                                                 const float* __restrict__ A_log) {
  const int idx = blockIdx.x * 256 + threadIdx.x;  // d*16+n
  const int b = blockIdx.y;
  const int d = idx >> 4;
  const float nacK = -fexp(A_log[idx]) * LOG2E;
  float hcur = 0.f;
  for (int c = 0; c < CCH; ++c) {
    const size_t cell = ((size_t)b * CCH + c) * DI;
    const size_t bi = (cell + d) * 16 + (idx & 15);
    const float S  = Sws[cell + d];
    const float Ba = Bws[bi];
    Bws[bi] = hcur;                       // h entering chunk c
    hcur = hcur * __builtin_amdgcn_exp2f(S * nacK) + Ba;
  }
}

// ---- pass 2: rerun local scan from Hin (=Bws), emit gated y (bf16) ----
__global__ __launch_bounds__(256) void scan_p2(const unsigned short* __restrict__ zxbc,
                                               const unsigned short* __restrict__ dtw,
                                               const float* __restrict__ dt_b,
                                               const float* __restrict__ conv_w,
                                               const float* __restrict__ conv_b,
                                               const float* __restrict__ A_log,
                                               const float* __restrict__ Dv,
                                               const float* __restrict__ Hin,
                                               unsigned short* __restrict__ yf) {
  const int d = blockIdx.x * 256 + threadIdx.x;
  const int c = blockIdx.y;
  const int b = blockIdx.z;
  const int h = d >> 4, p = d & 15;

  const float bias = dt_b[d];
  const float Dd   = Dv[d];
  const float cw0 = conv_w[d*4+0], cw1 = conv_w[d*4+1], cw2 = conv_w[d*4+2], cw3 = conv_w[d*4+3];
  const float cb  = conv_b[d];
  float nacK[16];
#pragma unroll
  for (int n = 0; n < 16; ++n) nacK[n] = -fexp(A_log[d * SN + n]) * LOG2E;

  float hst[16];
  const float* Hi = Hin + (((size_t)b * CCH + c) * DI + d) * 16;
#pragma unroll
  for (int q = 0; q < 4; ++q) {
    const float4 v = *(const float4*)&Hi[q*4];
    hst[q*4] = v.x; hst[q*4+1] = v.y; hst[q*4+2] = v.z; hst[q*4+3] = v.w;
  }

  const unsigned short* rp  = zxbc + (size_t)b * L_ * NZ;
  const unsigned short* pdt = dtw  + (size_t)b * L_ * DI + d;
  unsigned short* py = yf + (size_t)b * L_ * DI + d;
  const int oz = d;
  const int ox = DI + ((h >> 2) << 4) + p;
  const int oB = DI + DXB + ((h >> 2) << 4);
  const int oC = DI + 2*DXB + (h << 4);
  const int t0 = c * TCH;

  float xm1 = (t0 >= 1) ? bf2f(rp[(size_t)(t0-1)*NZ + ox]) : 0.f;
  float xm2 = (t0 >= 2) ? bf2f(rp[(size_t)(t0-2)*NZ + ox]) : 0.f;
  float xm3 = (t0 >= 3) ? bf2f(rp[(size_t)(t0-3)*NZ + ox]) : 0.f;

  for (int t = t0; t < t0 + TCH; ++t) {
    const size_t row = (size_t)t * NZ;
    const float xv = bf2f(rp[row + ox]);
    const float zv = bf2f(rp[row + oz]);
    const s16x8 bv0 = *(const s16x8*)&rp[row + oB];
    const s16x8 bv1 = *(const s16x8*)&rp[row + oB + 8];
    const s16x8 cv0 = *(const s16x8*)&rp[row + oC];
    const s16x8 cv1 = *(const s16x8*)&rp[row + oC + 8];
    const float dr = bf2f(pdt[(size_t)t * DI]);

    const float cs  = cb + cw0*xm3 + cw1*xm2 + cw2*xm1 + cw3*xv;
    const float xa  = fsilu(cs);
    const float dtv = fsoftplus(dr + bias);
    const float g = dtv * xa;
    float y = 0.f;
#pragma unroll
    for (int n = 0; n < 16; ++n) {
      const float Bn = bf2f((unsigned short)(n < 8 ? bv0[n] : bv1[n-8]));
      const float Cn = bf2f((unsigned short)(n < 8 ? cv0[n] : cv1[n-8]));
      const float a  = __builtin_amdgcn_exp2f(dtv * nacK[n]);
      hst[n] = hst[n] * a + g * Bn;
      y += hst[n] * Cn;
    }
    py[(size_t)t * DI] = f2bf((y + Dd * xa) * fsilu(zv));
    xm3 = xm2; xm2 = xm1; xm1 = xv;
  }
}

// ---------------- launch ----------------
extern "C" void kernel_launch(void* const* d_in, const int* in_sizes, int n_in,
                              void* d_out, int out_size, void* d_ws, size_t ws_size,
                              hipStream_t stream) {
  const float* hs     = (const float*)d_in[0];
  const float* w_in   = (const float*)d_in[1];
  const float* w_dti  = (const float*)d_in[2];
  const float* w_dtp  = (const float*)d_in[3];
  const float* dt_b   = (const float*)d_in[4];
  const float* conv_w = (const float*)d_in[5];
  const float* conv_b = (const float*)d_in[6];
  const float* A_log  = (const float*)d_in[7];
  const float* Dv     = (const float*)d_in[8];
  const float* w_out  = (const float*)d_in[9];
  float* out = (float*)d_out;

  char* ws = (char*)d_ws;
  size_t off = 0;
  auto take = [&](size_t bytes) -> void* {
    void* p = ws + off;
    off += (bytes + 255) & ~(size_t)255;
    return p;
  };
  // ---- shared intermediates (~170 MB) ----
  unsigned short* zxbc  = (unsigned short*)take((size_t)MT * NZ * 2);
  unsigned short* t1b   = (unsigned short*)take((size_t)MT * DTR * 2);
  unsigned short* dtraw = (unsigned short*)take((size_t)MT * DI * 2);
  unsigned short* yfb   = (unsigned short*)take((size_t)MT * DI * 2);
  float*          Sws   = (float*)take((size_t)B_ * CCH * DI * 4);
  float*          Bws   = (float*)take((size_t)B_ * CCH * DI * 16 * 4);

  // ---- bf16 operand copies for the fast path (~62 MB more) ----
  size_t off_base = off;
  unsigned short* hsb   = (unsigned short*)take((size_t)MT * DM * 2);
  unsigned short* w1b   = (unsigned short*)take((size_t)NZ * DM * 2);   // later reused for w_out bf16
  unsigned short* wdtib = (unsigned short*)take((size_t)DTR * DM * 2);
  unsigned short* wdtpb = (unsigned short*)take((size_t)DI * DTR * 2);
  const bool fast = (off <= ws_size);

  auto cast = [&](const float* src, unsigned short* dst, size_t n) {
    int n4 = (int)(n / 4);
    int blocks = (n4 + 255) / 256;
    if (blocks > 2048) blocks = 2048;
    cast_kernel<<<dim3(blocks), dim3(256), 0, stream>>>((const float4*)src, (ushort4*)dst, n4);
  };

  if (fast) {
    cast(hs,    hsb,   (size_t)MT * DM);
    cast(w_in,  w1b,   (size_t)NZ * DM);
    cast(w_dti, wdtib, (size_t)DTR * DM);
    cast(w_dtp, wdtpb, (size_t)DI * DTR);
    // zxbc = hs @ in_proj_w.T   (4096 x 10240, K=2048) -> bf16
    gemm_g16<true><<<dim3(NZ / 128, MT / 128), 256, 0, stream>>>(hsb, w1b, zxbc, MT, NZ, DM);
    // t1 = hs @ dt_in_proj_w.T  (4096 x 128, K=2048) -> bf16
    gemm_g16<true><<<dim3(DTR / 128, MT / 128), 256, 0, stream>>>(hsb, wdtib, t1b, MT, DTR, DM);
    // dtraw = t1 @ dt_proj_w.T  (4096 x 4096, K=128) -> bf16
    gemm_g16<true><<<dim3(DI / 128, MT / 128), 256, 0, stream>>>(t1b, wdtpb, dtraw, MT, DI, DTR);
    // w1b dead now: cast w_out into its region
    cast(w_out, w1b, (size_t)DM * DI);
  } else {
    (void)off_base;
    gemm_nt<float, float, true><<<dim3(NZ / 128, MT / 128), 256, 0, stream>>>(hs, w_in, zxbc, MT, NZ, DM);
    gemm_nt<float, float, true><<<dim3(DTR / 128, MT / 128), 256, 0, stream>>>(hs, w_dti, t1b, MT, DTR, DM);
    gemm_nt<unsigned short, float, true><<<dim3(DI / 128, MT / 128), 256, 0, stream>>>(t1b, w_dtp, dtraw, MT, DI, DTR);
  }

  // chunked selective scan (conv fused, recomputed in both passes)
  scan_p1  <<<dim3(DI/256, CCH, B_), 256, 0, stream>>>(zxbc, dtraw, dt_b, conv_w, conv_b, A_log, Sws, Bws);
  scan_comb<<<dim3(DI*SN/256, B_),  256, 0, stream>>>(Sws, Bws, A_log);
  scan_p2  <<<dim3(DI/256, CCH, B_), 256, 0, stream>>>(zxbc, dtraw, dt_b, conv_w, conv_b, A_log, Dv, Bws, yfb);

  // out = yf @ out_proj_w.T   (4096 x 2048, K=4096) -> f32
  if (fast) {
    gemm_g16<false><<<dim3(DM / 128, MT / 128), 256, 0, stream>>>(yfb, w1b, out, MT, DM, DI);
  } else {
    gemm_nt<unsigned short, float, false><<<dim3(DM / 128, MT / 128), 256, 0, stream>>>(yfb, w_out, out, MT, DM, DI);
  }
}

// Round 6
// 629.828 us; speedup vs baseline: 3.7105x; 1.0205x over previous
//
#include <hip/hip_runtime.h>
#include <cstdint>
#include <cstddef>

// ---------------- problem constants ----------------
constexpr int B_  = 2;
constexpr int L_  = 2048;
constexpr int DM  = 2048;
constexpr int DI  = 4096;
constexpr int DXB = 1024;
constexpr int SN  = 16;     // state dim N
constexpr int DTR = 128;
constexpr int H_  = DI / SN;        // 256 heads
constexpr int NZ  = 2*DXB + 2*DI;   // 10240 (zxbc width)
constexpr int MT  = B_ * L_;        // 4096 rows
constexpr int CCH = 32;             // scan chunks
constexpr int TCH = L_ / CCH;       // 64 steps per chunk

constexpr float LOG2E = 1.4426950408889634f;
constexpr float LN2   = 0.6931471805599453f;

typedef __attribute__((ext_vector_type(4))) float f32x4;
typedef __attribute__((ext_vector_type(8))) short s16x8;

__device__ __forceinline__ unsigned short f2bf(float f) {
  union { float f; unsigned u; } v; v.f = f;
  unsigned r = v.u + 0x7fff + ((v.u >> 16) & 1);   // RNE
  return (unsigned short)(r >> 16);
}
__device__ __forceinline__ float bf2f(unsigned short u) {
  union { unsigned u; float f; } v; v.u = ((unsigned)u) << 16; return v.f;
}
__device__ __forceinline__ float fexp(float x)  { return __builtin_amdgcn_exp2f(x * LOG2E); }
__device__ __forceinline__ float fsilu(float x) { return x * __builtin_amdgcn_rcpf(1.f + fexp(-x)); }
__device__ __forceinline__ float fsoftplus(float x) {
  return (x > 20.f) ? x : __builtin_amdgcn_logf(1.f + fexp(x)) * LN2;
}

// ---------------- f32 -> bf16 cast ----------------
__global__ __launch_bounds__(256) void cast_kernel(const float4* __restrict__ in,
                                                   ushort4* __restrict__ out, int n4) {
  int stride = gridDim.x * blockDim.x;
  for (int i = blockIdx.x * blockDim.x + threadIdx.x; i < n4; i += stride) {
    float4 v = in[i];
    ushort4 o;
    o.x = f2bf(v.x); o.y = f2bf(v.y); o.z = f2bf(v.z); o.w = f2bf(v.w);
    out[i] = o;
  }
}

// ================= 256x256 8-phase GEMM (T2+T3+T4+T5) =================
// C[m,n] = sum_k A[m,k]*W[n,k]; bf16 in, 512 thr (8 waves, 2M x 4N), BK=64.
// LDS: 2 dbuf x 4 half-tiles (A0,A1,B0,B1) x 128x64 bf16 = 128 KiB.
// st_16x32 swizzle: read byte x ^= ((x>>9)&1)<<5 ; stage slot s ^= ((s>>5)&1)<<1
// (same involution on both sides; LDS dest stays linear for global_load_lds).

__device__ __forceinline__ void stage_pair(const unsigned short* __restrict__ G,
                                           int row0, int K, int k0,
                                           unsigned short* lh0, unsigned short* lh1,
                                           int wave, int lane) {
#pragma unroll
  for (int ht = 0; ht < 2; ++ht) {
    unsigned short* lh = ht ? lh1 : lh0;
#pragma unroll
    for (int r = 0; r < 2; ++r) {
      const int sbase = (2 * wave + r) * 64;               // wave-uniform 16B-slot base
      const int s  = sbase + lane;
      const int sp = s ^ (((s >> 5) & 1) << 1);            // pre-swizzled source slot
      const unsigned short* g = G + (size_t)(row0 + ht * 128 + (sp >> 3)) * K + k0 + (sp & 7) * 8;
      __builtin_amdgcn_global_load_lds((const __attribute__((address_space(1))) void*)g,
                                       (__attribute__((address_space(3))) void*)(lh + sbase * 8), 16, 0, 0);
    }
  }
}

__device__ __forceinline__ s16x8 ldsrd(const unsigned short* half_, int row, int kk, int g) {
  int x = row * 128 + kk * 64 + g * 16;                    // linear byte in 128x64 half-tile
  x ^= ((x >> 9) & 1) << 5;                                // st_16x32 swizzle
  return *(const s16x8*)((const char*)half_ + x);
}

template<bool BF16OUT>
__global__ __launch_bounds__(512, 2) void gemm8p(const unsigned short* __restrict__ A,
                                                 const unsigned short* __restrict__ W,
                                                 void* __restrict__ Cout,
                                                 int M, int N, int K) {
  __shared__ unsigned short lds[2][4][8192];
  const int tid = threadIdx.x, lane = tid & 63, wave = tid >> 6;
  const int wr = wave >> 2, wc = wave & 3;
  const int r16 = lane & 15, g = lane >> 4;

  const int ntx = N >> 8;
  const int nwg = gridDim.x;
  const int q8  = nwg >> 3;
  const int gid = ((nwg & 7) == 0) ? (int)(blockIdx.x & 7) * q8 + (int)(blockIdx.x >> 3)
                                   : (int)blockIdx.x;
  const int m0 = (gid / ntx) << 8, n0 = (gid % ntx) << 8;

  f32x4 acc[8][4] = {};
  const int NT = K >> 6;

  // prologue: stage K-tile 0 into buf 0 (8 loads/wave)
  stage_pair(A, m0, K, 0, &lds[0][0][0], &lds[0][1][0], wave, lane);
  stage_pair(W, n0, K, 0, &lds[0][2][0], &lds[0][3][0], wave, lane);

  for (int kt = 0; kt < NT; ++kt) {
    const int p = kt & 1;
    const unsigned short* Ah = &lds[p][wr][0];             // this wave's 128-row A slice
    const unsigned short* Bh = &lds[p][2 + (wc >> 1)][0];  // this wave's B half
    const int brow0 = (wc & 1) * 64;
    const int k0n = (kt + 1) << 6;
    const bool more = (kt + 1 < NT);

    s16x8 bf[4][2], af[2][2];

    // ---------- phase 0: stage A(kt+1); counted wait; B frags + quadrant 0 ----------
    if (more) stage_pair(A, m0, K, k0n, &lds[p ^ 1][0][0], &lds[p ^ 1][1][0], wave, lane);
    if (more) asm volatile("s_waitcnt vmcnt(4)" ::: "memory");   // kt's 8 done; kt+1 A in flight
    else      asm volatile("s_waitcnt vmcnt(0)" ::: "memory");
    asm volatile("s_barrier" ::: "memory");
#pragma unroll
    for (int j = 0; j < 4; ++j)
#pragma unroll
      for (int kk = 0; kk < 2; ++kk)
        bf[j][kk] = ldsrd(Bh, brow0 + j * 16 + r16, kk, g);
#pragma unroll
    for (int i2 = 0; i2 < 2; ++i2)
#pragma unroll
      for (int kk = 0; kk < 2; ++kk)
        af[i2][kk] = ldsrd(Ah, i2 * 16 + r16, kk, g);
    __builtin_amdgcn_s_setprio(1);
#pragma unroll
    for (int kk = 0; kk < 2; ++kk)
#pragma unroll
      for (int i2 = 0; i2 < 2; ++i2)
#pragma unroll
        for (int j = 0; j < 4; ++j)
          acc[i2][j] = __builtin_amdgcn_mfma_f32_16x16x32_bf16(af[i2][kk], bf[j][kk], acc[i2][j], 0, 0, 0);
    __builtin_amdgcn_s_setprio(0);
    __builtin_amdgcn_sched_barrier(0);
    asm volatile("s_barrier" ::: "memory");

    // ---------- phase 1: stage B(kt+1); quadrant 1 ----------
    if (more) stage_pair(W, n0, K, k0n, &lds[p ^ 1][2][0], &lds[p ^ 1][3][0], wave, lane);
#pragma unroll
    for (int i2 = 0; i2 < 2; ++i2)
#pragma unroll
      for (int kk = 0; kk < 2; ++kk)
        af[i2][kk] = ldsrd(Ah, (2 + i2) * 16 + r16, kk, g);
    __builtin_amdgcn_s_setprio(1);
#pragma unroll
    for (int kk = 0; kk < 2; ++kk)
#pragma unroll
      for (int i2 = 0; i2 < 2; ++i2)
#pragma unroll
        for (int j = 0; j < 4; ++j)
          acc[2 + i2][j] = __builtin_amdgcn_mfma_f32_16x16x32_bf16(af[i2][kk], bf[j][kk], acc[2 + i2][j], 0, 0, 0);
    __builtin_amdgcn_s_setprio(0);
    __builtin_amdgcn_sched_barrier(0);
    asm volatile("s_barrier" ::: "memory");

    // ---------- phase 2: quadrant 2 ----------
#pragma unroll
    for (int i2 = 0; i2 < 2; ++i2)
#pragma unroll
      for (int kk = 0; kk < 2; ++kk)
        af[i2][kk] = ldsrd(Ah, (4 + i2) * 16 + r16, kk, g);
    __builtin_amdgcn_s_setprio(1);
#pragma unroll
    for (int kk = 0; kk < 2; ++kk)
#pragma unroll
      for (int i2 = 0; i2 < 2; ++i2)
#pragma unroll
        for (int j = 0; j < 4; ++j)
          acc[4 + i2][j] = __builtin_amdgcn_mfma_f32_16x16x32_bf16(af[i2][kk], bf[j][kk], acc[4 + i2][j], 0, 0, 0);
    __builtin_amdgcn_s_setprio(0);
    __builtin_amdgcn_sched_barrier(0);
    asm volatile("s_barrier" ::: "memory");

    // ---------- phase 3: quadrant 3; end-of-tile barrier guards WAR ----------
#pragma unroll
    for (int i2 = 0; i2 < 2; ++i2)
#pragma unroll
      for (int kk = 0; kk < 2; ++kk)
        af[i2][kk] = ldsrd(Ah, (6 + i2) * 16 + r16, kk, g);
    __builtin_amdgcn_s_setprio(1);
#pragma unroll
    for (int kk = 0; kk < 2; ++kk)
#pragma unroll
      for (int i2 = 0; i2 < 2; ++i2)
#pragma unroll
        for (int j = 0; j < 4; ++j)
          acc[6 + i2][j] = __builtin_amdgcn_mfma_f32_16x16x32_bf16(af[i2][kk], bf[j][kk], acc[6 + i2][j], 0, 0, 0);
    __builtin_amdgcn_s_setprio(0);
    __builtin_amdgcn_sched_barrier(0);
    asm volatile("s_barrier" ::: "memory");
  }

  // epilogue
#pragma unroll
  for (int i = 0; i < 8; ++i)
#pragma unroll
    for (int j = 0; j < 4; ++j) {
      const int row0 = m0 + wr * 128 + i * 16 + g * 4;
      const int col  = n0 + wc * 64 + j * 16 + r16;
#pragma unroll
      for (int e = 0; e < 4; ++e) {
        float v = acc[i][j][e];
        if constexpr (BF16OUT) ((unsigned short*)Cout)[(size_t)(row0 + e) * N + col] = f2bf(v);
        else                   ((float*)Cout)[(size_t)(row0 + e) * N + col] = v;
      }
    }
}

// ---------------- 128x128 bf16 GEMM, global_load_lds staging (m97 structure) ----------------
template<bool BF16OUT>
__global__ __launch_bounds__(256) void gemm_g16(const unsigned short* __restrict__ A,
                                                const unsigned short* __restrict__ W,
                                                void* __restrict__ Cout,
                                                int M, int N, int K) {
  __shared__ alignas(16) unsigned short sA[128 * 32];
  __shared__ alignas(16) unsigned short sB[128 * 32];
  const int tid  = threadIdx.x;
  const int lane = tid & 63;
  const int wave = tid >> 6;
  const int m0 = blockIdx.y * 128, n0 = blockIdx.x * 128;
  const int wr = wave >> 1, wc = wave & 1;
  const int r16 = lane & 15, g = lane >> 4;
  f32x4 acc[4][4] = {};

  for (int k0 = 0; k0 < K; k0 += 32) {
    __syncthreads();
#pragma unroll
    for (int it = 0; it < 2; ++it) {
      const int base = wave * 128 + it * 64;
      const int slot = base + lane;
      const int r = slot >> 2, c8 = slot & 3;
      const unsigned short* ga = A + (size_t)(m0 + r) * K + k0 + c8 * 8;
      const unsigned short* gb = W + (size_t)(n0 + r) * K + k0 + c8 * 8;
      __builtin_amdgcn_global_load_lds((const __attribute__((address_space(1))) void*)ga,
                                       (__attribute__((address_space(3))) void*)(sA + base * 8), 16, 0, 0);
      __builtin_amdgcn_global_load_lds((const __attribute__((address_space(1))) void*)gb,
                                       (__attribute__((address_space(3))) void*)(sB + base * 8), 16, 0, 0);
    }
    __syncthreads();

    s16x8 af[4], bfr[4];
#pragma unroll
    for (int f = 0; f < 4; ++f) {
      af[f]  = *(const s16x8*)&sA[(wr * 64 + f * 16 + r16) * 32 + g * 8];
      bfr[f] = *(const s16x8*)&sB[(wc * 64 + f * 16 + r16) * 32 + g * 8];
    }
#pragma unroll
    for (int i = 0; i < 4; ++i)
#pragma unroll
      for (int j = 0; j < 4; ++j)
        acc[i][j] = __builtin_amdgcn_mfma_f32_16x16x32_bf16(af[i], bfr[j], acc[i][j], 0, 0, 0);
  }

#pragma unroll
  for (int i = 0; i < 4; ++i)
#pragma unroll
    for (int j = 0; j < 4; ++j) {
      const int row0 = m0 + wr * 64 + i * 16 + g * 4;
      const int col  = n0 + wc * 64 + j * 16 + r16;
#pragma unroll
      for (int e = 0; e < 4; ++e) {
        float v = acc[i][j][e];
        if constexpr (BF16OUT) ((unsigned short*)Cout)[(size_t)(row0 + e) * N + col] = f2bf(v);
        else                   ((float*)Cout)[(size_t)(row0 + e) * N + col] = v;
      }
    }
}

// ---------------- fallback GEMM (reg-staged, f32-or-bf16 inputs) ----------------
template<typename AT, typename WT, bool BF16OUT>
__global__ __launch_bounds__(256) void gemm_nt(const AT* __restrict__ A,
                                               const WT* __restrict__ W,
                                               void* __restrict__ Cout,
                                               int M, int N, int K) {
  __shared__ alignas(16) unsigned short sA[128 * 32];
  __shared__ alignas(16) unsigned short sB[128 * 32];
  const int tid  = threadIdx.x;
  const int lane = tid & 63;
  const int wave = tid >> 6;
  const int m0 = blockIdx.y * 128, n0 = blockIdx.x * 128;
  const int wr = wave >> 1, wc = wave & 1;
  const int r16 = lane & 15, g = lane >> 4;
  f32x4 acc[4][4] = {};

  for (int k0 = 0; k0 < K; k0 += 32) {
    __syncthreads();
    if constexpr (sizeof(AT) == 4) {
#pragma unroll
      for (int s = 0; s < 4; ++s) {
        const int slot = tid + s * 256;
        const int row = slot >> 3, c4 = slot & 7;
        const float4 v = *(const float4*)((const float*)A + (size_t)(m0 + row) * K + k0 + c4 * 4);
        ushort4 o; o.x = f2bf(v.x); o.y = f2bf(v.y); o.z = f2bf(v.z); o.w = f2bf(v.w);
        *(ushort4*)&sA[row * 32 + c4 * 4] = o;
      }
    } else {
#pragma unroll
      for (int s = 0; s < 2; ++s) {
        const int slot = tid + s * 256;
        const int row = slot >> 2, c8 = slot & 3;
        *(s16x8*)&sA[row * 32 + c8 * 8] =
            *(const s16x8*)((const unsigned short*)A + (size_t)(m0 + row) * K + k0 + c8 * 8);
      }
    }
    if constexpr (sizeof(WT) == 4) {
#pragma unroll
      for (int s = 0; s < 4; ++s) {
        const int slot = tid + s * 256;
        const int row = slot >> 3, c4 = slot & 7;
        const float4 v = *(const float4*)((const float*)W + (size_t)(n0 + row) * K + k0 + c4 * 4);
        ushort4 o; o.x = f2bf(v.x); o.y = f2bf(v.y); o.z = f2bf(v.z); o.w = f2bf(v.w);
        *(ushort4*)&sB[row * 32 + c4 * 4] = o;
      }
    } else {
#pragma unroll
      for (int s = 0; s < 2; ++s) {
        const int slot = tid + s * 256;
        const int row = slot >> 2, c8 = slot & 3;
        *(s16x8*)&sB[row * 32 + c8 * 8] =
            *(const s16x8*)((const unsigned short*)W + (size_t)(n0 + row) * K + k0 + c8 * 8);
      }
    }
    __syncthreads();

    s16x8 af[4], bfr[4];
#pragma unroll
    for (int f = 0; f < 4; ++f) {
      af[f]  = *(const s16x8*)&sA[(wr * 64 + f * 16 + r16) * 32 + g * 8];
      bfr[f] = *(const s16x8*)&sB[(wc * 64 + f * 16 + r16) * 32 + g * 8];
    }
#pragma unroll
    for (int i = 0; i < 4; ++i)
#pragma unroll
      for (int j = 0; j < 4; ++j)
        acc[i][j] = __builtin_amdgcn_mfma_f32_16x16x32_bf16(af[i], bfr[j], acc[i][j], 0, 0, 0);
  }

#pragma unroll
  for (int i = 0; i < 4; ++i)
#pragma unroll
    for (int j = 0; j < 4; ++j) {
      const int row0 = m0 + wr * 64 + i * 16 + g * 4;
      const int col  = n0 + wc * 64 + j * 16 + r16;
#pragma unroll
      for (int e = 0; e < 4; ++e) {
        float v = acc[i][j][e];
        if constexpr (BF16OUT) ((unsigned short*)Cout)[(size_t)(row0 + e) * N + col] = f2bf(v);
        else                   ((float*)Cout)[(size_t)(row0 + e) * N + col] = v;
      }
    }
}

// ================= chunked selective scan =================

__global__ __launch_bounds__(256) void scan_p1(const unsigned short* __restrict__ zxbc,
                                               const unsigned short* __restrict__ dtw,
                                               const float* __restrict__ dt_b,
                                               const float* __restrict__ conv_w,
                                               const float* __restrict__ conv_b,
                                               const float* __restrict__ A_log,
                                               float* __restrict__ Sws,
                                               float* __restrict__ Bws) {
  const int d = blockIdx.x * 256 + threadIdx.x;
  const int c = blockIdx.y;
  const int b = blockIdx.z;
  const int h = d >> 4, p = d & 15;

  const float bias = dt_b[d];
  const float cw0 = conv_w[d*4+0], cw1 = conv_w[d*4+1], cw2 = conv_w[d*4+2], cw3 = conv_w[d*4+3];
  const float cb  = conv_b[d];
  float nacK[16];
#pragma unroll
  for (int n = 0; n < 16; ++n) nacK[n] = -fexp(A_log[d * SN + n]) * LOG2E;

  const unsigned short* rp  = zxbc + (size_t)b * L_ * NZ;
  const unsigned short* pdt = dtw  + (size_t)b * L_ * DI + d;
  const int ox = DI + ((h >> 2) << 4) + p;
  const int oB = DI + DXB + ((h >> 2) << 4);
  const int t0 = c * TCH;

  float xm1 = (t0 >= 1) ? bf2f(rp[(size_t)(t0-1)*NZ + ox]) : 0.f;
  float xm2 = (t0 >= 2) ? bf2f(rp[(size_t)(t0-2)*NZ + ox]) : 0.f;
  float xm3 = (t0 >= 3) ? bf2f(rp[(size_t)(t0-3)*NZ + ox]) : 0.f;

  float S = 0.f;
  float Bacc[16] = {};

  for (int t = t0; t < t0 + TCH; ++t) {
    const size_t row = (size_t)t * NZ;
    const float xv = bf2f(rp[row + ox]);
    const s16x8 bv0 = *(const s16x8*)&rp[row + oB];
    const s16x8 bv1 = *(const s16x8*)&rp[row + oB + 8];
    const float dr = bf2f(pdt[(size_t)t * DI]);

    const float cs  = cb + cw0*xm3 + cw1*xm2 + cw2*xm1 + cw3*xv;
    const float xa  = fsilu(cs);
    const float dtv = fsoftplus(dr + bias);
    S += dtv;
    const float g = dtv * xa;
#pragma unroll
    for (int n = 0; n < 16; ++n) {
      const float Bn = bf2f((unsigned short)(n < 8 ? bv0[n] : bv1[n-8]));
      const float a  = __builtin_amdgcn_exp2f(dtv * nacK[n]);
      Bacc[n] = Bacc[n] * a + g * Bn;
    }
    xm3 = xm2; xm2 = xm1; xm1 = xv;
  }

  Sws[((size_t)b * CCH + c) * DI + d] = S;
  float* Bo = Bws + (((size_t)b * CCH + c) * DI + d) * 16;
#pragma unroll
  for (int q = 0; q < 4; ++q)
    *(float4*)&Bo[q*4] = make_float4(Bacc[q*4], Bacc[q*4+1], Bacc[q*4+2], Bacc[q*4+3]);
}

__global__ __launch_bounds__(256) void scan_comb(const float* __restrict__ Sws,
                                                 float* __restrict__ Bws,
                                                 const float* __restrict__ A_log) {
  const int idx = blockIdx.x * 256 + threadIdx.x;
  const int b = blockIdx.y;
  const int d = idx >> 4;
  const float nacK = -fexp(A_log[idx]) * LOG2E;
  float hcur = 0.f;
  for (int c = 0; c < CCH; ++c) {
    const size_t cell = ((size_t)b * CCH + c) * DI;
    const size_t bi = (cell + d) * 16 + (idx & 15);
    const float S  = Sws[cell + d];
    const float Ba = Bws[bi];
    Bws[bi] = hcur;
    hcur = hcur * __builtin_amdgcn_exp2f(S * nacK) + Ba;
  }
}

__global__ __launch_bounds__(256) void scan_p2(const unsigned short* __restrict__ zxbc,
                                               const unsigned short* __restrict__ dtw,
                                               const float* __restrict__ dt_b,
                                               const float* __restrict__ conv_w,
                                               const float* __restrict__ conv_b,
                                               const float* __restrict__ A_log,
                                               const float* __restrict__ Dv,
                                               const float* __restrict__ Hin,
                                               unsigned short* __restrict__ yf) {
  const int d = blockIdx.x * 256 + threadIdx.x;
  const int c = blockIdx.y;
  const int b = blockIdx.z;
  const int h = d >> 4, p = d & 15;

  const float bias = dt_b[d];
  const float Dd   = Dv[d];
  const float cw0 = conv_w[d*4+0], cw1 = conv_w[d*4+1], cw2 = conv_w[d*4+2], cw3 = conv_w[d*4+3];
  const float cb  = conv_b[d];
  float nacK[16];
#pragma unroll
  for (int n = 0; n < 16; ++n) nacK[n] = -fexp(A_log[d * SN + n]) * LOG2E;

  float hst[16];
  const float* Hi = Hin + (((size_t)b * CCH + c) * DI + d) * 16;
#pragma unroll
  for (int q = 0; q < 4; ++q) {
    const float4 v = *(const float4*)&Hi[q*4];
    hst[q*4] = v.x; hst[q*4+1] = v.y; hst[q*4+2] = v.z; hst[q*4+3] = v.w;
  }

  const unsigned short* rp  = zxbc + (size_t)b * L_ * NZ;
  const unsigned short* pdt = dtw  + (size_t)b * L_ * DI + d;
  unsigned short* py = yf + (size_t)b * L_ * DI + d;
  const int oz = d;
  const int ox = DI + ((h >> 2) << 4) + p;
  const int oB = DI + DXB + ((h >> 2) << 4);
  const int oC = DI + 2*DXB + (h << 4);
  const int t0 = c * TCH;

  float xm1 = (t0 >= 1) ? bf2f(rp[(size_t)(t0-1)*NZ + ox]) : 0.f;
  float xm2 = (t0 >= 2) ? bf2f(rp[(size_t)(t0-2)*NZ + ox]) : 0.f;
  float xm3 = (t0 >= 3) ? bf2f(rp[(size_t)(t0-3)*NZ + ox]) : 0.f;

  for (int t = t0; t < t0 + TCH; ++t) {
    const size_t row = (size_t)t * NZ;
    const float xv = bf2f(rp[row + ox]);
    const float zv = bf2f(rp[row + oz]);
    const s16x8 bv0 = *(const s16x8*)&rp[row + oB];
    const s16x8 bv1 = *(const s16x8*)&rp[row + oB + 8];
    const s16x8 cv0 = *(const s16x8*)&rp[row + oC];
    const s16x8 cv1 = *(const s16x8*)&rp[row + oC + 8];
    const float dr = bf2f(pdt[(size_t)t * DI]);

    const float cs  = cb + cw0*xm3 + cw1*xm2 + cw2*xm1 + cw3*xv;
    const float xa  = fsilu(cs);
    const float dtv = fsoftplus(dr + bias);
    const float g = dtv * xa;
    float y = 0.f;
#pragma unroll
    for (int n = 0; n < 16; ++n) {
      const float Bn = bf2f((unsigned short)(n < 8 ? bv0[n] : bv1[n-8]));
      const float Cn = bf2f((unsigned short)(n < 8 ? cv0[n] : cv1[n-8]));
      const float a  = __builtin_amdgcn_exp2f(dtv * nacK[n]);
      hst[n] = hst[n] * a + g * Bn;
      y += hst[n] * Cn;
    }
    py[(size_t)t * DI] = f2bf((y + Dd * xa) * fsilu(zv));
    xm3 = xm2; xm2 = xm1; xm1 = xv;
  }
}

// ---------------- launch ----------------
extern "C" void kernel_launch(void* const* d_in, const int* in_sizes, int n_in,
                              void* d_out, int out_size, void* d_ws, size_t ws_size,
                              hipStream_t stream) {
  const float* hs     = (const float*)d_in[0];
  const float* w_in   = (const float*)d_in[1];
  const float* w_dti  = (const float*)d_in[2];
  const float* w_dtp  = (const float*)d_in[3];
  const float* dt_b   = (const float*)d_in[4];
  const float* conv_w = (const float*)d_in[5];
  const float* conv_b = (const float*)d_in[6];
  const float* A_log  = (const float*)d_in[7];
  const float* Dv     = (const float*)d_in[8];
  const float* w_out  = (const float*)d_in[9];
  float* out = (float*)d_out;

  char* ws = (char*)d_ws;
  size_t off = 0;
  auto take = [&](size_t bytes) -> void* {
    void* p = ws + off;
    off += (bytes + 255) & ~(size_t)255;
    return p;
  };
  // ---- shared intermediates (~170 MB) ----
  unsigned short* zxbc  = (unsigned short*)take((size_t)MT * NZ * 2);
  unsigned short* t1b   = (unsigned short*)take((size_t)MT * DTR * 2);
  unsigned short* dtraw = (unsigned short*)take((size_t)MT * DI * 2);
  unsigned short* yfb   = (unsigned short*)take((size_t)MT * DI * 2);
  float*          Sws   = (float*)take((size_t)B_ * CCH * DI * 4);
  float*          Bws   = (float*)take((size_t)B_ * CCH * DI * 16 * 4);

  // ---- bf16 operand copies for the fast path (~62 MB more) ----
  unsigned short* hsb   = (unsigned short*)take((size_t)MT * DM * 2);
  unsigned short* w1b   = (unsigned short*)take((size_t)NZ * DM * 2);   // later reused for w_out bf16
  unsigned short* wdtib = (unsigned short*)take((size_t)DTR * DM * 2);
  unsigned short* wdtpb = (unsigned short*)take((size_t)DI * DTR * 2);
  const bool fast = (off <= ws_size);

  auto cast = [&](const float* src, unsigned short* dst, size_t n) {
    int n4 = (int)(n / 4);
    int blocks = (n4 + 255) / 256;
    if (blocks > 2048) blocks = 2048;
    cast_kernel<<<dim3(blocks), dim3(256), 0, stream>>>((const float4*)src, (ushort4*)dst, n4);
  };

  if (fast) {
    cast(hs,    hsb,   (size_t)MT * DM);
    cast(w_in,  w1b,   (size_t)NZ * DM);
    cast(w_dti, wdtib, (size_t)DTR * DM);
    cast(w_dtp, wdtpb, (size_t)DI * DTR);
    // zxbc = hs @ in_proj_w.T   (4096 x 10240, K=2048) -> bf16 [256^2 8-phase]
    gemm8p<true><<<dim3((NZ / 256) * (MT / 256)), 512, 0, stream>>>(hsb, w1b, zxbc, MT, NZ, DM);
    // t1 = hs @ dt_in_proj_w.T  (4096 x 128, K=2048) -> bf16
    gemm_g16<true><<<dim3(DTR / 128, MT / 128), 256, 0, stream>>>(hsb, wdtib, t1b, MT, DTR, DM);
    // dtraw = t1 @ dt_proj_w.T  (4096 x 4096, K=128) -> bf16
    gemm_g16<true><<<dim3(DI / 128, MT / 128), 256, 0, stream>>>(t1b, wdtpb, dtraw, MT, DI, DTR);
    // w1b dead now: cast w_out into its region
    cast(w_out, w1b, (size_t)DM * DI);
  } else {
    gemm_nt<float, float, true><<<dim3(NZ / 128, MT / 128), 256, 0, stream>>>(hs, w_in, zxbc, MT, NZ, DM);
    gemm_nt<float, float, true><<<dim3(DTR / 128, MT / 128), 256, 0, stream>>>(hs, w_dti, t1b, MT, DTR, DM);
    gemm_nt<unsigned short, float, true><<<dim3(DI / 128, MT / 128), 256, 0, stream>>>(t1b, w_dtp, dtraw, MT, DI, DTR);
  }

  // chunked selective scan (conv fused, recomputed in both passes)
  scan_p1  <<<dim3(DI/256, CCH, B_), 256, 0, stream>>>(zxbc, dtraw, dt_b, conv_w, conv_b, A_log, Sws, Bws);
  scan_comb<<<dim3(DI*SN/256, B_),  256, 0, stream>>>(Sws, Bws, A_log);
  scan_p2  <<<dim3(DI/256, CCH, B_), 256, 0, stream>>>(zxbc, dtraw, dt_b, conv_w, conv_b, A_log, Dv, Bws, yfb);

  // out = yf @ out_proj_w.T   (4096 x 2048, K=4096) -> f32
  if (fast) {
    gemm_g16<false><<<dim3(DM / 128, MT / 128), 256, 0, stream>>>(yfb, w1b, out, MT, DM, DI);
  } else {
    gemm_nt<unsigned short, float, false><<<dim3(DM / 128, MT / 128), 256, 0, stream>>>(yfb, w_out, out, MT, DM, DI);
  }
}

// Round 7
// 618.220 us; speedup vs baseline: 3.7802x; 1.0188x over previous
//
#include <hip/hip_runtime.h>
#include <cstdint>
#include <cstddef>

// ---------------- problem constants ----------------
constexpr int B_  = 2;
constexpr int L_  = 2048;
constexpr int DM  = 2048;
constexpr int DI  = 4096;
constexpr int DXB = 1024;
constexpr int SN  = 16;     // state dim N
constexpr int DTR = 128;
constexpr int H_  = DI / SN;        // 256 heads
constexpr int NZ  = 2*DXB + 2*DI;   // 10240 (zxbc width)
constexpr int MT  = B_ * L_;        // 4096 rows
constexpr int CCH = 32;             // scan chunks
constexpr int TCH = L_ / CCH;       // 64 steps per chunk

constexpr float LOG2E = 1.4426950408889634f;
constexpr float LN2   = 0.6931471805599453f;

typedef __attribute__((ext_vector_type(4))) float f32x4;
typedef __attribute__((ext_vector_type(8))) short s16x8;

__device__ __forceinline__ unsigned short f2bf(float f) {
  union { float f; unsigned u; } v; v.f = f;
  unsigned r = v.u + 0x7fff + ((v.u >> 16) & 1);   // RNE
  return (unsigned short)(r >> 16);
}
__device__ __forceinline__ float bf2f(unsigned short u) {
  union { unsigned u; float f; } v; v.u = ((unsigned)u) << 16; return v.f;
}
__device__ __forceinline__ float fexp(float x)  { return __builtin_amdgcn_exp2f(x * LOG2E); }
__device__ __forceinline__ float fsilu(float x) { return x * __builtin_amdgcn_rcpf(1.f + fexp(-x)); }
__device__ __forceinline__ float fsoftplus(float x) {
  return (x > 20.f) ? x : __builtin_amdgcn_logf(1.f + fexp(x)) * LN2;
}

// ---------------- f32 -> bf16 cast ----------------
__global__ __launch_bounds__(256) void cast_kernel(const float4* __restrict__ in,
                                                   ushort4* __restrict__ out, int n4) {
  int stride = gridDim.x * blockDim.x;
  for (int i = blockIdx.x * blockDim.x + threadIdx.x; i < n4; i += stride) {
    float4 v = in[i];
    ushort4 o;
    o.x = f2bf(v.x); o.y = f2bf(v.y); o.z = f2bf(v.z); o.w = f2bf(v.w);
    out[i] = o;
  }
}

// ================= 256x256 8-phase GEMM (T2+T3+T4+T5) =================
// C[m,n] = sum_k A[m,k]*W[n,k]; bf16 in, 512 thr (8 waves, 2M x 4N), BK=64.
// LDS: 2 dbuf x 4 half-tiles (A0,A1,B0,B1) x 128x64 bf16 = 128 KiB.
// Swizzle (full 3-bit, conflict-free): read byte x ^= ((x>>7)&7)<<4
// (chunk bits 4-6 ^= row&7); stage source slot sp = s ^ ((s>>3)&7).
// Same involution on both sides; LDS dest stays linear for global_load_lds.

__device__ __forceinline__ void stage_pair(const unsigned short* __restrict__ G,
                                           int row0, int K, int k0,
                                           unsigned short* lh0, unsigned short* lh1,
                                           int wave, int lane) {
#pragma unroll
  for (int ht = 0; ht < 2; ++ht) {
    unsigned short* lh = ht ? lh1 : lh0;
#pragma unroll
    for (int r = 0; r < 2; ++r) {
      const int sbase = (2 * wave + r) * 64;               // wave-uniform 16B-slot base
      const int s  = sbase + lane;
      const int sp = s ^ ((s >> 3) & 7);                   // pre-swizzled source slot (row kept)
      const unsigned short* g = G + (size_t)(row0 + ht * 128 + (sp >> 3)) * K + k0 + (sp & 7) * 8;
      __builtin_amdgcn_global_load_lds((const __attribute__((address_space(1))) void*)g,
                                       (__attribute__((address_space(3))) void*)(lh + sbase * 8), 16, 0, 0);
    }
  }
}

__device__ __forceinline__ s16x8 ldsrd(const unsigned short* half_, int row, int kk, int g) {
  int x = row * 128 + kk * 64 + g * 16;                    // linear byte in 128x64 half-tile
  x ^= (x >> 3) & 0x70;                                    // chunk ^= row&7 (involution)
  return *(const s16x8*)((const char*)half_ + x);
}

template<bool BF16OUT>
__global__ __launch_bounds__(512, 2) void gemm8p(const unsigned short* __restrict__ A,
                                                 const unsigned short* __restrict__ W,
                                                 void* __restrict__ Cout,
                                                 int M, int N, int K) {
  __shared__ unsigned short lds[2][4][8192];
  const int tid = threadIdx.x, lane = tid & 63, wave = tid >> 6;
  const int wr = wave >> 2, wc = wave & 3;
  const int r16 = lane & 15, g = lane >> 4;

  const int ntx = N >> 8;
  const int nwg = gridDim.x;
  const int q8  = nwg >> 3;
  const int gid = ((nwg & 7) == 0) ? (int)(blockIdx.x & 7) * q8 + (int)(blockIdx.x >> 3)
                                   : (int)blockIdx.x;
  const int m0 = (gid / ntx) << 8, n0 = (gid % ntx) << 8;

  f32x4 acc[8][4] = {};
  const int NT = K >> 6;

  // prologue: stage K-tile 0 into buf 0 (8 loads/wave)
  stage_pair(A, m0, K, 0, &lds[0][0][0], &lds[0][1][0], wave, lane);
  stage_pair(W, n0, K, 0, &lds[0][2][0], &lds[0][3][0], wave, lane);

  for (int kt = 0; kt < NT; ++kt) {
    const int p = kt & 1;
    const unsigned short* Ah = &lds[p][wr][0];             // this wave's 128-row A slice
    const unsigned short* Bh = &lds[p][2 + (wc >> 1)][0];  // this wave's B half
    const int brow0 = (wc & 1) * 64;
    const int k0n = (kt + 1) << 6;
    const bool more = (kt + 1 < NT);

    s16x8 bf[4][2], af[2][2];

    // ---------- phase 0: stage A(kt+1); counted wait; B frags + quadrant 0 ----------
    if (more) stage_pair(A, m0, K, k0n, &lds[p ^ 1][0][0], &lds[p ^ 1][1][0], wave, lane);
    if (more) asm volatile("s_waitcnt vmcnt(4)" ::: "memory");   // kt's 8 done; kt+1 A in flight
    else      asm volatile("s_waitcnt vmcnt(0)" ::: "memory");
    asm volatile("s_barrier" ::: "memory");
#pragma unroll
    for (int j = 0; j < 4; ++j)
#pragma unroll
      for (int kk = 0; kk < 2; ++kk)
        bf[j][kk] = ldsrd(Bh, brow0 + j * 16 + r16, kk, g);
#pragma unroll
    for (int i2 = 0; i2 < 2; ++i2)
#pragma unroll
      for (int kk = 0; kk < 2; ++kk)
        af[i2][kk] = ldsrd(Ah, i2 * 16 + r16, kk, g);
    __builtin_amdgcn_s_setprio(1);
#pragma unroll
    for (int kk = 0; kk < 2; ++kk)
#pragma unroll
      for (int i2 = 0; i2 < 2; ++i2)
#pragma unroll
        for (int j = 0; j < 4; ++j)
          acc[i2][j] = __builtin_amdgcn_mfma_f32_16x16x32_bf16(af[i2][kk], bf[j][kk], acc[i2][j], 0, 0, 0);
    __builtin_amdgcn_s_setprio(0);
    __builtin_amdgcn_sched_barrier(0);
    asm volatile("s_barrier" ::: "memory");

    // ---------- phase 1: stage B(kt+1); quadrant 1 ----------
    if (more) stage_pair(W, n0, K, k0n, &lds[p ^ 1][2][0], &lds[p ^ 1][3][0], wave, lane);
#pragma unroll
    for (int i2 = 0; i2 < 2; ++i2)
#pragma unroll
      for (int kk = 0; kk < 2; ++kk)
        af[i2][kk] = ldsrd(Ah, (2 + i2) * 16 + r16, kk, g);
    __builtin_amdgcn_s_setprio(1);
#pragma unroll
    for (int kk = 0; kk < 2; ++kk)
#pragma unroll
      for (int i2 = 0; i2 < 2; ++i2)
#pragma unroll
        for (int j = 0; j < 4; ++j)
          acc[2 + i2][j] = __builtin_amdgcn_mfma_f32_16x16x32_bf16(af[i2][kk], bf[j][kk], acc[2 + i2][j], 0, 0, 0);
    __builtin_amdgcn_s_setprio(0);
    __builtin_amdgcn_sched_barrier(0);
    asm volatile("s_barrier" ::: "memory");

    // ---------- phase 2: quadrant 2 ----------
#pragma unroll
    for (int i2 = 0; i2 < 2; ++i2)
#pragma unroll
      for (int kk = 0; kk < 2; ++kk)
        af[i2][kk] = ldsrd(Ah, (4 + i2) * 16 + r16, kk, g);
    __builtin_amdgcn_s_setprio(1);
#pragma unroll
    for (int kk = 0; kk < 2; ++kk)
#pragma unroll
      for (int i2 = 0; i2 < 2; ++i2)
#pragma unroll
        for (int j = 0; j < 4; ++j)
          acc[4 + i2][j] = __builtin_amdgcn_mfma_f32_16x16x32_bf16(af[i2][kk], bf[j][kk], acc[4 + i2][j], 0, 0, 0);
    __builtin_amdgcn_s_setprio(0);
    __builtin_amdgcn_sched_barrier(0);
    asm volatile("s_barrier" ::: "memory");

    // ---------- phase 3: quadrant 3; end-of-tile barrier guards WAR ----------
#pragma unroll
    for (int i2 = 0; i2 < 2; ++i2)
#pragma unroll
      for (int kk = 0; kk < 2; ++kk)
        af[i2][kk] = ldsrd(Ah, (6 + i2) * 16 + r16, kk, g);
    __builtin_amdgcn_s_setprio(1);
#pragma unroll
    for (int kk = 0; kk < 2; ++kk)
#pragma unroll
      for (int i2 = 0; i2 < 2; ++i2)
#pragma unroll
        for (int j = 0; j < 4; ++j)
          acc[6 + i2][j] = __builtin_amdgcn_mfma_f32_16x16x32_bf16(af[i2][kk], bf[j][kk], acc[6 + i2][j], 0, 0, 0);
    __builtin_amdgcn_s_setprio(0);
    __builtin_amdgcn_sched_barrier(0);
    asm volatile("s_barrier" ::: "memory");
  }

  // epilogue
#pragma unroll
  for (int i = 0; i < 8; ++i)
#pragma unroll
    for (int j = 0; j < 4; ++j) {
      const int row0 = m0 + wr * 128 + i * 16 + g * 4;
      const int col  = n0 + wc * 64 + j * 16 + r16;
#pragma unroll
      for (int e = 0; e < 4; ++e) {
        float v = acc[i][j][e];
        if constexpr (BF16OUT) ((unsigned short*)Cout)[(size_t)(row0 + e) * N + col] = f2bf(v);
        else                   ((float*)Cout)[(size_t)(row0 + e) * N + col] = v;
      }
    }
}

// ---------------- 128x128 bf16 GEMM, global_load_lds staging (m97 structure) ----------------
template<bool BF16OUT>
__global__ __launch_bounds__(256) void gemm_g16(const unsigned short* __restrict__ A,
                                                const unsigned short* __restrict__ W,
                                                void* __restrict__ Cout,
                                                int M, int N, int K) {
  __shared__ alignas(16) unsigned short sA[128 * 32];
  __shared__ alignas(16) unsigned short sB[128 * 32];
  const int tid  = threadIdx.x;
  const int lane = tid & 63;
  const int wave = tid >> 6;
  const int m0 = blockIdx.y * 128, n0 = blockIdx.x * 128;
  const int wr = wave >> 1, wc = wave & 1;
  const int r16 = lane & 15, g = lane >> 4;
  f32x4 acc[4][4] = {};

  for (int k0 = 0; k0 < K; k0 += 32) {
    __syncthreads();
#pragma unroll
    for (int it = 0; it < 2; ++it) {
      const int base = wave * 128 + it * 64;
      const int slot = base + lane;
      const int r = slot >> 2, c8 = slot & 3;
      const unsigned short* ga = A + (size_t)(m0 + r) * K + k0 + c8 * 8;
      const unsigned short* gb = W + (size_t)(n0 + r) * K + k0 + c8 * 8;
      __builtin_amdgcn_global_load_lds((const __attribute__((address_space(1))) void*)ga,
                                       (__attribute__((address_space(3))) void*)(sA + base * 8), 16, 0, 0);
      __builtin_amdgcn_global_load_lds((const __attribute__((address_space(1))) void*)gb,
                                       (__attribute__((address_space(3))) void*)(sB + base * 8), 16, 0, 0);
    }
    __syncthreads();

    s16x8 af[4], bfr[4];
#pragma unroll
    for (int f = 0; f < 4; ++f) {
      af[f]  = *(const s16x8*)&sA[(wr * 64 + f * 16 + r16) * 32 + g * 8];
      bfr[f] = *(const s16x8*)&sB[(wc * 64 + f * 16 + r16) * 32 + g * 8];
    }
#pragma unroll
    for (int i = 0; i < 4; ++i)
#pragma unroll
      for (int j = 0; j < 4; ++j)
        acc[i][j] = __builtin_amdgcn_mfma_f32_16x16x32_bf16(af[i], bfr[j], acc[i][j], 0, 0, 0);
  }

#pragma unroll
  for (int i = 0; i < 4; ++i)
#pragma unroll
    for (int j = 0; j < 4; ++j) {
      const int row0 = m0 + wr * 64 + i * 16 + g * 4;
      const int col  = n0 + wc * 64 + j * 16 + r16;
#pragma unroll
      for (int e = 0; e < 4; ++e) {
        float v = acc[i][j][e];
        if constexpr (BF16OUT) ((unsigned short*)Cout)[(size_t)(row0 + e) * N + col] = f2bf(v);
        else                   ((float*)Cout)[(size_t)(row0 + e) * N + col] = v;
      }
    }
}

// ---------------- fallback GEMM (reg-staged, f32-or-bf16 inputs) ----------------
template<typename AT, typename WT, bool BF16OUT>
__global__ __launch_bounds__(256) void gemm_nt(const AT* __restrict__ A,
                                               const WT* __restrict__ W,
                                               void* __restrict__ Cout,
                                               int M, int N, int K) {
  __shared__ alignas(16) unsigned short sA[128 * 32];
  __shared__ alignas(16) unsigned short sB[128 * 32];
  const int tid  = threadIdx.x;
  const int lane = tid & 63;
  const int wave = tid >> 6;
  const int m0 = blockIdx.y * 128, n0 = blockIdx.x * 128;
  const int wr = wave >> 1, wc = wave & 1;
  const int r16 = lane & 15, g = lane >> 4;
  f32x4 acc[4][4] = {};

  for (int k0 = 0; k0 < K; k0 += 32) {
    __syncthreads();
    if constexpr (sizeof(AT) == 4) {
#pragma unroll
      for (int s = 0; s < 4; ++s) {
        const int slot = tid + s * 256;
        const int row = slot >> 3, c4 = slot & 7;
        const float4 v = *(const float4*)((const float*)A + (size_t)(m0 + row) * K + k0 + c4 * 4);
        ushort4 o; o.x = f2bf(v.x); o.y = f2bf(v.y); o.z = f2bf(v.z); o.w = f2bf(v.w);
        *(ushort4*)&sA[row * 32 + c4 * 4] = o;
      }
    } else {
#pragma unroll
      for (int s = 0; s < 2; ++s) {
        const int slot = tid + s * 256;
        const int row = slot >> 2, c8 = slot & 3;
        *(s16x8*)&sA[row * 32 + c8 * 8] =
            *(const s16x8*)((const unsigned short*)A + (size_t)(m0 + row) * K + k0 + c8 * 8);
      }
    }
    if constexpr (sizeof(WT) == 4) {
#pragma unroll
      for (int s = 0; s < 4; ++s) {
        const int slot = tid + s * 256;
        const int row = slot >> 3, c4 = slot & 7;
        const float4 v = *(const float4*)((const float*)W + (size_t)(n0 + row) * K + k0 + c4 * 4);
        ushort4 o; o.x = f2bf(v.x); o.y = f2bf(v.y); o.z = f2bf(v.z); o.w = f2bf(v.w);
        *(ushort4*)&sB[row * 32 + c4 * 4] = o;
      }
    } else {
#pragma unroll
      for (int s = 0; s < 2; ++s) {
        const int slot = tid + s * 256;
        const int row = slot >> 2, c8 = slot & 3;
        *(s16x8*)&sB[row * 32 + c8 * 8] =
            *(const s16x8*)((const unsigned short*)W + (size_t)(n0 + row) * K + k0 + c8 * 8);
      }
    }
    __syncthreads();

    s16x8 af[4], bfr[4];
#pragma unroll
    for (int f = 0; f < 4; ++f) {
      af[f]  = *(const s16x8*)&sA[(wr * 64 + f * 16 + r16) * 32 + g * 8];
      bfr[f] = *(const s16x8*)&sB[(wc * 64 + f * 16 + r16) * 32 + g * 8];
    }
#pragma unroll
    for (int i = 0; i < 4; ++i)
#pragma unroll
      for (int j = 0; j < 4; ++j)
        acc[i][j] = __builtin_amdgcn_mfma_f32_16x16x32_bf16(af[i], bfr[j], acc[i][j], 0, 0, 0);
  }

#pragma unroll
  for (int i = 0; i < 4; ++i)
#pragma unroll
    for (int j = 0; j < 4; ++j) {
      const int row0 = m0 + wr * 64 + i * 16 + g * 4;
      const int col  = n0 + wc * 64 + j * 16 + r16;
#pragma unroll
      for (int e = 0; e < 4; ++e) {
        float v = acc[i][j][e];
        if constexpr (BF16OUT) ((unsigned short*)Cout)[(size_t)(row0 + e) * N + col] = f2bf(v);
        else                   ((float*)Cout)[(size_t)(row0 + e) * N + col] = v;
      }
    }
}

// ================= chunked selective scan =================

__global__ __launch_bounds__(256) void scan_p1(const unsigned short* __restrict__ zxbc,
                                               const unsigned short* __restrict__ dtw,
                                               const float* __restrict__ dt_b,
                                               const float* __restrict__ conv_w,
                                               const float* __restrict__ conv_b,
                                               const float* __restrict__ A_log,
                                               float* __restrict__ Sws,
                                               float* __restrict__ Bws) {
  const int d = blockIdx.x * 256 + threadIdx.x;
  const int c = blockIdx.y;
  const int b = blockIdx.z;
  const int h = d >> 4, p = d & 15;

  const float bias = dt_b[d];
  const float cw0 = conv_w[d*4+0], cw1 = conv_w[d*4+1], cw2 = conv_w[d*4+2], cw3 = conv_w[d*4+3];
  const float cb  = conv_b[d];
  float nacK[16];
#pragma unroll
  for (int n = 0; n < 16; ++n) nacK[n] = -fexp(A_log[d * SN + n]) * LOG2E;

  const unsigned short* rp  = zxbc + (size_t)b * L_ * NZ;
  const unsigned short* pdt = dtw  + (size_t)b * L_ * DI + d;
  const int ox = DI + ((h >> 2) << 4) + p;
  const int oB = DI + DXB + ((h >> 2) << 4);
  const int t0 = c * TCH;

  float xm1 = (t0 >= 1) ? bf2f(rp[(size_t)(t0-1)*NZ + ox]) : 0.f;
  float xm2 = (t0 >= 2) ? bf2f(rp[(size_t)(t0-2)*NZ + ox]) : 0.f;
  float xm3 = (t0 >= 3) ? bf2f(rp[(size_t)(t0-3)*NZ + ox]) : 0.f;

  float S = 0.f;
  float Bacc[16] = {};

  for (int t = t0; t < t0 + TCH; ++t) {
    const size_t row = (size_t)t * NZ;
    const float xv = bf2f(rp[row + ox]);
    const s16x8 bv0 = *(const s16x8*)&rp[row + oB];
    const s16x8 bv1 = *(const s16x8*)&rp[row + oB + 8];
    const float dr = bf2f(pdt[(size_t)t * DI]);

    const float cs  = cb + cw0*xm3 + cw1*xm2 + cw2*xm1 + cw3*xv;
    const float xa  = fsilu(cs);
    const float dtv = fsoftplus(dr + bias);
    S += dtv;
    const float g = dtv * xa;
#pragma unroll
    for (int n = 0; n < 16; ++n) {
      const float Bn = bf2f((unsigned short)(n < 8 ? bv0[n] : bv1[n-8]));
      const float a  = __builtin_amdgcn_exp2f(dtv * nacK[n]);
      Bacc[n] = Bacc[n] * a + g * Bn;
    }
    xm3 = xm2; xm2 = xm1; xm1 = xv;
  }

  Sws[((size_t)b * CCH + c) * DI + d] = S;
  float* Bo = Bws + (((size_t)b * CCH + c) * DI + d) * 16;
#pragma unroll
  for (int q = 0; q < 4; ++q)
    *(float4*)&Bo[q*4] = make_float4(Bacc[q*4], Bacc[q*4+1], Bacc[q*4+2], Bacc[q*4+3]);
}

__global__ __launch_bounds__(256) void scan_comb(const float* __restrict__ Sws,
                                                 float* __restrict__ Bws,
                                                 const float* __restrict__ A_log) {
  const int idx = blockIdx.x * 256 + threadIdx.x;
  const int b = blockIdx.y;
  const int d = idx >> 4;
  const float nacK = -fexp(A_log[idx]) * LOG2E;
  float hcur = 0.f;
  for (int c = 0; c < CCH; ++c) {
    const size_t cell = ((size_t)b * CCH + c) * DI;
    const size_t bi = (cell + d) * 16 + (idx & 15);
    const float S  = Sws[cell + d];
    const float Ba = Bws[bi];
    Bws[bi] = hcur;
    hcur = hcur * __builtin_amdgcn_exp2f(S * nacK) + Ba;
  }
}

__global__ __launch_bounds__(256) void scan_p2(const unsigned short* __restrict__ zxbc,
                                               const unsigned short* __restrict__ dtw,
                                               const float* __restrict__ dt_b,
                                               const float* __restrict__ conv_w,
                                               const float* __restrict__ conv_b,
                                               const float* __restrict__ A_log,
                                               const float* __restrict__ Dv,
                                               const float* __restrict__ Hin,
                                               unsigned short* __restrict__ yf) {
  const int d = blockIdx.x * 256 + threadIdx.x;
  const int c = blockIdx.y;
  const int b = blockIdx.z;
  const int h = d >> 4, p = d & 15;

  const float bias = dt_b[d];
  const float Dd   = Dv[d];
  const float cw0 = conv_w[d*4+0], cw1 = conv_w[d*4+1], cw2 = conv_w[d*4+2], cw3 = conv_w[d*4+3];
  const float cb  = conv_b[d];
  float nacK[16];
#pragma unroll
  for (int n = 0; n < 16; ++n) nacK[n] = -fexp(A_log[d * SN + n]) * LOG2E;

  float hst[16];
  const float* Hi = Hin + (((size_t)b * CCH + c) * DI + d) * 16;
#pragma unroll
  for (int q = 0; q < 4; ++q) {
    const float4 v = *(const float4*)&Hi[q*4];
    hst[q*4] = v.x; hst[q*4+1] = v.y; hst[q*4+2] = v.z; hst[q*4+3] = v.w;
  }

  const unsigned short* rp  = zxbc + (size_t)b * L_ * NZ;
  const unsigned short* pdt = dtw  + (size_t)b * L_ * DI + d;
  unsigned short* py = yf + (size_t)b * L_ * DI + d;
  const int oz = d;
  const int ox = DI + ((h >> 2) << 4) + p;
  const int oB = DI + DXB + ((h >> 2) << 4);
  const int oC = DI + 2*DXB + (h << 4);
  const int t0 = c * TCH;

  float xm1 = (t0 >= 1) ? bf2f(rp[(size_t)(t0-1)*NZ + ox]) : 0.f;
  float xm2 = (t0 >= 2) ? bf2f(rp[(size_t)(t0-2)*NZ + ox]) : 0.f;
  float xm3 = (t0 >= 3) ? bf2f(rp[(size_t)(t0-3)*NZ + ox]) : 0.f;

  for (int t = t0; t < t0 + TCH; ++t) {
    const size_t row = (size_t)t * NZ;
    const float xv = bf2f(rp[row + ox]);
    const float zv = bf2f(rp[row + oz]);
    const s16x8 bv0 = *(const s16x8*)&rp[row + oB];
    const s16x8 bv1 = *(const s16x8*)&rp[row + oB + 8];
    const s16x8 cv0 = *(const s16x8*)&rp[row + oC];
    const s16x8 cv1 = *(const s16x8*)&rp[row + oC + 8];
    const float dr = bf2f(pdt[(size_t)t * DI]);

    const float cs  = cb + cw0*xm3 + cw1*xm2 + cw2*xm1 + cw3*xv;
    const float xa  = fsilu(cs);
    const float dtv = fsoftplus(dr + bias);
    const float g = dtv * xa;
    float y = 0.f;
#pragma unroll
    for (int n = 0; n < 16; ++n) {
      const float Bn = bf2f((unsigned short)(n < 8 ? bv0[n] : bv1[n-8]));
      const float Cn = bf2f((unsigned short)(n < 8 ? cv0[n] : cv1[n-8]));
      const float a  = __builtin_amdgcn_exp2f(dtv * nacK[n]);
      hst[n] = hst[n] * a + g * Bn;
      y += hst[n] * Cn;
    }
    py[(size_t)t * DI] = f2bf((y + Dd * xa) * fsilu(zv));
    xm3 = xm2; xm2 = xm1; xm1 = xv;
  }
}

// ---------------- launch ----------------
extern "C" void kernel_launch(void* const* d_in, const int* in_sizes, int n_in,
                              void* d_out, int out_size, void* d_ws, size_t ws_size,
                              hipStream_t stream) {
  const float* hs     = (const float*)d_in[0];
  const float* w_in   = (const float*)d_in[1];
  const float* w_dti  = (const float*)d_in[2];
  const float* w_dtp  = (const float*)d_in[3];
  const float* dt_b   = (const float*)d_in[4];
  const float* conv_w = (const float*)d_in[5];
  const float* conv_b = (const float*)d_in[6];
  const float* A_log  = (const float*)d_in[7];
  const float* Dv     = (const float*)d_in[8];
  const float* w_out  = (const float*)d_in[9];
  float* out = (float*)d_out;

  char* ws = (char*)d_ws;
  size_t off = 0;
  auto take = [&](size_t bytes) -> void* {
    void* p = ws + off;
    off += (bytes + 255) & ~(size_t)255;
    return p;
  };
  // ---- shared intermediates (~170 MB) ----
  unsigned short* zxbc  = (unsigned short*)take((size_t)MT * NZ * 2);
  unsigned short* t1b   = (unsigned short*)take((size_t)MT * DTR * 2);
  unsigned short* dtraw = (unsigned short*)take((size_t)MT * DI * 2);
  unsigned short* yfb   = (unsigned short*)take((size_t)MT * DI * 2);
  float*          Sws   = (float*)take((size_t)B_ * CCH * DI * 4);
  float*          Bws   = (float*)take((size_t)B_ * CCH * DI * 16 * 4);

  // ---- bf16 operand copies for the fast path (~62 MB more) ----
  unsigned short* hsb   = (unsigned short*)take((size_t)MT * DM * 2);
  unsigned short* w1b   = (unsigned short*)take((size_t)NZ * DM * 2);   // later reused for w_out bf16
  unsigned short* wdtib = (unsigned short*)take((size_t)DTR * DM * 2);
  unsigned short* wdtpb = (unsigned short*)take((size_t)DI * DTR * 2);
  const bool fast = (off <= ws_size);

  auto cast = [&](const float* src, unsigned short* dst, size_t n) {
    int n4 = (int)(n / 4);
    int blocks = (n4 + 255) / 256;
    if (blocks > 2048) blocks = 2048;
    cast_kernel<<<dim3(blocks), dim3(256), 0, stream>>>((const float4*)src, (ushort4*)dst, n4);
  };

  if (fast) {
    cast(hs,    hsb,   (size_t)MT * DM);
    cast(w_in,  w1b,   (size_t)NZ * DM);
    cast(w_dti, wdtib, (size_t)DTR * DM);
    cast(w_dtp, wdtpb, (size_t)DI * DTR);
    // zxbc = hs @ in_proj_w.T   (4096 x 10240, K=2048) -> bf16 [256^2 8-phase]
    gemm8p<true><<<dim3((NZ / 256) * (MT / 256)), 512, 0, stream>>>(hsb, w1b, zxbc, MT, NZ, DM);
    // t1 = hs @ dt_in_proj_w.T  (4096 x 128, K=2048) -> bf16 (N=128 < 256 -> g16)
    gemm_g16<true><<<dim3(DTR / 128, MT / 128), 256, 0, stream>>>(hsb, wdtib, t1b, MT, DTR, DM);
    // dtraw = t1 @ dt_proj_w.T  (4096 x 4096, K=128) -> bf16 [256^2 8-phase, NT=2]
    gemm8p<true><<<dim3((DI / 256) * (MT / 256)), 512, 0, stream>>>(t1b, wdtpb, dtraw, MT, DI, DTR);
    // w1b dead now: cast w_out into its region
    cast(w_out, w1b, (size_t)DM * DI);
  } else {
    gemm_nt<float, float, true><<<dim3(NZ / 128, MT / 128), 256, 0, stream>>>(hs, w_in, zxbc, MT, NZ, DM);
    gemm_nt<float, float, true><<<dim3(DTR / 128, MT / 128), 256, 0, stream>>>(hs, w_dti, t1b, MT, DTR, DM);
    gemm_nt<unsigned short, float, true><<<dim3(DI / 128, MT / 128), 256, 0, stream>>>(t1b, w_dtp, dtraw, MT, DI, DTR);
  }

  // chunked selective scan (conv fused, recomputed in both passes)
  scan_p1  <<<dim3(DI/256, CCH, B_), 256, 0, stream>>>(zxbc, dtraw, dt_b, conv_w, conv_b, A_log, Sws, Bws);
  scan_comb<<<dim3(DI*SN/256, B_),  256, 0, stream>>>(Sws, Bws, A_log);
  scan_p2  <<<dim3(DI/256, CCH, B_), 256, 0, stream>>>(zxbc, dtraw, dt_b, conv_w, conv_b, A_log, Dv, Bws, yfb);

  // out = yf @ out_proj_w.T   (4096 x 2048, K=4096) -> f32 [256^2 8-phase]
  if (fast) {
    gemm8p<false><<<dim3((DM / 256) * (MT / 256)), 512, 0, stream>>>(yfb, w1b, out, MT, DM, DI);
  } else {
    gemm_nt<unsigned short, float, false><<<dim3(DM / 128, MT / 128), 256, 0, stream>>>(yfb, w_out, out, MT, DM, DI);
  }
}

// Round 8
// 589.307 us; speedup vs baseline: 3.9657x; 1.0491x over previous
//
#include <hip/hip_runtime.h>
#include <cstdint>
#include <cstddef>

// ---------------- problem constants ----------------
constexpr int B_  = 2;
constexpr int L_  = 2048;
constexpr int DM  = 2048;
constexpr int DI  = 4096;
constexpr int DXB = 1024;
constexpr int SN  = 16;     // state dim N
constexpr int DTR = 128;
constexpr int H_  = DI / SN;        // 256 heads
constexpr int NZ  = 2*DXB + 2*DI;   // 10240 (zxbc width)
constexpr int MT  = B_ * L_;        // 4096 rows
constexpr int CCH = 32;             // scan chunks
constexpr int TCH = L_ / CCH;       // 64 steps per chunk

constexpr float LOG2E = 1.4426950408889634f;
constexpr float LN2   = 0.6931471805599453f;

typedef __attribute__((ext_vector_type(4))) float f32x4;
typedef __attribute__((ext_vector_type(8))) short s16x8;

__device__ __forceinline__ unsigned short f2bf(float f) {
  union { float f; unsigned u; } v; v.f = f;
  unsigned r = v.u + 0x7fff + ((v.u >> 16) & 1);   // RNE
  return (unsigned short)(r >> 16);
}
__device__ __forceinline__ float bf2f(unsigned short u) {
  union { unsigned u; float f; } v; v.u = ((unsigned)u) << 16; return v.f;
}
__device__ __forceinline__ float fexp(float x)  { return __builtin_amdgcn_exp2f(x * LOG2E); }
__device__ __forceinline__ float fsilu(float x) { return x * __builtin_amdgcn_rcpf(1.f + fexp(-x)); }
__device__ __forceinline__ float fsoftplus(float x) {
  return (x > 20.f) ? x : __builtin_amdgcn_logf(1.f + fexp(x)) * LN2;
}

// ---------------- f32 -> bf16 cast ----------------
__global__ __launch_bounds__(256) void cast_kernel(const float4* __restrict__ in,
                                                   ushort4* __restrict__ out, int n4) {
  int stride = gridDim.x * blockDim.x;
  for (int i = blockIdx.x * blockDim.x + threadIdx.x; i < n4; i += stride) {
    float4 v = in[i];
    ushort4 o;
    o.x = f2bf(v.x); o.y = f2bf(v.y); o.z = f2bf(v.z); o.w = f2bf(v.w);
    out[i] = o;
  }
}

// ================= shared GEMM helpers (swizzle verified: 0 bank conflicts) =================
// Swizzle: read byte x ^= ((x>>7)&7)<<4 ; stage source slot sp = s ^ ((s>>3)&7).

__device__ __forceinline__ void stage_half(const unsigned short* __restrict__ G,
                                           int row0, int K, int k0,
                                           unsigned short* lh, int wave, int lane) {
#pragma unroll
  for (int r = 0; r < 2; ++r) {
    const int sbase = (2 * wave + r) * 64;               // wave-uniform 16B-slot base
    const int s  = sbase + lane;
    const int sp = s ^ ((s >> 3) & 7);                   // pre-swizzled source slot
    const unsigned short* g = G + (size_t)(row0 + (sp >> 3)) * K + k0 + (sp & 7) * 8;
    __builtin_amdgcn_global_load_lds((const __attribute__((address_space(1))) void*)g,
                                     (__attribute__((address_space(3))) void*)(lh + sbase * 8), 16, 0, 0);
  }
}

__device__ __forceinline__ s16x8 ldsrd(const unsigned short* half_, int row, int kk, int g) {
  int x = row * 128 + kk * 64 + g * 16;                  // linear byte in 128x64 half-tile
  x ^= (x >> 3) & 0x70;                                  // chunk ^= row&7 (involution)
  return *(const s16x8*)((const char*)half_ + x);
}

// ================= 256x256 8-phase GEMM (dtraw: grid 256 = 1 round) =================
template<bool BF16OUT>
__global__ __launch_bounds__(512, 2) void gemm8p(const unsigned short* __restrict__ A,
                                                 const unsigned short* __restrict__ W,
                                                 void* __restrict__ Cout,
                                                 int M, int N, int K) {
  __shared__ unsigned short lds[2][4][8192];
  const int tid = threadIdx.x, lane = tid & 63, wave = tid >> 6;
  const int wr = wave >> 2, wc = wave & 3;
  const int r16 = lane & 15, g = lane >> 4;

  const int ntx = N >> 8;
  const int nwg = gridDim.x;
  const int q8  = nwg >> 3;
  const int gid = ((nwg & 7) == 0) ? (int)(blockIdx.x & 7) * q8 + (int)(blockIdx.x >> 3)
                                   : (int)blockIdx.x;
  const int m0 = (gid / ntx) << 8, n0 = (gid % ntx) << 8;

  f32x4 acc[8][4] = {};
  const int NT = K >> 6;

  stage_half(A, m0,       K, 0, &lds[0][0][0], wave, lane);
  stage_half(A, m0 + 128, K, 0, &lds[0][1][0], wave, lane);
  stage_half(W, n0,       K, 0, &lds[0][2][0], wave, lane);
  stage_half(W, n0 + 128, K, 0, &lds[0][3][0], wave, lane);

  for (int kt = 0; kt < NT; ++kt) {
    const int p = kt & 1;
    const unsigned short* Ah = &lds[p][wr][0];
    const unsigned short* Bh = &lds[p][2 + (wc >> 1)][0];
    const int brow0 = (wc & 1) * 64;
    const int k0n = (kt + 1) << 6;
    const bool more = (kt + 1 < NT);

    s16x8 bf[4][2], af[2][2];

    // phase 0: stage A(kt+1); counted wait; B frags + quadrant 0
    if (more) { stage_half(A, m0, K, k0n, &lds[p ^ 1][0][0], wave, lane);
                stage_half(A, m0 + 128, K, k0n, &lds[p ^ 1][1][0], wave, lane); }
    if (more) asm volatile("s_waitcnt vmcnt(4)" ::: "memory");
    else      asm volatile("s_waitcnt vmcnt(0)" ::: "memory");
    asm volatile("s_barrier" ::: "memory");
#pragma unroll
    for (int j = 0; j < 4; ++j)
#pragma unroll
      for (int kk = 0; kk < 2; ++kk)
        bf[j][kk] = ldsrd(Bh, brow0 + j * 16 + r16, kk, g);
#pragma unroll
    for (int i2 = 0; i2 < 2; ++i2)
#pragma unroll
      for (int kk = 0; kk < 2; ++kk)
        af[i2][kk] = ldsrd(Ah, i2 * 16 + r16, kk, g);
    __builtin_amdgcn_s_setprio(1);
#pragma unroll
    for (int kk = 0; kk < 2; ++kk)
#pragma unroll
      for (int i2 = 0; i2 < 2; ++i2)
#pragma unroll
        for (int j = 0; j < 4; ++j)
          acc[i2][j] = __builtin_amdgcn_mfma_f32_16x16x32_bf16(af[i2][kk], bf[j][kk], acc[i2][j], 0, 0, 0);
    __builtin_amdgcn_s_setprio(0);
    __builtin_amdgcn_sched_barrier(0);
    asm volatile("s_barrier" ::: "memory");

    // phase 1: stage B(kt+1); quadrant 1
    if (more) { stage_half(W, n0, K, k0n, &lds[p ^ 1][2][0], wave, lane);
                stage_half(W, n0 + 128, K, k0n, &lds[p ^ 1][3][0], wave, lane); }
#pragma unroll
    for (int i2 = 0; i2 < 2; ++i2)
#pragma unroll
      for (int kk = 0; kk < 2; ++kk)
        af[i2][kk] = ldsrd(Ah, (2 + i2) * 16 + r16, kk, g);
    __builtin_amdgcn_s_setprio(1);
#pragma unroll
    for (int kk = 0; kk < 2; ++kk)
#pragma unroll
      for (int i2 = 0; i2 < 2; ++i2)
#pragma unroll
        for (int j = 0; j < 4; ++j)
          acc[2 + i2][j] = __builtin_amdgcn_mfma_f32_16x16x32_bf16(af[i2][kk], bf[j][kk], acc[2 + i2][j], 0, 0, 0);
    __builtin_amdgcn_s_setprio(0);
    __builtin_amdgcn_sched_barrier(0);
    asm volatile("s_barrier" ::: "memory");

    // phase 2: quadrant 2
#pragma unroll
    for (int i2 = 0; i2 < 2; ++i2)
#pragma unroll
      for (int kk = 0; kk < 2; ++kk)
        af[i2][kk] = ldsrd(Ah, (4 + i2) * 16 + r16, kk, g);
    __builtin_amdgcn_s_setprio(1);
#pragma unroll
    for (int kk = 0; kk < 2; ++kk)
#pragma unroll
      for (int i2 = 0; i2 < 2; ++i2)
#pragma unroll
        for (int j = 0; j < 4; ++j)
          acc[4 + i2][j] = __builtin_amdgcn_mfma_f32_16x16x32_bf16(af[i2][kk], bf[j][kk], acc[4 + i2][j], 0, 0, 0);
    __builtin_amdgcn_s_setprio(0);
    __builtin_amdgcn_sched_barrier(0);
    asm volatile("s_barrier" ::: "memory");

    // phase 3: quadrant 3
#pragma unroll
    for (int i2 = 0; i2 < 2; ++i2)
#pragma unroll
      for (int kk = 0; kk < 2; ++kk)
        af[i2][kk] = ldsrd(Ah, (6 + i2) * 16 + r16, kk, g);
    __builtin_amdgcn_s_setprio(1);
#pragma unroll
    for (int kk = 0; kk < 2; ++kk)
#pragma unroll
      for (int i2 = 0; i2 < 2; ++i2)
#pragma unroll
        for (int j = 0; j < 4; ++j)
          acc[6 + i2][j] = __builtin_amdgcn_mfma_f32_16x16x32_bf16(af[i2][kk], bf[j][kk], acc[6 + i2][j], 0, 0, 0);
    __builtin_amdgcn_s_setprio(0);
    __builtin_amdgcn_sched_barrier(0);
    asm volatile("s_barrier" ::: "memory");
  }

#pragma unroll
  for (int i = 0; i < 8; ++i)
#pragma unroll
    for (int j = 0; j < 4; ++j) {
      const int row0 = m0 + wr * 128 + i * 16 + g * 4;
      const int col  = n0 + wc * 64 + j * 16 + r16;
#pragma unroll
      for (int e = 0; e < 4; ++e) {
        float v = acc[i][j][e];
        if constexpr (BF16OUT) ((unsigned short*)Cout)[(size_t)(row0 + e) * N + col] = f2bf(v);
        else                   ((float*)Cout)[(size_t)(row0 + e) * N + col] = v;
      }
    }
}

// ================= 128x256 2-phase variant (in_proj: 1280 blk = 5 rounds; out_proj: 256 = 1) =================
template<bool BF16OUT>
__global__ __launch_bounds__(512, 2) void gemm8p_128(const unsigned short* __restrict__ A,
                                                     const unsigned short* __restrict__ W,
                                                     void* __restrict__ Cout,
                                                     int M, int N, int K) {
  __shared__ unsigned short lds[2][3][8192];             // [buf][A, B0, B1]
  const int tid = threadIdx.x, lane = tid & 63, wave = tid >> 6;
  const int wr = wave >> 2, wc = wave & 3;               // wr: M-half of 128 rows; wc: N-quarter
  const int r16 = lane & 15, g = lane >> 4;

  const int ntx = N >> 8;
  const int nwg = gridDim.x;
  const int q8  = nwg >> 3;
  const int gid = ((nwg & 7) == 0) ? (int)(blockIdx.x & 7) * q8 + (int)(blockIdx.x >> 3)
                                   : (int)blockIdx.x;
  const int m0 = (gid / ntx) << 7, n0 = (gid % ntx) << 8;

  f32x4 acc[4][4] = {};
  const int NT = K >> 6;

  // prologue: 6 loads/wave for K-tile 0
  stage_half(A, m0,       K, 0, &lds[0][0][0], wave, lane);
  stage_half(W, n0,       K, 0, &lds[0][1][0], wave, lane);
  stage_half(W, n0 + 128, K, 0, &lds[0][2][0], wave, lane);

  for (int kt = 0; kt < NT; ++kt) {
    const int p = kt & 1;
    const unsigned short* Ah = &lds[p][0][0];
    const unsigned short* Bh = &lds[p][1 + (wc >> 1)][0];
    const int brow0 = (wc & 1) * 64;
    const int k0n = (kt + 1) << 6;
    const bool more = (kt + 1 < NT);

    s16x8 bf[4][2], af[2][2];

    // ---------- phase 0: stage A(kt+1)+B0(kt+1); vmcnt(4); frags; 16 MFMA ----------
    if (more) { stage_half(A, m0, K, k0n, &lds[p ^ 1][0][0], wave, lane);
                stage_half(W, n0, K, k0n, &lds[p ^ 1][1][0], wave, lane); }
    if (more) asm volatile("s_waitcnt vmcnt(4)" ::: "memory");   // kt's 6 done; kt+1's 4 in flight
    else      asm volatile("s_waitcnt vmcnt(0)" ::: "memory");
    asm volatile("s_barrier" ::: "memory");
#pragma unroll
    for (int j = 0; j < 4; ++j)
#pragma unroll
      for (int kk = 0; kk < 2; ++kk)
        bf[j][kk] = ldsrd(Bh, brow0 + j * 16 + r16, kk, g);
#pragma unroll
    for (int i2 = 0; i2 < 2; ++i2)
#pragma unroll
      for (int kk = 0; kk < 2; ++kk)
        af[i2][kk] = ldsrd(Ah, wr * 64 + i2 * 16 + r16, kk, g);
    __builtin_amdgcn_s_setprio(1);
#pragma unroll
    for (int kk = 0; kk < 2; ++kk)
#pragma unroll
      for (int i2 = 0; i2 < 2; ++i2)
#pragma unroll
        for (int j = 0; j < 4; ++j)
          acc[i2][j] = __builtin_amdgcn_mfma_f32_16x16x32_bf16(af[i2][kk], bf[j][kk], acc[i2][j], 0, 0, 0);
    __builtin_amdgcn_s_setprio(0);
    __builtin_amdgcn_sched_barrier(0);
    asm volatile("s_barrier" ::: "memory");

    // ---------- phase 1: stage B1(kt+1); rows 2-3; 16 MFMA ----------
    if (more) stage_half(W, n0 + 128, K, k0n, &lds[p ^ 1][2][0], wave, lane);
#pragma unroll
    for (int i2 = 0; i2 < 2; ++i2)
#pragma unroll
      for (int kk = 0; kk < 2; ++kk)
        af[i2][kk] = ldsrd(Ah, wr * 64 + (2 + i2) * 16 + r16, kk, g);
    __builtin_amdgcn_s_setprio(1);
#pragma unroll
    for (int kk = 0; kk < 2; ++kk)
#pragma unroll
      for (int i2 = 0; i2 < 2; ++i2)
#pragma unroll
        for (int j = 0; j < 4; ++j)
          acc[2 + i2][j] = __builtin_amdgcn_mfma_f32_16x16x32_bf16(af[i2][kk], bf[j][kk], acc[2 + i2][j], 0, 0, 0);
    __builtin_amdgcn_s_setprio(0);
    __builtin_amdgcn_sched_barrier(0);
    asm volatile("s_barrier" ::: "memory");
  }

  // epilogue: wave covers rows m0+wr*64.., cols n0+wc*64..
#pragma unroll
  for (int i = 0; i < 4; ++i)
#pragma unroll
    for (int j = 0; j < 4; ++j) {
      const int row0 = m0 + wr * 64 + i * 16 + g * 4;
      const int col  = n0 + wc * 64 + j * 16 + r16;
#pragma unroll
      for (int e = 0; e < 4; ++e) {
        float v = acc[i][j][e];
        if constexpr (BF16OUT) ((unsigned short*)Cout)[(size_t)(row0 + e) * N + col] = f2bf(v);
        else                   ((float*)Cout)[(size_t)(row0 + e) * N + col] = v;
      }
    }
}

// ---------------- split-K 128x128 GEMM (dt1): f32 partials per K-chunk ----------------
__global__ __launch_bounds__(256) void gemm_g16_sk(const unsigned short* __restrict__ A,
                                                   const unsigned short* __restrict__ W,
                                                   float* __restrict__ Pout,
                                                   int M, int N, int K, int KC) {
  __shared__ alignas(16) unsigned short sA[128 * 32];
  __shared__ alignas(16) unsigned short sB[128 * 32];
  const int tid  = threadIdx.x;
  const int lane = tid & 63;
  const int wave = tid >> 6;
  const int m0 = blockIdx.y * 128, n0 = blockIdx.x * 128;
  const int z  = blockIdx.z;
  const int wr = wave >> 1, wc = wave & 1;
  const int r16 = lane & 15, g = lane >> 4;
  f32x4 acc[4][4] = {};

  for (int k0 = z * KC; k0 < z * KC + KC; k0 += 32) {
    __syncthreads();
#pragma unroll
    for (int it = 0; it < 2; ++it) {
      const int base = wave * 128 + it * 64;
      const int slot = base + lane;
      const int r = slot >> 2, c8 = slot & 3;
      const unsigned short* ga = A + (size_t)(m0 + r) * K + k0 + c8 * 8;
      const unsigned short* gb = W + (size_t)(n0 + r) * K + k0 + c8 * 8;
      __builtin_amdgcn_global_load_lds((const __attribute__((address_space(1))) void*)ga,
                                       (__attribute__((address_space(3))) void*)(sA + base * 8), 16, 0, 0);
      __builtin_amdgcn_global_load_lds((const __attribute__((address_space(1))) void*)gb,
                                       (__attribute__((address_space(3))) void*)(sB + base * 8), 16, 0, 0);
    }
    __syncthreads();

    s16x8 af[4], bfr[4];
#pragma unroll
    for (int f = 0; f < 4; ++f) {
      af[f]  = *(const s16x8*)&sA[(wr * 64 + f * 16 + r16) * 32 + g * 8];
      bfr[f] = *(const s16x8*)&sB[(wc * 64 + f * 16 + r16) * 32 + g * 8];
    }
#pragma unroll
    for (int i = 0; i < 4; ++i)
#pragma unroll
      for (int j = 0; j < 4; ++j)
        acc[i][j] = __builtin_amdgcn_mfma_f32_16x16x32_bf16(af[i], bfr[j], acc[i][j], 0, 0, 0);
  }

  float* P = Pout + (size_t)z * M * N;
#pragma unroll
  for (int i = 0; i < 4; ++i)
#pragma unroll
    for (int j = 0; j < 4; ++j) {
      const int row0 = m0 + wr * 64 + i * 16 + g * 4;
      const int col  = n0 + wc * 64 + j * 16 + r16;
#pragma unroll
      for (int e = 0; e < 4; ++e)
        P[(size_t)(row0 + e) * N + col] = acc[i][j][e];
    }
}

// ---- reduce 8 f32 partials -> bf16 ----
__global__ __launch_bounds__(256) void reduce_cast8(const float4* __restrict__ P,
                                                    ushort4* __restrict__ outb, int n4) {
  const int i = blockIdx.x * 256 + threadIdx.x;
  if (i >= n4) return;
  float4 s = P[i];
#pragma unroll
  for (int z = 1; z < 8; ++z) {
    const float4 v = P[i + z * n4];
    s.x += v.x; s.y += v.y; s.z += v.z; s.w += v.w;
  }
  ushort4 o; o.x = f2bf(s.x); o.y = f2bf(s.y); o.z = f2bf(s.z); o.w = f2bf(s.w);
  outb[i] = o;
}

// ---------------- fallback GEMM (reg-staged, f32-or-bf16 inputs) ----------------
template<typename AT, typename WT, bool BF16OUT>
__global__ __launch_bounds__(256) void gemm_nt(const AT* __restrict__ A,
                                               const WT* __restrict__ W,
                                               void* __restrict__ Cout,
                                               int M, int N, int K) {
  __shared__ alignas(16) unsigned short sA[128 * 32];
  __shared__ alignas(16) unsigned short sB[128 * 32];
  const int tid  = threadIdx.x;
  const int lane = tid & 63;
  const int wave = tid >> 6;
  const int m0 = blockIdx.y * 128, n0 = blockIdx.x * 128;
  const int wr = wave >> 1, wc = wave & 1;
  const int r16 = lane & 15, g = lane >> 4;
  f32x4 acc[4][4] = {};

  for (int k0 = 0; k0 < K; k0 += 32) {
    __syncthreads();
    if constexpr (sizeof(AT) == 4) {
#pragma unroll
      for (int s = 0; s < 4; ++s) {
        const int slot = tid + s * 256;
        const int row = slot >> 3, c4 = slot & 7;
        const float4 v = *(const float4*)((const float*)A + (size_t)(m0 + row) * K + k0 + c4 * 4);
        ushort4 o; o.x = f2bf(v.x); o.y = f2bf(v.y); o.z = f2bf(v.z); o.w = f2bf(v.w);
        *(ushort4*)&sA[row * 32 + c4 * 4] = o;
      }
    } else {
#pragma unroll
      for (int s = 0; s < 2; ++s) {
        const int slot = tid + s * 256;
        const int row = slot >> 2, c8 = slot & 3;
        *(s16x8*)&sA[row * 32 + c8 * 8] =
            *(const s16x8*)((const unsigned short*)A + (size_t)(m0 + row) * K + k0 + c8 * 8);
      }
    }
    if constexpr (sizeof(WT) == 4) {
#pragma unroll
      for (int s = 0; s < 4; ++s) {
        const int slot = tid + s * 256;
        const int row = slot >> 3, c4 = slot & 7;
        const float4 v = *(const float4*)((const float*)W + (size_t)(n0 + row) * K + k0 + c4 * 4);
        ushort4 o; o.x = f2bf(v.x); o.y = f2bf(v.y); o.z = f2bf(v.z); o.w = f2bf(v.w);
        *(ushort4*)&sB[row * 32 + c4 * 4] = o;
      }
    } else {
#pragma unroll
      for (int s = 0; s < 2; ++s) {
        const int slot = tid + s * 256;
        const int row = slot >> 2, c8 = slot & 3;
        *(s16x8*)&sB[row * 32 + c8 * 8] =
            *(const s16x8*)((const unsigned short*)W + (size_t)(n0 + row) * K + k0 + c8 * 8);
      }
    }
    __syncthreads();

    s16x8 af[4], bfr[4];
#pragma unroll
    for (int f = 0; f < 4; ++f) {
      af[f]  = *(const s16x8*)&sA[(wr * 64 + f * 16 + r16) * 32 + g * 8];
      bfr[f] = *(const s16x8*)&sB[(wc * 64 + f * 16 + r16) * 32 + g * 8];
    }
#pragma unroll
    for (int i = 0; i < 4; ++i)
#pragma unroll
      for (int j = 0; j < 4; ++j)
        acc[i][j] = __builtin_amdgcn_mfma_f32_16x16x32_bf16(af[i], bfr[j], acc[i][j], 0, 0, 0);
  }

#pragma unroll
  for (int i = 0; i < 4; ++i)
#pragma unroll
    for (int j = 0; j < 4; ++j) {
      const int row0 = m0 + wr * 64 + i * 16 + g * 4;
      const int col  = n0 + wc * 64 + j * 16 + r16;
#pragma unroll
      for (int e = 0; e < 4; ++e) {
        float v = acc[i][j][e];
        if constexpr (BF16OUT) ((unsigned short*)Cout)[(size_t)(row0 + e) * N + col] = f2bf(v);
        else                   ((float*)Cout)[(size_t)(row0 + e) * N + col] = v;
      }
    }
}

// ================= chunked selective scan =================

__global__ __launch_bounds__(256) void scan_p1(const unsigned short* __restrict__ zxbc,
                                               const unsigned short* __restrict__ dtw,
                                               const float* __restrict__ dt_b,
                                               const float* __restrict__ conv_w,
                                               const float* __restrict__ conv_b,
                                               const float* __restrict__ A_log,
                                               float* __restrict__ Sws,
                                               float* __restrict__ Bws) {
  const int d = blockIdx.x * 256 + threadIdx.x;
  const int c = blockIdx.y;
  const int b = blockIdx.z;
  const int h = d >> 4, p = d & 15;

  const float bias = dt_b[d];
  const float cw0 = conv_w[d*4+0], cw1 = conv_w[d*4+1], cw2 = conv_w[d*4+2], cw3 = conv_w[d*4+3];
  const float cb  = conv_b[d];
  float nacK[16];
#pragma unroll
  for (int n = 0; n < 16; ++n) nacK[n] = -fexp(A_log[d * SN + n]) * LOG2E;

  const unsigned short* rp  = zxbc + (size_t)b * L_ * NZ;
  const unsigned short* pdt = dtw  + (size_t)b * L_ * DI + d;
  const int ox = DI + ((h >> 2) << 4) + p;
  const int oB = DI + DXB + ((h >> 2) << 4);
  const int t0 = c * TCH;

  float xm1 = (t0 >= 1) ? bf2f(rp[(size_t)(t0-1)*NZ + ox]) : 0.f;
  float xm2 = (t0 >= 2) ? bf2f(rp[(size_t)(t0-2)*NZ + ox]) : 0.f;
  float xm3 = (t0 >= 3) ? bf2f(rp[(size_t)(t0-3)*NZ + ox]) : 0.f;

  float S = 0.f;
  float Bacc[16] = {};

  for (int t = t0; t < t0 + TCH; ++t) {
    const size_t row = (size_t)t * NZ;
    const float xv = bf2f(rp[row + ox]);
    const s16x8 bv0 = *(const s16x8*)&rp[row + oB];
    const s16x8 bv1 = *(const s16x8*)&rp[row + oB + 8];
    const float dr = bf2f(pdt[(size_t)t * DI]);

    const float cs  = cb + cw0*xm3 + cw1*xm2 + cw2*xm1 + cw3*xv;
    const float xa  = fsilu(cs);
    const float dtv = fsoftplus(dr + bias);
    S += dtv;
    const float g = dtv * xa;
#pragma unroll
    for (int n = 0; n < 16; ++n) {
      const float Bn = bf2f((unsigned short)(n < 8 ? bv0[n] : bv1[n-8]));
      const float a  = __builtin_amdgcn_exp2f(dtv * nacK[n]);
      Bacc[n] = Bacc[n] * a + g * Bn;
    }
    xm3 = xm2; xm2 = xm1; xm1 = xv;
  }

  Sws[((size_t)b * CCH + c) * DI + d] = S;
  float* Bo = Bws + (((size_t)b * CCH + c) * DI + d) * 16;
#pragma unroll
  for (int q = 0; q < 4; ++q)
    *(float4*)&Bo[q*4] = make_float4(Bacc[q*4], Bacc[q*4+1], Bacc[q*4+2], Bacc[q*4+3]);
}

__global__ __launch_bounds__(256) void scan_comb(const float* __restrict__ Sws,
                                                 float* __restrict__ Bws,
                                                 const float* __restrict__ A_log) {
  const int idx = blockIdx.x * 256 + threadIdx.x;
  const int b = blockIdx.y;
  const int d = idx >> 4;
  const float nacK = -fexp(A_log[idx]) * LOG2E;
  float hcur = 0.f;
  for (int c = 0; c < CCH; ++c) {
    const size_t cell = ((size_t)b * CCH + c) * DI;
    const size_t bi = (cell + d) * 16 + (idx & 15);
    const float S  = Sws[cell + d];
    const float Ba = Bws[bi];
    Bws[bi] = hcur;
    hcur = hcur * __builtin_amdgcn_exp2f(S * nacK) + Ba;
  }
}

__global__ __launch_bounds__(256) void scan_p2(const unsigned short* __restrict__ zxbc,
                                               const unsigned short* __restrict__ dtw,
                                               const float* __restrict__ dt_b,
                                               const float* __restrict__ conv_w,
                                               const float* __restrict__ conv_b,
                                               const float* __restrict__ A_log,
                                               const float* __restrict__ Dv,
                                               const float* __restrict__ Hin,
                                               unsigned short* __restrict__ yf) {
  const int d = blockIdx.x * 256 + threadIdx.x;
  const int c = blockIdx.y;
  const int b = blockIdx.z;
  const int h = d >> 4, p = d & 15;

  const float bias = dt_b[d];
  const float Dd   = Dv[d];
  const float cw0 = conv_w[d*4+0], cw1 = conv_w[d*4+1], cw2 = conv_w[d*4+2], cw3 = conv_w[d*4+3];
  const float cb  = conv_b[d];
  float nacK[16];
#pragma unroll
  for (int n = 0; n < 16; ++n) nacK[n] = -fexp(A_log[d * SN + n]) * LOG2E;

  float hst[16];
  const float* Hi = Hin + (((size_t)b * CCH + c) * DI + d) * 16;
#pragma unroll
  for (int q = 0; q < 4; ++q) {
    const float4 v = *(const float4*)&Hi[q*4];
    hst[q*4] = v.x; hst[q*4+1] = v.y; hst[q*4+2] = v.z; hst[q*4+3] = v.w;
  }

  const unsigned short* rp  = zxbc + (size_t)b * L_ * NZ;
  const unsigned short* pdt = dtw  + (size_t)b * L_ * DI + d;
  unsigned short* py = yf + (size_t)b * L_ * DI + d;
  const int oz = d;
  const int ox = DI + ((h >> 2) << 4) + p;
  const int oB = DI + DXB + ((h >> 2) << 4);
  const int oC = DI + 2*DXB + (h << 4);
  const int t0 = c * TCH;

  float xm1 = (t0 >= 1) ? bf2f(rp[(size_t)(t0-1)*NZ + ox]) : 0.f;
  float xm2 = (t0 >= 2) ? bf2f(rp[(size_t)(t0-2)*NZ + ox]) : 0.f;
  float xm3 = (t0 >= 3) ? bf2f(rp[(size_t)(t0-3)*NZ + ox]) : 0.f;

  for (int t = t0; t < t0 + TCH; ++t) {
    const size_t row = (size_t)t * NZ;
    const float xv = bf2f(rp[row + ox]);
    const float zv = bf2f(rp[row + oz]);
    const s16x8 bv0 = *(const s16x8*)&rp[row + oB];
    const s16x8 bv1 = *(const s16x8*)&rp[row + oB + 8];
    const s16x8 cv0 = *(const s16x8*)&rp[row + oC];
    const s16x8 cv1 = *(const s16x8*)&rp[row + oC + 8];
    const float dr = bf2f(pdt[(size_t)t * DI]);

    const float cs  = cb + cw0*xm3 + cw1*xm2 + cw2*xm1 + cw3*xv;
    const float xa  = fsilu(cs);
    const float dtv = fsoftplus(dr + bias);
    const float g = dtv * xa;
    float y = 0.f;
#pragma unroll
    for (int n = 0; n < 16; ++n) {
      const float Bn = bf2f((unsigned short)(n < 8 ? bv0[n] : bv1[n-8]));
      const float Cn = bf2f((unsigned short)(n < 8 ? cv0[n] : cv1[n-8]));
      const float a  = __builtin_amdgcn_exp2f(dtv * nacK[n]);
      hst[n] = hst[n] * a + g * Bn;
      y += hst[n] * Cn;
    }
    py[(size_t)t * DI] = f2bf((y + Dd * xa) * fsilu(zv));
    xm3 = xm2; xm2 = xm1; xm1 = xv;
  }
}

// ---------------- launch ----------------
extern "C" void kernel_launch(void* const* d_in, const int* in_sizes, int n_in,
                              void* d_out, int out_size, void* d_ws, size_t ws_size,
                              hipStream_t stream) {
  const float* hs     = (const float*)d_in[0];
  const float* w_in   = (const float*)d_in[1];
  const float* w_dti  = (const float*)d_in[2];
  const float* w_dtp  = (const float*)d_in[3];
  const float* dt_b   = (const float*)d_in[4];
  const float* conv_w = (const float*)d_in[5];
  const float* conv_b = (const float*)d_in[6];
  const float* A_log  = (const float*)d_in[7];
  const float* Dv     = (const float*)d_in[8];
  const float* w_out  = (const float*)d_in[9];
  float* out = (float*)d_out;

  char* ws = (char*)d_ws;
  size_t off = 0;
  auto take = [&](size_t bytes) -> void* {
    void* p = ws + off;
    off += (bytes + 255) & ~(size_t)255;
    return p;
  };
  // ---- shared intermediates ----
  unsigned short* zxbc  = (unsigned short*)take((size_t)MT * NZ * 2);
  unsigned short* t1b   = (unsigned short*)take((size_t)MT * DTR * 2);
  unsigned short* dtraw = (unsigned short*)take((size_t)MT * DI * 2);
  unsigned short* yfb   = (unsigned short*)take((size_t)MT * DI * 2);
  float*          Sws   = (float*)take((size_t)B_ * CCH * DI * 4);
  float*          Bws   = (float*)take((size_t)B_ * CCH * DI * 16 * 4);

  // ---- bf16 operand copies + split-K partials (fast path) ----
  unsigned short* hsb   = (unsigned short*)take((size_t)MT * DM * 2);
  unsigned short* w1b   = (unsigned short*)take((size_t)NZ * DM * 2);   // later reused for w_out bf16
  unsigned short* wdtib = (unsigned short*)take((size_t)DTR * DM * 2);
  unsigned short* wdtpb = (unsigned short*)take((size_t)DI * DTR * 2);
  float*          t1p   = (float*)take((size_t)8 * MT * DTR * 4);       // 16.8 MB partials
  const bool fast = (off <= ws_size);

  auto cast = [&](const float* src, unsigned short* dst, size_t n) {
    int n4 = (int)(n / 4);
    int blocks = (n4 + 255) / 256;
    if (blocks > 2048) blocks = 2048;
    cast_kernel<<<dim3(blocks), dim3(256), 0, stream>>>((const float4*)src, (ushort4*)dst, n4);
  };

  if (fast) {
    cast(hs,    hsb,   (size_t)MT * DM);
    cast(w_in,  w1b,   (size_t)NZ * DM);
    cast(w_dti, wdtib, (size_t)DTR * DM);
    cast(w_dtp, wdtpb, (size_t)DI * DTR);
    // zxbc = hs @ in_proj_w.T   (4096 x 10240, K=2048) [128x256 tiles: 1280 blk = 5 rounds]
    gemm8p_128<true><<<dim3((MT / 128) * (NZ / 256)), 512, 0, stream>>>(hsb, w1b, zxbc, MT, NZ, DM);
    // t1 = hs @ dt_in_proj_w.T  (4096 x 128, K=2048) [split-K x8 -> f32 partials -> bf16]
    gemm_g16_sk<<<dim3(DTR / 128, MT / 128, 8), 256, 0, stream>>>(hsb, wdtib, t1p, MT, DTR, DM, DM / 8);
    reduce_cast8<<<dim3((MT * DTR / 4 + 255) / 256), 256, 0, stream>>>((const float4*)t1p, (ushort4*)t1b, MT * DTR / 4);
    // dtraw = t1 @ dt_proj_w.T  (4096 x 4096, K=128) [256^2: 256 blk = 1 round]
    gemm8p<true><<<dim3((DI / 256) * (MT / 256)), 512, 0, stream>>>(t1b, wdtpb, dtraw, MT, DI, DTR);
    // w1b dead now: cast w_out into its region
    cast(w_out, w1b, (size_t)DM * DI);
  } else {
    gemm_nt<float, float, true><<<dim3(NZ / 128, MT / 128), 256, 0, stream>>>(hs, w_in, zxbc, MT, NZ, DM);
    gemm_nt<float, float, true><<<dim3(DTR / 128, MT / 128), 256, 0, stream>>>(hs, w_dti, t1b, MT, DTR, DM);
    gemm_nt<unsigned short, float, true><<<dim3(DI / 128, MT / 128), 256, 0, stream>>>(t1b, w_dtp, dtraw, MT, DI, DTR);
  }

  // chunked selective scan (conv fused, recomputed in both passes)
  scan_p1  <<<dim3(DI/256, CCH, B_), 256, 0, stream>>>(zxbc, dtraw, dt_b, conv_w, conv_b, A_log, Sws, Bws);
  scan_comb<<<dim3(DI*SN/256, B_),  256, 0, stream>>>(Sws, Bws, A_log);
  scan_p2  <<<dim3(DI/256, CCH, B_), 256, 0, stream>>>(zxbc, dtraw, dt_b, conv_w, conv_b, A_log, Dv, Bws, yfb);

  // out = yf @ out_proj_w.T   (4096 x 2048, K=4096) [128x256 tiles: 256 blk = 1 round]
  if (fast) {
    gemm8p_128<false><<<dim3((MT / 128) * (DM / 256)), 512, 0, stream>>>(yfb, w1b, out, MT, DM, DI);
  } else {
    gemm_nt<unsigned short, float, false><<<dim3(DM / 128, MT / 128), 256, 0, stream>>>(yfb, w_out, out, MT, DM, DI);
  }
}

// Round 9
// 571.390 us; speedup vs baseline: 4.0900x; 1.0314x over previous
//
#include <hip/hip_runtime.h>
#include <cstdint>
#include <cstddef>

// ---------------- problem constants ----------------
constexpr int B_  = 2;
constexpr int L_  = 2048;
constexpr int DM  = 2048;
constexpr int DI  = 4096;
constexpr int DXB = 1024;
constexpr int SN  = 16;     // state dim N
constexpr int DTR = 128;
constexpr int H_  = DI / SN;        // 256 heads
constexpr int NZ  = 2*DXB + 2*DI;   // 10240 (zxbc width)
constexpr int MT  = B_ * L_;        // 4096 rows
constexpr int CCH = 32;             // scan chunks
constexpr int TCH = L_ / CCH;       // 64 steps per chunk

constexpr float LOG2E = 1.4426950408889634f;
constexpr float LN2   = 0.6931471805599453f;

typedef __attribute__((ext_vector_type(4))) float f32x4;
typedef __attribute__((ext_vector_type(8))) short s16x8;

__device__ __forceinline__ unsigned short f2bf(float f) {
  union { float f; unsigned u; } v; v.f = f;
  unsigned r = v.u + 0x7fff + ((v.u >> 16) & 1);   // RNE
  return (unsigned short)(r >> 16);
}
__device__ __forceinline__ float bf2f(unsigned short u) {
  union { unsigned u; float f; } v; v.u = ((unsigned)u) << 16; return v.f;
}
__device__ __forceinline__ float fexp(float x)  { return __builtin_amdgcn_exp2f(x * LOG2E); }
__device__ __forceinline__ float fsilu(float x) { return x * __builtin_amdgcn_rcpf(1.f + fexp(-x)); }
__device__ __forceinline__ float fsoftplus(float x) {
  return (x > 20.f) ? x : __builtin_amdgcn_logf(1.f + fexp(x)) * LN2;
}

// ---------------- f32 -> bf16 cast ----------------
__global__ __launch_bounds__(256) void cast_kernel(const float4* __restrict__ in,
                                                   ushort4* __restrict__ out, int n4) {
  int stride = gridDim.x * blockDim.x;
  for (int i = blockIdx.x * blockDim.x + threadIdx.x; i < n4; i += stride) {
    float4 v = in[i];
    ushort4 o;
    o.x = f2bf(v.x); o.y = f2bf(v.y); o.z = f2bf(v.z); o.w = f2bf(v.w);
    out[i] = o;
  }
}

// ================= shared GEMM helpers (swizzle verified: 0 bank conflicts) =================
// Swizzle: read byte x ^= ((x>>7)&7)<<4 ; stage source slot sp = s ^ ((s>>3)&7).

__device__ __forceinline__ void stage_half(const unsigned short* __restrict__ G,
                                           int row0, int K, int k0,
                                           unsigned short* lh, int wave, int lane) {
#pragma unroll
  for (int r = 0; r < 2; ++r) {
    const int sbase = (2 * wave + r) * 64;               // wave-uniform 16B-slot base
    const int s  = sbase + lane;
    const int sp = s ^ ((s >> 3) & 7);                   // pre-swizzled source slot
    const unsigned short* g = G + (size_t)(row0 + (sp >> 3)) * K + k0 + (sp & 7) * 8;
    __builtin_amdgcn_global_load_lds((const __attribute__((address_space(1))) void*)g,
                                     (__attribute__((address_space(3))) void*)(lh + sbase * 8), 16, 0, 0);
  }
}

__device__ __forceinline__ s16x8 ldsrd(const unsigned short* half_, int row, int kk, int g) {
  int x = row * 128 + kk * 64 + g * 16;                  // linear byte in 128x64 half-tile
  x ^= (x >> 3) & 0x70;                                  // chunk ^= row&7 (involution)
  return *(const s16x8*)((const char*)half_ + x);
}

// ================= 256x256 8-phase GEMM (with optional split-K via blockIdx.y) =================
// K = row stride of A/W; KL = K-length this block reduces (koff = blockIdx.y * KL).
// gridDim.y > 1 => write f32 partials at ((float*)Cout) + z*M*N.
template<bool BF16OUT>
__global__ __launch_bounds__(512, 2) void gemm8p(const unsigned short* __restrict__ A,
                                                 const unsigned short* __restrict__ W,
                                                 void* __restrict__ Cout,
                                                 int M, int N, int K, int KL) {
  __shared__ unsigned short lds[2][4][8192];
  const int tid = threadIdx.x, lane = tid & 63, wave = tid >> 6;
  const int wr = wave >> 2, wc = wave & 3;
  const int r16 = lane & 15, g = lane >> 4;

  const int ntx = N >> 8;
  const int nwg = gridDim.x;
  const int q8  = nwg >> 3;
  const int gid = ((nwg & 7) == 0) ? (int)(blockIdx.x & 7) * q8 + (int)(blockIdx.x >> 3)
                                   : (int)blockIdx.x;
  const int m0 = (gid / ntx) << 8, n0 = (gid % ntx) << 8;
  const int z  = blockIdx.y;
  const int koff = z * KL;

  f32x4 acc[8][4] = {};
  const int NT = KL >> 6;

  stage_half(A, m0,       K, koff, &lds[0][0][0], wave, lane);
  stage_half(A, m0 + 128, K, koff, &lds[0][1][0], wave, lane);
  stage_half(W, n0,       K, koff, &lds[0][2][0], wave, lane);
  stage_half(W, n0 + 128, K, koff, &lds[0][3][0], wave, lane);

  for (int kt = 0; kt < NT; ++kt) {
    const int p = kt & 1;
    const unsigned short* Ah = &lds[p][wr][0];
    const unsigned short* Bh = &lds[p][2 + (wc >> 1)][0];
    const int brow0 = (wc & 1) * 64;
    const int k0n = koff + ((kt + 1) << 6);
    const bool more = (kt + 1 < NT);

    s16x8 bf[4][2], af[2][2];

    // phase 0: stage A(kt+1); counted wait; B frags + quadrant 0
    if (more) { stage_half(A, m0, K, k0n, &lds[p ^ 1][0][0], wave, lane);
                stage_half(A, m0 + 128, K, k0n, &lds[p ^ 1][1][0], wave, lane); }
    if (more) asm volatile("s_waitcnt vmcnt(4)" ::: "memory");
    else      asm volatile("s_waitcnt vmcnt(0)" ::: "memory");
    asm volatile("s_barrier" ::: "memory");
#pragma unroll
    for (int j = 0; j < 4; ++j)
#pragma unroll
      for (int kk = 0; kk < 2; ++kk)
        bf[j][kk] = ldsrd(Bh, brow0 + j * 16 + r16, kk, g);
#pragma unroll
    for (int i2 = 0; i2 < 2; ++i2)
#pragma unroll
      for (int kk = 0; kk < 2; ++kk)
        af[i2][kk] = ldsrd(Ah, i2 * 16 + r16, kk, g);
    __builtin_amdgcn_s_setprio(1);
#pragma unroll
    for (int kk = 0; kk < 2; ++kk)
#pragma unroll
      for (int i2 = 0; i2 < 2; ++i2)
#pragma unroll
        for (int j = 0; j < 4; ++j)
          acc[i2][j] = __builtin_amdgcn_mfma_f32_16x16x32_bf16(af[i2][kk], bf[j][kk], acc[i2][j], 0, 0, 0);
    __builtin_amdgcn_s_setprio(0);
    __builtin_amdgcn_sched_barrier(0);
    asm volatile("s_barrier" ::: "memory");

    // phase 1: stage B(kt+1); quadrant 1
    if (more) { stage_half(W, n0, K, k0n, &lds[p ^ 1][2][0], wave, lane);
                stage_half(W, n0 + 128, K, k0n, &lds[p ^ 1][3][0], wave, lane); }
#pragma unroll
    for (int i2 = 0; i2 < 2; ++i2)
#pragma unroll
      for (int kk = 0; kk < 2; ++kk)
        af[i2][kk] = ldsrd(Ah, (2 + i2) * 16 + r16, kk, g);
    __builtin_amdgcn_s_setprio(1);
#pragma unroll
    for (int kk = 0; kk < 2; ++kk)
#pragma unroll
      for (int i2 = 0; i2 < 2; ++i2)
#pragma unroll
        for (int j = 0; j < 4; ++j)
          acc[2 + i2][j] = __builtin_amdgcn_mfma_f32_16x16x32_bf16(af[i2][kk], bf[j][kk], acc[2 + i2][j], 0, 0, 0);
    __builtin_amdgcn_s_setprio(0);
    __builtin_amdgcn_sched_barrier(0);
    asm volatile("s_barrier" ::: "memory");

    // phase 2: quadrant 2
#pragma unroll
    for (int i2 = 0; i2 < 2; ++i2)
#pragma unroll
      for (int kk = 0; kk < 2; ++kk)
        af[i2][kk] = ldsrd(Ah, (4 + i2) * 16 + r16, kk, g);
    __builtin_amdgcn_s_setprio(1);
#pragma unroll
    for (int kk = 0; kk < 2; ++kk)
#pragma unroll
      for (int i2 = 0; i2 < 2; ++i2)
#pragma unroll
        for (int j = 0; j < 4; ++j)
          acc[4 + i2][j] = __builtin_amdgcn_mfma_f32_16x16x32_bf16(af[i2][kk], bf[j][kk], acc[4 + i2][j], 0, 0, 0);
    __builtin_amdgcn_s_setprio(0);
    __builtin_amdgcn_sched_barrier(0);
    asm volatile("s_barrier" ::: "memory");

    // phase 3: quadrant 3
#pragma unroll
    for (int i2 = 0; i2 < 2; ++i2)
#pragma unroll
      for (int kk = 0; kk < 2; ++kk)
        af[i2][kk] = ldsrd(Ah, (6 + i2) * 16 + r16, kk, g);
    __builtin_amdgcn_s_setprio(1);
#pragma unroll
    for (int kk = 0; kk < 2; ++kk)
#pragma unroll
      for (int i2 = 0; i2 < 2; ++i2)
#pragma unroll
        for (int j = 0; j < 4; ++j)
          acc[6 + i2][j] = __builtin_amdgcn_mfma_f32_16x16x32_bf16(af[i2][kk], bf[j][kk], acc[6 + i2][j], 0, 0, 0);
    __builtin_amdgcn_s_setprio(0);
    __builtin_amdgcn_sched_barrier(0);
    asm volatile("s_barrier" ::: "memory");
  }

  if (gridDim.y > 1) {
    float* P = (float*)Cout + (size_t)z * M * N;
#pragma unroll
    for (int i = 0; i < 8; ++i)
#pragma unroll
      for (int j = 0; j < 4; ++j) {
        const int row0 = m0 + wr * 128 + i * 16 + g * 4;
        const int col  = n0 + wc * 64 + j * 16 + r16;
#pragma unroll
        for (int e = 0; e < 4; ++e)
          P[(size_t)(row0 + e) * N + col] = acc[i][j][e];
      }
  } else {
#pragma unroll
    for (int i = 0; i < 8; ++i)
#pragma unroll
      for (int j = 0; j < 4; ++j) {
        const int row0 = m0 + wr * 128 + i * 16 + g * 4;
        const int col  = n0 + wc * 64 + j * 16 + r16;
#pragma unroll
        for (int e = 0; e < 4; ++e) {
          float v = acc[i][j][e];
          if constexpr (BF16OUT) ((unsigned short*)Cout)[(size_t)(row0 + e) * N + col] = f2bf(v);
          else                   ((float*)Cout)[(size_t)(row0 + e) * N + col] = v;
        }
      }
  }
}

// ---------------- split-K 128x128 GEMM (dt1): f32 partials per K-chunk ----------------
__global__ __launch_bounds__(256) void gemm_g16_sk(const unsigned short* __restrict__ A,
                                                   const unsigned short* __restrict__ W,
                                                   float* __restrict__ Pout,
                                                   int M, int N, int K, int KC) {
  __shared__ alignas(16) unsigned short sA[128 * 32];
  __shared__ alignas(16) unsigned short sB[128 * 32];
  const int tid  = threadIdx.x;
  const int lane = tid & 63;
  const int wave = tid >> 6;
  const int m0 = blockIdx.y * 128, n0 = blockIdx.x * 128;
  const int z  = blockIdx.z;
  const int wr = wave >> 1, wc = wave & 1;
  const int r16 = lane & 15, g = lane >> 4;
  f32x4 acc[4][4] = {};

  for (int k0 = z * KC; k0 < z * KC + KC; k0 += 32) {
    __syncthreads();
#pragma unroll
    for (int it = 0; it < 2; ++it) {
      const int base = wave * 128 + it * 64;
      const int slot = base + lane;
      const int r = slot >> 2, c8 = slot & 3;
      const unsigned short* ga = A + (size_t)(m0 + r) * K + k0 + c8 * 8;
      const unsigned short* gb = W + (size_t)(n0 + r) * K + k0 + c8 * 8;
      __builtin_amdgcn_global_load_lds((const __attribute__((address_space(1))) void*)ga,
                                       (__attribute__((address_space(3))) void*)(sA + base * 8), 16, 0, 0);
      __builtin_amdgcn_global_load_lds((const __attribute__((address_space(1))) void*)gb,
                                       (__attribute__((address_space(3))) void*)(sB + base * 8), 16, 0, 0);
    }
    __syncthreads();

    s16x8 af[4], bfr[4];
#pragma unroll
    for (int f = 0; f < 4; ++f) {
      af[f]  = *(const s16x8*)&sA[(wr * 64 + f * 16 + r16) * 32 + g * 8];
      bfr[f] = *(const s16x8*)&sB[(wc * 64 + f * 16 + r16) * 32 + g * 8];
    }
#pragma unroll
    for (int i = 0; i < 4; ++i)
#pragma unroll
      for (int j = 0; j < 4; ++j)
        acc[i][j] = __builtin_amdgcn_mfma_f32_16x16x32_bf16(af[i], bfr[j], acc[i][j], 0, 0, 0);
  }

  float* P = Pout + (size_t)z * M * N;
#pragma unroll
  for (int i = 0; i < 4; ++i)
#pragma unroll
    for (int j = 0; j < 4; ++j) {
      const int row0 = m0 + wr * 64 + i * 16 + g * 4;
      const int col  = n0 + wc * 64 + j * 16 + r16;
#pragma unroll
      for (int e = 0; e < 4; ++e)
        P[(size_t)(row0 + e) * N + col] = acc[i][j][e];
    }
}

// ---- reduce 8 f32 partials -> bf16 ----
__global__ __launch_bounds__(256) void reduce_cast8(const float4* __restrict__ P,
                                                    ushort4* __restrict__ outb, int n4) {
  const int i = blockIdx.x * 256 + threadIdx.x;
  if (i >= n4) return;
  float4 s = P[i];
#pragma unroll
  for (int z = 1; z < 8; ++z) {
    const float4 v = P[i + (size_t)z * n4];
    s.x += v.x; s.y += v.y; s.z += v.z; s.w += v.w;
  }
  ushort4 o; o.x = f2bf(s.x); o.y = f2bf(s.y); o.z = f2bf(s.z); o.w = f2bf(s.w);
  outb[i] = o;
}

// ---- reduce 2 f32 partials -> f32 ----
__global__ __launch_bounds__(256) void reduce_add2(const float4* __restrict__ P,
                                                   float4* __restrict__ outf, int n4) {
  const int i = blockIdx.x * 256 + threadIdx.x;
  if (i >= n4) return;
  float4 a = P[i];
  const float4 b = P[i + (size_t)n4];
  a.x += b.x; a.y += b.y; a.z += b.z; a.w += b.w;
  outf[i] = a;
}

// ---------------- fallback GEMM (reg-staged, f32-or-bf16 inputs) ----------------
template<typename AT, typename WT, bool BF16OUT>
__global__ __launch_bounds__(256) void gemm_nt(const AT* __restrict__ A,
                                               const WT* __restrict__ W,
                                               void* __restrict__ Cout,
                                               int M, int N, int K) {
  __shared__ alignas(16) unsigned short sA[128 * 32];
  __shared__ alignas(16) unsigned short sB[128 * 32];
  const int tid  = threadIdx.x;
  const int lane = tid & 63;
  const int wave = tid >> 6;
  const int m0 = blockIdx.y * 128, n0 = blockIdx.x * 128;
  const int wr = wave >> 1, wc = wave & 1;
  const int r16 = lane & 15, g = lane >> 4;
  f32x4 acc[4][4] = {};

  for (int k0 = 0; k0 < K; k0 += 32) {
    __syncthreads();
    if constexpr (sizeof(AT) == 4) {
#pragma unroll
      for (int s = 0; s < 4; ++s) {
        const int slot = tid + s * 256;
        const int row = slot >> 3, c4 = slot & 7;
        const float4 v = *(const float4*)((const float*)A + (size_t)(m0 + row) * K + k0 + c4 * 4);
        ushort4 o; o.x = f2bf(v.x); o.y = f2bf(v.y); o.z = f2bf(v.z); o.w = f2bf(v.w);
        *(ushort4*)&sA[row * 32 + c4 * 4] = o;
      }
    } else {
#pragma unroll
      for (int s = 0; s < 2; ++s) {
        const int slot = tid + s * 256;
        const int row = slot >> 2, c8 = slot & 3;
        *(s16x8*)&sA[row * 32 + c8 * 8] =
            *(const s16x8*)((const unsigned short*)A + (size_t)(m0 + row) * K + k0 + c8 * 8);
      }
    }
    if constexpr (sizeof(WT) == 4) {
#pragma unroll
      for (int s = 0; s < 4; ++s) {
        const int slot = tid + s * 256;
        const int row = slot >> 3, c4 = slot & 7;
        const float4 v = *(const float4*)((const float*)W + (size_t)(n0 + row) * K + k0 + c4 * 4);
        ushort4 o; o.x = f2bf(v.x); o.y = f2bf(v.y); o.z = f2bf(v.z); o.w = f2bf(v.w);
        *(ushort4*)&sB[row * 32 + c4 * 4] = o;
      }
    } else {
#pragma unroll
      for (int s = 0; s < 2; ++s) {
        const int slot = tid + s * 256;
        const int row = slot >> 2, c8 = slot & 3;
        *(s16x8*)&sB[row * 32 + c8 * 8] =
            *(const s16x8*)((const unsigned short*)W + (size_t)(n0 + row) * K + k0 + c8 * 8);
      }
    }
    __syncthreads();

    s16x8 af[4], bfr[4];
#pragma unroll
    for (int f = 0; f < 4; ++f) {
      af[f]  = *(const s16x8*)&sA[(wr * 64 + f * 16 + r16) * 32 + g * 8];
      bfr[f] = *(const s16x8*)&sB[(wc * 64 + f * 16 + r16) * 32 + g * 8];
    }
#pragma unroll
    for (int i = 0; i < 4; ++i)
#pragma unroll
      for (int j = 0; j < 4; ++j)
        acc[i][j] = __builtin_amdgcn_mfma_f32_16x16x32_bf16(af[i], bfr[j], acc[i][j], 0, 0, 0);
  }

#pragma unroll
  for (int i = 0; i < 4; ++i)
#pragma unroll
    for (int j = 0; j < 4; ++j) {
      const int row0 = m0 + wr * 64 + i * 16 + g * 4;
      const int col  = n0 + wc * 64 + j * 16 + r16;
#pragma unroll
      for (int e = 0; e < 4; ++e) {
        float v = acc[i][j][e];
        if constexpr (BF16OUT) ((unsigned short*)Cout)[(size_t)(row0 + e) * N + col] = f2bf(v);
        else                   ((float*)Cout)[(size_t)(row0 + e) * N + col] = v;
      }
    }
}

// ================= chunked selective scan =================

__global__ __launch_bounds__(256) void scan_p1(const unsigned short* __restrict__ zxbc,
                                               const unsigned short* __restrict__ dtw,
                                               const float* __restrict__ dt_b,
                                               const float* __restrict__ conv_w,
                                               const float* __restrict__ conv_b,
                                               const float* __restrict__ A_log,
                                               float* __restrict__ Sws,
                                               float* __restrict__ Bws) {
  const int d = blockIdx.x * 256 + threadIdx.x;
  const int c = blockIdx.y;
  const int b = blockIdx.z;
  const int h = d >> 4, p = d & 15;

  const float bias = dt_b[d];
  const float cw0 = conv_w[d*4+0], cw1 = conv_w[d*4+1], cw2 = conv_w[d*4+2], cw3 = conv_w[d*4+3];
  const float cb  = conv_b[d];
  float nacK[16];
#pragma unroll
  for (int n = 0; n < 16; ++n) nacK[n] = -fexp(A_log[d * SN + n]) * LOG2E;

  const unsigned short* rp  = zxbc + (size_t)b * L_ * NZ;
  const unsigned short* pdt = dtw  + (size_t)b * L_ * DI + d;
  const int ox = DI + ((h >> 2) << 4) + p;
  const int oB = DI + DXB + ((h >> 2) << 4);
  const int t0 = c * TCH;

  float xm1 = (t0 >= 1) ? bf2f(rp[(size_t)(t0-1)*NZ + ox]) : 0.f;
  float xm2 = (t0 >= 2) ? bf2f(rp[(size_t)(t0-2)*NZ + ox]) : 0.f;
  float xm3 = (t0 >= 3) ? bf2f(rp[(size_t)(t0-3)*NZ + ox]) : 0.f;

  float S = 0.f;
  float Bacc[16] = {};

  for (int t = t0; t < t0 + TCH; ++t) {
    const size_t row = (size_t)t * NZ;
    const float xv = bf2f(rp[row + ox]);
    const s16x8 bv0 = *(const s16x8*)&rp[row + oB];
    const s16x8 bv1 = *(const s16x8*)&rp[row + oB + 8];
    const float dr = bf2f(pdt[(size_t)t * DI]);

    const float cs  = cb + cw0*xm3 + cw1*xm2 + cw2*xm1 + cw3*xv;
    const float xa  = fsilu(cs);
    const float dtv = fsoftplus(dr + bias);
    S += dtv;
    const float g = dtv * xa;
#pragma unroll
    for (int n = 0; n < 16; ++n) {
      const float Bn = bf2f((unsigned short)(n < 8 ? bv0[n] : bv1[n-8]));
      const float a  = __builtin_amdgcn_exp2f(dtv * nacK[n]);
      Bacc[n] = Bacc[n] * a + g * Bn;
    }
    xm3 = xm2; xm2 = xm1; xm1 = xv;
  }

  Sws[((size_t)b * CCH + c) * DI + d] = S;
  float* Bo = Bws + (((size_t)b * CCH + c) * DI + d) * 16;
#pragma unroll
  for (int q = 0; q < 4; ++q)
    *(float4*)&Bo[q*4] = make_float4(Bacc[q*4], Bacc[q*4+1], Bacc[q*4+2], Bacc[q*4+3]);
}

__global__ __launch_bounds__(256) void scan_comb(const float* __restrict__ Sws,
                                                 float* __restrict__ Bws,
                                                 const float* __restrict__ A_log) {
  const int idx = blockIdx.x * 256 + threadIdx.x;
  const int b = blockIdx.y;
  const int d = idx >> 4;
  const float nacK = -fexp(A_log[idx]) * LOG2E;
  float hcur = 0.f;
  for (int c = 0; c < CCH; ++c) {
    const size_t cell = ((size_t)b * CCH + c) * DI;
    const size_t bi = (cell + d) * 16 + (idx & 15);
    const float S  = Sws[cell + d];
    const float Ba = Bws[bi];
    Bws[bi] = hcur;
    hcur = hcur * __builtin_amdgcn_exp2f(S * nacK) + Ba;
  }
}

__global__ __launch_bounds__(256) void scan_p2(const unsigned short* __restrict__ zxbc,
                                               const unsigned short* __restrict__ dtw,
                                               const float* __restrict__ dt_b,
                                               const float* __restrict__ conv_w,
                                               const float* __restrict__ conv_b,
                                               const float* __restrict__ A_log,
                                               const float* __restrict__ Dv,
                                               const float* __restrict__ Hin,
                                               unsigned short* __restrict__ yf) {
  const int d = blockIdx.x * 256 + threadIdx.x;
  const int c = blockIdx.y;
  const int b = blockIdx.z;
  const int h = d >> 4, p = d & 15;

  const float bias = dt_b[d];
  const float Dd   = Dv[d];
  const float cw0 = conv_w[d*4+0], cw1 = conv_w[d*4+1], cw2 = conv_w[d*4+2], cw3 = conv_w[d*4+3];
  const float cb  = conv_b[d];
  float nacK[16];
#pragma unroll
  for (int n = 0; n < 16; ++n) nacK[n] = -fexp(A_log[d * SN + n]) * LOG2E;

  float hst[16];
  const float* Hi = Hin + (((size_t)b * CCH + c) * DI + d) * 16;
#pragma unroll
  for (int q = 0; q < 4; ++q) {
    const float4 v = *(const float4*)&Hi[q*4];
    hst[q*4] = v.x; hst[q*4+1] = v.y; hst[q*4+2] = v.z; hst[q*4+3] = v.w;
  }

  const unsigned short* rp  = zxbc + (size_t)b * L_ * NZ;
  const unsigned short* pdt = dtw  + (size_t)b * L_ * DI + d;
  unsigned short* py = yf + (size_t)b * L_ * DI + d;
  const int oz = d;
  const int ox = DI + ((h >> 2) << 4) + p;
  const int oB = DI + DXB + ((h >> 2) << 4);
  const int oC = DI + 2*DXB + (h << 4);
  const int t0 = c * TCH;

  float xm1 = (t0 >= 1) ? bf2f(rp[(size_t)(t0-1)*NZ + ox]) : 0.f;
  float xm2 = (t0 >= 2) ? bf2f(rp[(size_t)(t0-2)*NZ + ox]) : 0.f;
  float xm3 = (t0 >= 3) ? bf2f(rp[(size_t)(t0-3)*NZ + ox]) : 0.f;

  for (int t = t0; t < t0 + TCH; ++t) {
    const size_t row = (size_t)t * NZ;
    const float xv = bf2f(rp[row + ox]);
    const float zv = bf2f(rp[row + oz]);
    const s16x8 bv0 = *(const s16x8*)&rp[row + oB];
    const s16x8 bv1 = *(const s16x8*)&rp[row + oB + 8];
    const s16x8 cv0 = *(const s16x8*)&rp[row + oC];
    const s16x8 cv1 = *(const s16x8*)&rp[row + oC + 8];
    const float dr = bf2f(pdt[(size_t)t * DI]);

    const float cs  = cb + cw0*xm3 + cw1*xm2 + cw2*xm1 + cw3*xv;
    const float xa  = fsilu(cs);
    const float dtv = fsoftplus(dr + bias);
    const float g = dtv * xa;
    float y = 0.f;
#pragma unroll
    for (int n = 0; n < 16; ++n) {
      const float Bn = bf2f((unsigned short)(n < 8 ? bv0[n] : bv1[n-8]));
      const float Cn = bf2f((unsigned short)(n < 8 ? cv0[n] : cv1[n-8]));
      const float a  = __builtin_amdgcn_exp2f(dtv * nacK[n]);
      hst[n] = hst[n] * a + g * Bn;
      y += hst[n] * Cn;
    }
    py[(size_t)t * DI] = f2bf((y + Dd * xa) * fsilu(zv));
    xm3 = xm2; xm2 = xm1; xm1 = xv;
  }
}

// ---------------- launch ----------------
extern "C" void kernel_launch(void* const* d_in, const int* in_sizes, int n_in,
                              void* d_out, int out_size, void* d_ws, size_t ws_size,
                              hipStream_t stream) {
  const float* hs     = (const float*)d_in[0];
  const float* w_in   = (const float*)d_in[1];
  const float* w_dti  = (const float*)d_in[2];
  const float* w_dtp  = (const float*)d_in[3];
  const float* dt_b   = (const float*)d_in[4];
  const float* conv_w = (const float*)d_in[5];
  const float* conv_b = (const float*)d_in[6];
  const float* A_log  = (const float*)d_in[7];
  const float* Dv     = (const float*)d_in[8];
  const float* w_out  = (const float*)d_in[9];
  float* out = (float*)d_out;

  char* ws = (char*)d_ws;
  size_t off = 0;
  auto take = [&](size_t bytes) -> void* {
    void* p = ws + off;
    off += (bytes + 255) & ~(size_t)255;
    return p;
  };
  // ---- shared intermediates ----
  unsigned short* zxbc  = (unsigned short*)take((size_t)MT * NZ * 2);   // 84 MB; reused as out_proj f32 partials (67 MB) after scan
  unsigned short* t1b   = (unsigned short*)take((size_t)MT * DTR * 2);
  unsigned short* dtraw = (unsigned short*)take((size_t)MT * DI * 2);
  unsigned short* yfb   = (unsigned short*)take((size_t)MT * DI * 2);
  float*          Sws   = (float*)take((size_t)B_ * CCH * DI * 4);
  float*          Bws   = (float*)take((size_t)B_ * CCH * DI * 16 * 4);

  // ---- bf16 operand copies + split-K partials (fast path) ----
  unsigned short* hsb   = (unsigned short*)take((size_t)MT * DM * 2);
  unsigned short* w1b   = (unsigned short*)take((size_t)NZ * DM * 2);   // later reused for w_out bf16
  unsigned short* wdtib = (unsigned short*)take((size_t)DTR * DM * 2);
  unsigned short* wdtpb = (unsigned short*)take((size_t)DI * DTR * 2);
  float*          t1p   = (float*)take((size_t)8 * MT * DTR * 4);       // 16.8 MB partials
  const bool fast = (off <= ws_size);

  auto cast = [&](const float* src, unsigned short* dst, size_t n) {
    int n4 = (int)(n / 4);
    int blocks = (n4 + 255) / 256;
    if (blocks > 2048) blocks = 2048;
    cast_kernel<<<dim3(blocks), dim3(256), 0, stream>>>((const float4*)src, (ushort4*)dst, n4);
  };

  if (fast) {
    cast(hs,    hsb,   (size_t)MT * DM);
    cast(w_in,  w1b,   (size_t)NZ * DM);
    cast(w_dti, wdtib, (size_t)DTR * DM);
    cast(w_dtp, wdtpb, (size_t)DI * DTR);
    // zxbc = hs @ in_proj_w.T   (4096 x 10240, K=2048) [256^2 8-phase, 640 blocks]
    gemm8p<true><<<dim3((NZ / 256) * (MT / 256), 1), 512, 0, stream>>>(hsb, w1b, zxbc, MT, NZ, DM, DM);
    // t1 = hs @ dt_in_proj_w.T  (4096 x 128, K=2048) [split-K x8 -> f32 partials -> bf16]
    gemm_g16_sk<<<dim3(DTR / 128, MT / 128, 8), 256, 0, stream>>>(hsb, wdtib, t1p, MT, DTR, DM, DM / 8);
    reduce_cast8<<<dim3((MT * DTR / 4 + 255) / 256), 256, 0, stream>>>((const float4*)t1p, (ushort4*)t1b, MT * DTR / 4);
    // dtraw = t1 @ dt_proj_w.T  (4096 x 4096, K=128) [256^2, 256 blocks = 1 round]
    gemm8p<true><<<dim3((DI / 256) * (MT / 256), 1), 512, 0, stream>>>(t1b, wdtpb, dtraw, MT, DI, DTR, DTR);
    // w1b dead now: cast w_out into its region
    cast(w_out, w1b, (size_t)DM * DI);
  } else {
    gemm_nt<float, float, true><<<dim3(NZ / 128, MT / 128), 256, 0, stream>>>(hs, w_in, zxbc, MT, NZ, DM);
    gemm_nt<float, float, true><<<dim3(DTR / 128, MT / 128), 256, 0, stream>>>(hs, w_dti, t1b, MT, DTR, DM);
    gemm_nt<unsigned short, float, true><<<dim3(DI / 128, MT / 128), 256, 0, stream>>>(t1b, w_dtp, dtraw, MT, DI, DTR);
  }

  // chunked selective scan (conv fused, recomputed in both passes)
  scan_p1  <<<dim3(DI/256, CCH, B_), 256, 0, stream>>>(zxbc, dtraw, dt_b, conv_w, conv_b, A_log, Sws, Bws);
  scan_comb<<<dim3(DI*SN/256, B_),  256, 0, stream>>>(Sws, Bws, A_log);
  scan_p2  <<<dim3(DI/256, CCH, B_), 256, 0, stream>>>(zxbc, dtraw, dt_b, conv_w, conv_b, A_log, Dv, Bws, yfb);

  // out = yf @ out_proj_w.T   (4096 x 2048, K=4096)
  if (fast) {
    // zxbc is dead after scan_p2: reuse its region for 2 x f32 partials (67 MB < 84 MB)
    float* outp = (float*)zxbc;
    gemm8p<false><<<dim3((DM / 256) * (MT / 256), 2), 512, 0, stream>>>(yfb, w1b, outp, MT, DM, DI, DI / 2);
    reduce_add2<<<dim3((MT * DM / 4 + 255) / 256), 256, 0, stream>>>((const float4*)outp, (float4*)out, MT * DM / 4);
  } else {
    gemm_nt<unsigned short, float, false><<<dim3(DM / 128, MT / 128), 256, 0, stream>>>(yfb, w_out, out, MT, DM, DI);
  }
}

// Round 10
// 566.270 us; speedup vs baseline: 4.1270x; 1.0090x over previous
//
#include <hip/hip_runtime.h>
#include <cstdint>
#include <cstddef>

// ---------------- problem constants ----------------
constexpr int B_  = 2;
constexpr int L_  = 2048;
constexpr int DM  = 2048;
constexpr int DI  = 4096;
constexpr int DXB = 1024;
constexpr int SN  = 16;     // state dim N
constexpr int DTR = 128;
constexpr int H_  = DI / SN;        // 256 heads
constexpr int NZ  = 2*DXB + 2*DI;   // 10240 (zxbc width)
constexpr int MT  = B_ * L_;        // 4096 rows
constexpr int CCH = 32;             // scan chunks
constexpr int TCH = L_ / CCH;       // 64 steps per chunk

constexpr float LOG2E = 1.4426950408889634f;
constexpr float LN2   = 0.6931471805599453f;

typedef __attribute__((ext_vector_type(4))) float f32x4;
typedef __attribute__((ext_vector_type(8))) short s16x8;

__device__ __forceinline__ unsigned short f2bf(float f) {
  union { float f; unsigned u; } v; v.f = f;
  unsigned r = v.u + 0x7fff + ((v.u >> 16) & 1);   // RNE
  return (unsigned short)(r >> 16);
}
__device__ __forceinline__ float bf2f(unsigned short u) {
  union { unsigned u; float f; } v; v.u = ((unsigned)u) << 16; return v.f;
}
__device__ __forceinline__ float fexp(float x)  { return __builtin_amdgcn_exp2f(x * LOG2E); }
__device__ __forceinline__ float fsilu(float x) { return x * __builtin_amdgcn_rcpf(1.f + fexp(-x)); }
__device__ __forceinline__ float fsoftplus(float x) {
  return (x > 20.f) ? x : __builtin_amdgcn_logf(1.f + fexp(x)) * LN2;
}

// ---------------- f32 -> bf16 cast ----------------
__global__ __launch_bounds__(256) void cast_kernel(const float4* __restrict__ in,
                                                   ushort4* __restrict__ out, int n4) {
  int stride = gridDim.x * blockDim.x;
  for (int i = blockIdx.x * blockDim.x + threadIdx.x; i < n4; i += stride) {
    float4 v = in[i];
    ushort4 o;
    o.x = f2bf(v.x); o.y = f2bf(v.y); o.z = f2bf(v.z); o.w = f2bf(v.w);
    out[i] = o;
  }
}

// ================= shared GEMM helpers (swizzle verified: 0 bank conflicts) =================
// Swizzle byte map: x ^= ((x>>7)&7)<<4 == row&7 folded into bits 4-6.
// Since row&7 == r16&7 for all fragments and bits 4-6 of the linear address are
// exactly kk*64+g*16 (no overlap with row*128), the read address reduces to
//   base(half) + r16*128 + ((kk*64+g*16) ^ ((r16&7)<<4)) + compile-time-imm
// i.e. per-lane-constant bases + immediate offsets (no per-access VALU).
// Stage source slot: sp = s ^ ((s>>3)&7) (same involution, row preserved).

__device__ __forceinline__ void stage_half(const unsigned short* __restrict__ G,
                                           int row0, int K, int k0,
                                           unsigned short* lh, int wave, int lane) {
#pragma unroll
  for (int r = 0; r < 2; ++r) {
    const int sbase = (2 * wave + r) * 64;               // wave-uniform 16B-slot base
    const int s  = sbase + lane;
    const int sp = s ^ ((s >> 3) & 7);                   // pre-swizzled source slot
    const unsigned short* g = G + (size_t)(row0 + (sp >> 3)) * K + k0 + (sp & 7) * 8;
    __builtin_amdgcn_global_load_lds((const __attribute__((address_space(1))) void*)g,
                                     (__attribute__((address_space(3))) void*)(lh + sbase * 8), 16, 0, 0);
  }
}

// ================= 256x256 8-phase GEMM, m201-ordered phases =================
// K = row stride of A/W; KL = K-length this block reduces (koff = blockIdx.y * KL).
// gridDim.y > 1 => write f32 partials at ((float*)Cout) + z*M*N.
template<bool BF16OUT>
__global__ __launch_bounds__(512, 2) void gemm8p(const unsigned short* __restrict__ A,
                                                 const unsigned short* __restrict__ W,
                                                 void* __restrict__ Cout,
                                                 int M, int N, int K, int KL) {
  __shared__ unsigned short lds[2][4][8192];
  const int tid = threadIdx.x, lane = tid & 63, wave = tid >> 6;
  const int wr = wave >> 2, wc = wave & 3;
  const int r16 = lane & 15, g = lane >> 4;

  const int ntx = N >> 8;
  const int nwg = gridDim.x;
  const int q8  = nwg >> 3;
  const int gid = ((nwg & 7) == 0) ? (int)(blockIdx.x & 7) * q8 + (int)(blockIdx.x >> 3)
                                   : (int)blockIdx.x;
  const int m0 = (gid / ntx) << 8, n0 = (gid % ntx) << 8;
  const int z  = blockIdx.y;
  const int koff = z * KL;

  // per-lane constant swizzled sub-offsets
  const int xr = (r16 & 7) << 4;
  const int o0 = (g * 16) ^ xr;            // kk = 0
  const int o1 = (64 + g * 16) ^ xr;       // kk = 1
  const int aroff = r16 * 128;                              // A-half row base
  const int broff = ((wc & 1) * 64 + r16) * 128;            // B row base (incl. 64-row split)

  f32x4 acc[8][4] = {};
  const int NT = KL >> 6;

  stage_half(A, m0,       K, koff, &lds[0][0][0], wave, lane);
  stage_half(A, m0 + 128, K, koff, &lds[0][1][0], wave, lane);
  stage_half(W, n0,       K, koff, &lds[0][2][0], wave, lane);
  stage_half(W, n0 + 128, K, koff, &lds[0][3][0], wave, lane);

  for (int kt = 0; kt < NT; ++kt) {
    const int p = kt & 1;
    const char* Ahb = (const char*)&lds[p][wr][0] + aroff;
    const char* Bhb = (const char*)&lds[p][2 + (wc >> 1)][0] + broff;
    const char* A0 = Ahb + o0, *A1 = Ahb + o1;
    const char* B0 = Bhb + o0, *B1 = Bhb + o1;
    const int k0n = koff + ((kt + 1) << 6);
    const bool more = (kt + 1 < NT);

    s16x8 bf[4][2], af[2][2];

    // ---------- phase 0: stage A(kt+1); counted vmcnt; barrier; B frags + q0 ----------
    if (more) { stage_half(A, m0, K, k0n, &lds[p ^ 1][0][0], wave, lane);
                stage_half(A, m0 + 128, K, k0n, &lds[p ^ 1][1][0], wave, lane); }
    if (more) asm volatile("s_waitcnt vmcnt(4)" ::: "memory");  // kt's 8 done; kt+1 A in flight
    else      asm volatile("s_waitcnt vmcnt(0)" ::: "memory");
    asm volatile("s_barrier" ::: "memory");
#pragma unroll
    for (int j = 0; j < 4; ++j) {
      bf[j][0] = *(const s16x8*)(B0 + j * 2048);
      bf[j][1] = *(const s16x8*)(B1 + j * 2048);
    }
#pragma unroll
    for (int i2 = 0; i2 < 2; ++i2) {
      af[i2][0] = *(const s16x8*)(A0 + i2 * 2048);
      af[i2][1] = *(const s16x8*)(A1 + i2 * 2048);
    }
    __builtin_amdgcn_s_setprio(1);
#pragma unroll
    for (int kk = 0; kk < 2; ++kk)
#pragma unroll
      for (int i2 = 0; i2 < 2; ++i2)
#pragma unroll
        for (int j = 0; j < 4; ++j)
          acc[i2][j] = __builtin_amdgcn_mfma_f32_16x16x32_bf16(af[i2][kk], bf[j][kk], acc[i2][j], 0, 0, 0);
    __builtin_amdgcn_s_setprio(0);
    __builtin_amdgcn_sched_barrier(0);
    asm volatile("s_barrier" ::: "memory");

    // ---------- phase 1: ds q1 first; stage B(kt+1); barrier; q1 ----------
#pragma unroll
    for (int i2 = 0; i2 < 2; ++i2) {
      af[i2][0] = *(const s16x8*)(A0 + (2 + i2) * 2048);
      af[i2][1] = *(const s16x8*)(A1 + (2 + i2) * 2048);
    }
    if (more) { stage_half(W, n0, K, k0n, &lds[p ^ 1][2][0], wave, lane);
                stage_half(W, n0 + 128, K, k0n, &lds[p ^ 1][3][0], wave, lane); }
    asm volatile("s_barrier" ::: "memory");
    __builtin_amdgcn_s_setprio(1);
#pragma unroll
    for (int kk = 0; kk < 2; ++kk)
#pragma unroll
      for (int i2 = 0; i2 < 2; ++i2)
#pragma unroll
        for (int j = 0; j < 4; ++j)
          acc[2 + i2][j] = __builtin_amdgcn_mfma_f32_16x16x32_bf16(af[i2][kk], bf[j][kk], acc[2 + i2][j], 0, 0, 0);
    __builtin_amdgcn_s_setprio(0);
    __builtin_amdgcn_sched_barrier(0);
    asm volatile("s_barrier" ::: "memory");

    // ---------- phase 2: ds q2 first; barrier; q2 ----------
#pragma unroll
    for (int i2 = 0; i2 < 2; ++i2) {
      af[i2][0] = *(const s16x8*)(A0 + (4 + i2) * 2048);
      af[i2][1] = *(const s16x8*)(A1 + (4 + i2) * 2048);
    }
    asm volatile("s_barrier" ::: "memory");
    __builtin_amdgcn_s_setprio(1);
#pragma unroll
    for (int kk = 0; kk < 2; ++kk)
#pragma unroll
      for (int i2 = 0; i2 < 2; ++i2)
#pragma unroll
        for (int j = 0; j < 4; ++j)
          acc[4 + i2][j] = __builtin_amdgcn_mfma_f32_16x16x32_bf16(af[i2][kk], bf[j][kk], acc[4 + i2][j], 0, 0, 0);
    __builtin_amdgcn_s_setprio(0);
    __builtin_amdgcn_sched_barrier(0);
    asm volatile("s_barrier" ::: "memory");

    // ---------- phase 3: ds q3 first; barrier; q3; trailing barrier ends tile ----------
#pragma unroll
    for (int i2 = 0; i2 < 2; ++i2) {
      af[i2][0] = *(const s16x8*)(A0 + (6 + i2) * 2048);
      af[i2][1] = *(const s16x8*)(A1 + (6 + i2) * 2048);
    }
    asm volatile("s_barrier" ::: "memory");
    __builtin_amdgcn_s_setprio(1);
#pragma unroll
    for (int kk = 0; kk < 2; ++kk)
#pragma unroll
      for (int i2 = 0; i2 < 2; ++i2)
#pragma unroll
        for (int j = 0; j < 4; ++j)
          acc[6 + i2][j] = __builtin_amdgcn_mfma_f32_16x16x32_bf16(af[i2][kk], bf[j][kk], acc[6 + i2][j], 0, 0, 0);
    __builtin_amdgcn_s_setprio(0);
    __builtin_amdgcn_sched_barrier(0);
    asm volatile("s_barrier" ::: "memory");
  }

  if (gridDim.y > 1) {
    float* P = (float*)Cout + (size_t)z * M * N;
#pragma unroll
    for (int i = 0; i < 8; ++i)
#pragma unroll
      for (int j = 0; j < 4; ++j) {
        const int row0 = m0 + wr * 128 + i * 16 + g * 4;
        const int col  = n0 + wc * 64 + j * 16 + r16;
#pragma unroll
        for (int e = 0; e < 4; ++e)
          P[(size_t)(row0 + e) * N + col] = acc[i][j][e];
      }
  } else {
#pragma unroll
    for (int i = 0; i < 8; ++i)
#pragma unroll
      for (int j = 0; j < 4; ++j) {
        const int row0 = m0 + wr * 128 + i * 16 + g * 4;
        const int col  = n0 + wc * 64 + j * 16 + r16;
#pragma unroll
        for (int e = 0; e < 4; ++e) {
          float v = acc[i][j][e];
          if constexpr (BF16OUT) ((unsigned short*)Cout)[(size_t)(row0 + e) * N + col] = f2bf(v);
          else                   ((float*)Cout)[(size_t)(row0 + e) * N + col] = v;
        }
      }
  }
}

// ---------------- split-K 128x128 GEMM (dt1): f32 partials per K-chunk ----------------
__global__ __launch_bounds__(256) void gemm_g16_sk(const unsigned short* __restrict__ A,
                                                   const unsigned short* __restrict__ W,
                                                   float* __restrict__ Pout,
                                                   int M, int N, int K, int KC) {
  __shared__ alignas(16) unsigned short sA[128 * 32];
  __shared__ alignas(16) unsigned short sB[128 * 32];
  const int tid  = threadIdx.x;
  const int lane = tid & 63;
  const int wave = tid >> 6;
  const int m0 = blockIdx.y * 128, n0 = blockIdx.x * 128;
  const int z  = blockIdx.z;
  const int wr = wave >> 1, wc = wave & 1;
  const int r16 = lane & 15, g = lane >> 4;
  f32x4 acc[4][4] = {};

  for (int k0 = z * KC; k0 < z * KC + KC; k0 += 32) {
    __syncthreads();
#pragma unroll
    for (int it = 0; it < 2; ++it) {
      const int base = wave * 128 + it * 64;
      const int slot = base + lane;
      const int r = slot >> 2, c8 = slot & 3;
      const unsigned short* ga = A + (size_t)(m0 + r) * K + k0 + c8 * 8;
      const unsigned short* gb = W + (size_t)(n0 + r) * K + k0 + c8 * 8;
      __builtin_amdgcn_global_load_lds((const __attribute__((address_space(1))) void*)ga,
                                       (__attribute__((address_space(3))) void*)(sA + base * 8), 16, 0, 0);
      __builtin_amdgcn_global_load_lds((const __attribute__((address_space(1))) void*)gb,
                                       (__attribute__((address_space(3))) void*)(sB + base * 8), 16, 0, 0);
    }
    __syncthreads();

    s16x8 af[4], bfr[4];
#pragma unroll
    for (int f = 0; f < 4; ++f) {
      af[f]  = *(const s16x8*)&sA[(wr * 64 + f * 16 + r16) * 32 + g * 8];
      bfr[f] = *(const s16x8*)&sB[(wc * 64 + f * 16 + r16) * 32 + g * 8];
    }
#pragma unroll
    for (int i = 0; i < 4; ++i)
#pragma unroll
      for (int j = 0; j < 4; ++j)
        acc[i][j] = __builtin_amdgcn_mfma_f32_16x16x32_bf16(af[i], bfr[j], acc[i][j], 0, 0, 0);
  }

  float* P = Pout + (size_t)z * M * N;
#pragma unroll
  for (int i = 0; i < 4; ++i)
#pragma unroll
    for (int j = 0; j < 4; ++j) {
      const int row0 = m0 + wr * 64 + i * 16 + g * 4;
      const int col  = n0 + wc * 64 + j * 16 + r16;
#pragma unroll
      for (int e = 0; e < 4; ++e)
        P[(size_t)(row0 + e) * N + col] = acc[i][j][e];
    }
}

// ---- reduce 8 f32 partials -> bf16 ----
__global__ __launch_bounds__(256) void reduce_cast8(const float4* __restrict__ P,
                                                    ushort4* __restrict__ outb, int n4) {
  const int i = blockIdx.x * 256 + threadIdx.x;
  if (i >= n4) return;
  float4 s = P[i];
#pragma unroll
  for (int z = 1; z < 8; ++z) {
    const float4 v = P[i + (size_t)z * n4];
    s.x += v.x; s.y += v.y; s.z += v.z; s.w += v.w;
  }
  ushort4 o; o.x = f2bf(s.x); o.y = f2bf(s.y); o.z = f2bf(s.z); o.w = f2bf(s.w);
  outb[i] = o;
}

// ---- reduce 2 f32 partials -> f32 ----
__global__ __launch_bounds__(256) void reduce_add2(const float4* __restrict__ P,
                                                   float4* __restrict__ outf, int n4) {
  const int i = blockIdx.x * 256 + threadIdx.x;
  if (i >= n4) return;
  float4 a = P[i];
  const float4 b = P[i + (size_t)n4];
  a.x += b.x; a.y += b.y; a.z += b.z; a.w += b.w;
  outf[i] = a;
}

// ---------------- fallback GEMM (reg-staged, f32-or-bf16 inputs) ----------------
template<typename AT, typename WT, bool BF16OUT>
__global__ __launch_bounds__(256) void gemm_nt(const AT* __restrict__ A,
                                               const WT* __restrict__ W,
                                               void* __restrict__ Cout,
                                               int M, int N, int K) {
  __shared__ alignas(16) unsigned short sA[128 * 32];
  __shared__ alignas(16) unsigned short sB[128 * 32];
  const int tid  = threadIdx.x;
  const int lane = tid & 63;
  const int wave = tid >> 6;
  const int m0 = blockIdx.y * 128, n0 = blockIdx.x * 128;
  const int wr = wave >> 1, wc = wave & 1;
  const int r16 = lane & 15, g = lane >> 4;
  f32x4 acc[4][4] = {};

  for (int k0 = 0; k0 < K; k0 += 32) {
    __syncthreads();
    if constexpr (sizeof(AT) == 4) {
#pragma unroll
      for (int s = 0; s < 4; ++s) {
        const int slot = tid + s * 256;
        const int row = slot >> 3, c4 = slot & 7;
        const float4 v = *(const float4*)((const float*)A + (size_t)(m0 + row) * K + k0 + c4 * 4);
        ushort4 o; o.x = f2bf(v.x); o.y = f2bf(v.y); o.z = f2bf(v.z); o.w = f2bf(v.w);
        *(ushort4*)&sA[row * 32 + c4 * 4] = o;
      }
    } else {
#pragma unroll
      for (int s = 0; s < 2; ++s) {
        const int slot = tid + s * 256;
        const int row = slot >> 2, c8 = slot & 3;
        *(s16x8*)&sA[row * 32 + c8 * 8] =
            *(const s16x8*)((const unsigned short*)A + (size_t)(m0 + row) * K + k0 + c8 * 8);
      }
    }
    if constexpr (sizeof(WT) == 4) {
#pragma unroll
      for (int s = 0; s < 4; ++s) {
        const int slot = tid + s * 256;
        const int row = slot >> 3, c4 = slot & 7;
        const float4 v = *(const float4*)((const float*)W + (size_t)(n0 + row) * K + k0 + c4 * 4);
        ushort4 o; o.x = f2bf(v.x); o.y = f2bf(v.y); o.z = f2bf(v.z); o.w = f2bf(v.w);
        *(ushort4*)&sB[row * 32 + c4 * 4] = o;
      }
    } else {
#pragma unroll
      for (int s = 0; s < 2; ++s) {
        const int slot = tid + s * 256;
        const int row = slot >> 2, c8 = slot & 3;
        *(s16x8*)&sB[row * 32 + c8 * 8] =
            *(const s16x8*)((const unsigned short*)W + (size_t)(n0 + row) * K + k0 + c8 * 8);
      }
    }
    __syncthreads();

    s16x8 af[4], bfr[4];
#pragma unroll
    for (int f = 0; f < 4; ++f) {
      af[f]  = *(const s16x8*)&sA[(wr * 64 + f * 16 + r16) * 32 + g * 8];
      bfr[f] = *(const s16x8*)&sB[(wc * 64 + f * 16 + r16) * 32 + g * 8];
    }
#pragma unroll
    for (int i = 0; i < 4; ++i)
#pragma unroll
      for (int j = 0; j < 4; ++j)
        acc[i][j] = __builtin_amdgcn_mfma_f32_16x16x32_bf16(af[i], bfr[j], acc[i][j], 0, 0, 0);
  }

#pragma unroll
  for (int i = 0; i < 4; ++i)
#pragma unroll
    for (int j = 0; j < 4; ++j) {
      const int row0 = m0 + wr * 64 + i * 16 + g * 4;
      const int col  = n0 + wc * 64 + j * 16 + r16;
#pragma unroll
      for (int e = 0; e < 4; ++e) {
        float v = acc[i][j][e];
        if constexpr (BF16OUT) ((unsigned short*)Cout)[(size_t)(row0 + e) * N + col] = f2bf(v);
        else                   ((float*)Cout)[(size_t)(row0 + e) * N + col] = v;
      }
    }
}

// ================= chunked selective scan =================

__global__ __launch_bounds__(256) void scan_p1(const unsigned short* __restrict__ zxbc,
                                               const unsigned short* __restrict__ dtw,
                                               const float* __restrict__ dt_b,
                                               const float* __restrict__ conv_w,
                                               const float* __restrict__ conv_b,
                                               const float* __restrict__ A_log,
                                               float* __restrict__ Sws,
                                               float* __restrict__ Bws) {
  const int d = blockIdx.x * 256 + threadIdx.x;
  const int c = blockIdx.y;
  const int b = blockIdx.z;
  const int h = d >> 4, p = d & 15;

  const float bias = dt_b[d];
  const float cw0 = conv_w[d*4+0], cw1 = conv_w[d*4+1], cw2 = conv_w[d*4+2], cw3 = conv_w[d*4+3];
  const float cb  = conv_b[d];
  float nacK[16];
#pragma unroll
  for (int n = 0; n < 16; ++n) nacK[n] = -fexp(A_log[d * SN + n]) * LOG2E;

  const unsigned short* rp  = zxbc + (size_t)b * L_ * NZ;
  const unsigned short* pdt = dtw  + (size_t)b * L_ * DI + d;
  const int ox = DI + ((h >> 2) << 4) + p;
  const int oB = DI + DXB + ((h >> 2) << 4);
  const int t0 = c * TCH;

  float xm1 = (t0 >= 1) ? bf2f(rp[(size_t)(t0-1)*NZ + ox]) : 0.f;
  float xm2 = (t0 >= 2) ? bf2f(rp[(size_t)(t0-2)*NZ + ox]) : 0.f;
  float xm3 = (t0 >= 3) ? bf2f(rp[(size_t)(t0-3)*NZ + ox]) : 0.f;

  float S = 0.f;
  float Bacc[16] = {};

  for (int t = t0; t < t0 + TCH; ++t) {
    const size_t row = (size_t)t * NZ;
    const float xv = bf2f(rp[row + ox]);
    const s16x8 bv0 = *(const s16x8*)&rp[row + oB];
    const s16x8 bv1 = *(const s16x8*)&rp[row + oB + 8];
    const float dr = bf2f(pdt[(size_t)t * DI]);

    const float cs  = cb + cw0*xm3 + cw1*xm2 + cw2*xm1 + cw3*xv;
    const float xa  = fsilu(cs);
    const float dtv = fsoftplus(dr + bias);
    S += dtv;
    const float g = dtv * xa;
#pragma unroll
    for (int n = 0; n < 16; ++n) {
      const float Bn = bf2f((unsigned short)(n < 8 ? bv0[n] : bv1[n-8]));
      const float a  = __builtin_amdgcn_exp2f(dtv * nacK[n]);
      Bacc[n] = Bacc[n] * a + g * Bn;
    }
    xm3 = xm2; xm2 = xm1; xm1 = xv;
  }

  Sws[((size_t)b * CCH + c) * DI + d] = S;
  float* Bo = Bws + (((size_t)b * CCH + c) * DI + d) * 16;
#pragma unroll
  for (int q = 0; q < 4; ++q)
    *(float4*)&Bo[q*4] = make_float4(Bacc[q*4], Bacc[q*4+1], Bacc[q*4+2], Bacc[q*4+3]);
}

__global__ __launch_bounds__(256) void scan_comb(const float* __restrict__ Sws,
                                                 float* __restrict__ Bws,
                                                 const float* __restrict__ A_log) {
  const int idx = blockIdx.x * 256 + threadIdx.x;
  const int b = blockIdx.y;
  const int d = idx >> 4;
  const float nacK = -fexp(A_log[idx]) * LOG2E;
  float hcur = 0.f;
  for (int c = 0; c < CCH; ++c) {
    const size_t cell = ((size_t)b * CCH + c) * DI;
    const size_t bi = (cell + d) * 16 + (idx & 15);
    const float S  = Sws[cell + d];
    const float Ba = Bws[bi];
    Bws[bi] = hcur;
    hcur = hcur * __builtin_amdgcn_exp2f(S * nacK) + Ba;
  }
}

__global__ __launch_bounds__(256) void scan_p2(const unsigned short* __restrict__ zxbc,
                                               const unsigned short* __restrict__ dtw,
                                               const float* __restrict__ dt_b,
                                               const float* __restrict__ conv_w,
                                               const float* __restrict__ conv_b,
                                               const float* __restrict__ A_log,
                                               const float* __restrict__ Dv,
                                               const float* __restrict__ Hin,
                                               unsigned short* __restrict__ yf) {
  const int d = blockIdx.x * 256 + threadIdx.x;
  const int c = blockIdx.y;
  const int b = blockIdx.z;
  const int h = d >> 4, p = d & 15;

  const float bias = dt_b[d];
  const float Dd   = Dv[d];
  const float cw0 = conv_w[d*4+0], cw1 = conv_w[d*4+1], cw2 = conv_w[d*4+2], cw3 = conv_w[d*4+3];
  const float cb  = conv_b[d];
  float nacK[16];
#pragma unroll
  for (int n = 0; n < 16; ++n) nacK[n] = -fexp(A_log[d * SN + n]) * LOG2E;

  float hst[16];
  const float* Hi = Hin + (((size_t)b * CCH + c) * DI + d) * 16;
#pragma unroll
  for (int q = 0; q < 4; ++q) {
    const float4 v = *(const float4*)&Hi[q*4];
    hst[q*4] = v.x; hst[q*4+1] = v.y; hst[q*4+2] = v.z; hst[q*4+3] = v.w;
  }

  const unsigned short* rp  = zxbc + (size_t)b * L_ * NZ;
  const unsigned short* pdt = dtw  + (size_t)b * L_ * DI + d;
  unsigned short* py = yf + (size_t)b * L_ * DI + d;
  const int oz = d;
  const int ox = DI + ((h >> 2) << 4) + p;
  const int oB = DI + DXB + ((h >> 2) << 4);
  const int oC = DI + 2*DXB + (h << 4);
  const int t0 = c * TCH;

  float xm1 = (t0 >= 1) ? bf2f(rp[(size_t)(t0-1)*NZ + ox]) : 0.f;
  float xm2 = (t0 >= 2) ? bf2f(rp[(size_t)(t0-2)*NZ + ox]) : 0.f;
  float xm3 = (t0 >= 3) ? bf2f(rp[(size_t)(t0-3)*NZ + ox]) : 0.f;

  for (int t = t0; t < t0 + TCH; ++t) {
    const size_t row = (size_t)t * NZ;
    const float xv = bf2f(rp[row + ox]);
    const float zv = bf2f(rp[row + oz]);
    const s16x8 bv0 = *(const s16x8*)&rp[row + oB];
    const s16x8 bv1 = *(const s16x8*)&rp[row + oB + 8];
    const s16x8 cv0 = *(const s16x8*)&rp[row + oC];
    const s16x8 cv1 = *(const s16x8*)&rp[row + oC + 8];
    const float dr = bf2f(pdt[(size_t)t * DI]);

    const float cs  = cb + cw0*xm3 + cw1*xm2 + cw2*xm1 + cw3*xv;
    const float xa  = fsilu(cs);
    const float dtv = fsoftplus(dr + bias);
    const float g = dtv * xa;
    float y = 0.f;
#pragma unroll
    for (int n = 0; n < 16; ++n) {
      const float Bn = bf2f((unsigned short)(n < 8 ? bv0[n] : bv1[n-8]));
      const float Cn = bf2f((unsigned short)(n < 8 ? cv0[n] : cv1[n-8]));
      const float a  = __builtin_amdgcn_exp2f(dtv * nacK[n]);
      hst[n] = hst[n] * a + g * Bn;
      y += hst[n] * Cn;
    }
    py[(size_t)t * DI] = f2bf((y + Dd * xa) * fsilu(zv));
    xm3 = xm2; xm2 = xm1; xm1 = xv;
  }
}

// ---------------- launch ----------------
extern "C" void kernel_launch(void* const* d_in, const int* in_sizes, int n_in,
                              void* d_out, int out_size, void* d_ws, size_t ws_size,
                              hipStream_t stream) {
  const float* hs     = (const float*)d_in[0];
  const float* w_in   = (const float*)d_in[1];
  const float* w_dti  = (const float*)d_in[2];
  const float* w_dtp  = (const float*)d_in[3];
  const float* dt_b   = (const float*)d_in[4];
  const float* conv_w = (const float*)d_in[5];
  const float* conv_b = (const float*)d_in[6];
  const float* A_log  = (const float*)d_in[7];
  const float* Dv     = (const float*)d_in[8];
  const float* w_out  = (const float*)d_in[9];
  float* out = (float*)d_out;

  char* ws = (char*)d_ws;
  size_t off = 0;
  auto take = [&](size_t bytes) -> void* {
    void* p = ws + off;
    off += (bytes + 255) & ~(size_t)255;
    return p;
  };
  // ---- shared intermediates ----
  unsigned short* zxbc  = (unsigned short*)take((size_t)MT * NZ * 2);   // 84 MB; reused as out_proj f32 partials after scan
  unsigned short* t1b   = (unsigned short*)take((size_t)MT * DTR * 2);
  unsigned short* dtraw = (unsigned short*)take((size_t)MT * DI * 2);
  unsigned short* yfb   = (unsigned short*)take((size_t)MT * DI * 2);
  float*          Sws   = (float*)take((size_t)B_ * CCH * DI * 4);
  float*          Bws   = (float*)take((size_t)B_ * CCH * DI * 16 * 4);

  // ---- bf16 operand copies + split-K partials (fast path) ----
  unsigned short* hsb   = (unsigned short*)take((size_t)MT * DM * 2);
  unsigned short* w1b   = (unsigned short*)take((size_t)NZ * DM * 2);   // later reused for w_out bf16
  unsigned short* wdtib = (unsigned short*)take((size_t)DTR * DM * 2);
  unsigned short* wdtpb = (unsigned short*)take((size_t)DI * DTR * 2);
  float*          t1p   = (float*)take((size_t)8 * MT * DTR * 4);       // 16.8 MB partials
  const bool fast = (off <= ws_size);

  auto cast = [&](const float* src, unsigned short* dst, size_t n) {
    int n4 = (int)(n / 4);
    int blocks = (n4 + 255) / 256;
    if (blocks > 2048) blocks = 2048;
    cast_kernel<<<dim3(blocks), dim3(256), 0, stream>>>((const float4*)src, (ushort4*)dst, n4);
  };

  if (fast) {
    cast(hs,    hsb,   (size_t)MT * DM);
    cast(w_in,  w1b,   (size_t)NZ * DM);
    cast(w_dti, wdtib, (size_t)DTR * DM);
    cast(w_dtp, wdtpb, (size_t)DI * DTR);
    // zxbc = hs @ in_proj_w.T   (4096 x 10240, K=2048) [256^2 8-phase]
    gemm8p<true><<<dim3((NZ / 256) * (MT / 256), 1), 512, 0, stream>>>(hsb, w1b, zxbc, MT, NZ, DM, DM);
    // t1 = hs @ dt_in_proj_w.T  (4096 x 128, K=2048) [split-K x8 -> f32 partials -> bf16]
    gemm_g16_sk<<<dim3(DTR / 128, MT / 128, 8), 256, 0, stream>>>(hsb, wdtib, t1p, MT, DTR, DM, DM / 8);
    reduce_cast8<<<dim3((MT * DTR / 4 + 255) / 256), 256, 0, stream>>>((const float4*)t1p, (ushort4*)t1b, MT * DTR / 4);
    // dtraw = t1 @ dt_proj_w.T  (4096 x 4096, K=128) [256^2, 256 blocks = 1 round]
    gemm8p<true><<<dim3((DI / 256) * (MT / 256), 1), 512, 0, stream>>>(t1b, wdtpb, dtraw, MT, DI, DTR, DTR);
    // w1b dead now: cast w_out into its region
    cast(w_out, w1b, (size_t)DM * DI);
  } else {
    gemm_nt<float, float, true><<<dim3(NZ / 128, MT / 128), 256, 0, stream>>>(hs, w_in, zxbc, MT, NZ, DM);
    gemm_nt<float, float, true><<<dim3(DTR / 128, MT / 128), 256, 0, stream>>>(hs, w_dti, t1b, MT, DTR, DM);
    gemm_nt<unsigned short, float, true><<<dim3(DI / 128, MT / 128), 256, 0, stream>>>(t1b, w_dtp, dtraw, MT, DI, DTR);
  }

  // chunked selective scan (conv fused, recomputed in both passes)
  scan_p1  <<<dim3(DI/256, CCH, B_), 256, 0, stream>>>(zxbc, dtraw, dt_b, conv_w, conv_b, A_log, Sws, Bws);
  scan_comb<<<dim3(DI*SN/256, B_),  256, 0, stream>>>(Sws, Bws, A_log);
  scan_p2  <<<dim3(DI/256, CCH, B_), 256, 0, stream>>>(zxbc, dtraw, dt_b, conv_w, conv_b, A_log, Dv, Bws, yfb);

  // out = yf @ out_proj_w.T   (4096 x 2048, K=4096) [split-K x2 over dead zxbc region]
  if (fast) {
    float* outp = (float*)zxbc;
    gemm8p<false><<<dim3((DM / 256) * (MT / 256), 2), 512, 0, stream>>>(yfb, w1b, outp, MT, DM, DI, DI / 2);
    reduce_add2<<<dim3((MT * DM / 4 + 255) / 256), 256, 0, stream>>>((const float4*)outp, (float4*)out, MT * DM / 4);
  } else {
    gemm_nt<unsigned short, float, false><<<dim3(DM / 128, MT / 128), 256, 0, stream>>>(yfb, w_out, out, MT, DM, DI);
  }
}

// Round 11
// 557.707 us; speedup vs baseline: 4.1904x; 1.0154x over previous
//
#include <hip/hip_runtime.h>
#include <cstdint>
#include <cstddef>

// ---------------- problem constants ----------------
constexpr int B_  = 2;
constexpr int L_  = 2048;
constexpr int DM  = 2048;
constexpr int DI  = 4096;
constexpr int DXB = 1024;
constexpr int SN  = 16;     // state dim N
constexpr int DTR = 128;
constexpr int H_  = DI / SN;        // 256 heads
constexpr int NZ  = 2*DXB + 2*DI;   // 10240 (zxbc width)
constexpr int MT  = B_ * L_;        // 4096 rows
constexpr int CCH = 32;             // scan chunks
constexpr int TCH = L_ / CCH;       // 64 steps per chunk

constexpr float LOG2E = 1.4426950408889634f;
constexpr float LN2   = 0.6931471805599453f;

typedef __attribute__((ext_vector_type(4))) float f32x4;
typedef __attribute__((ext_vector_type(8))) short s16x8;

__device__ __forceinline__ unsigned short f2bf(float f) {
  union { float f; unsigned u; } v; v.f = f;
  unsigned r = v.u + 0x7fff + ((v.u >> 16) & 1);   // RNE
  return (unsigned short)(r >> 16);
}
__device__ __forceinline__ float bf2f(unsigned short u) {
  union { unsigned u; float f; } v; v.u = ((unsigned)u) << 16; return v.f;
}
__device__ __forceinline__ float fexp(float x)  { return __builtin_amdgcn_exp2f(x * LOG2E); }
__device__ __forceinline__ float fsilu(float x) { return x * __builtin_amdgcn_rcpf(1.f + fexp(-x)); }
__device__ __forceinline__ float fsoftplus(float x) {
  return (x > 20.f) ? x : __builtin_amdgcn_logf(1.f + fexp(x)) * LN2;
}

// ---------------- f32 -> bf16 cast ----------------
__global__ __launch_bounds__(256) void cast_kernel(const float4* __restrict__ in,
                                                   ushort4* __restrict__ out, int n4) {
  int stride = gridDim.x * blockDim.x;
  for (int i = blockIdx.x * blockDim.x + threadIdx.x; i < n4; i += stride) {
    float4 v = in[i];
    ushort4 o;
    o.x = f2bf(v.x); o.y = f2bf(v.y); o.z = f2bf(v.z); o.w = f2bf(v.w);
    out[i] = o;
  }
}

// ================= 256x128 GEMM, BK=32, 48KB LDS -> 2 blocks/CU =================
// Half-tile = 128 rows x 32 cols bf16 (8 KB), rows are 64 B.
// Swizzle: read byte x ^= ((x>>7)&3)<<4  (chunk bits 4-5 ^= row bits 1-2);
// stage source slot sp = s ^ ((s>>3)&3). Same involution both sides; 2-way
// residual lane aliasing only (free per m136). LDS dest stays linear.

__device__ __forceinline__ void stage_h32(const unsigned short* __restrict__ G,
                                          int row0, int K, int k0,
                                          unsigned short* lh, int wave, int lane) {
  const int s  = wave * 64 + lane;                       // 16B slot 0..511
  const int sp = s ^ ((s >> 3) & 3);                     // pre-swizzled source slot
  const unsigned short* g = G + (size_t)(row0 + (sp >> 2)) * K + k0 + (sp & 3) * 8;
  __builtin_amdgcn_global_load_lds((const __attribute__((address_space(1))) void*)g,
                                   (__attribute__((address_space(3))) void*)(lh + s * 8), 16, 0, 0);
}

// K = row stride of A/W; KL = K-length this block reduces (koff = blockIdx.y*KL).
// gridDim.y > 1 => f32 partials at ((float*)Cout) + z*M*N.
template<bool BF16OUT>
__global__ __launch_bounds__(512, 4) void gemm8p(const unsigned short* __restrict__ A,
                                                 const unsigned short* __restrict__ W,
                                                 void* __restrict__ Cout,
                                                 int M, int N, int K, int KL) {
  __shared__ unsigned short lds[2][3][4096];             // [buf][A0,A1,B] 8KB halves
  const int tid = threadIdx.x, lane = tid & 63, wave = tid >> 6;
  const int r16 = lane & 15, g = lane >> 4;

  const int ntx = N >> 7;
  const int nwg = gridDim.x;
  const int q8  = nwg >> 3;
  const int gid = ((nwg & 7) == 0) ? (int)(blockIdx.x & 7) * q8 + (int)(blockIdx.x >> 3)
                                   : (int)blockIdx.x;
  const int m0 = (gid / ntx) << 8, n0 = (gid % ntx) << 7;
  const int z  = blockIdx.y;
  const int koff = z * KL;

  // per-lane constant swizzled offsets (64B rows)
  const int o  = (g * 16) ^ (((r16 >> 1) & 3) << 4);
  const int arow = (((wave >> 1) & 1) * 64 + r16) * 64;  // byte offset within A-half
  const int brow = ((wave & 1) * 64 + r16) * 64;         // byte offset within B tile

  f32x4 acc[4][4] = {};
  const int NT = KL >> 5;

  // prologue: stage K-tile 0
  stage_h32(A, m0,       K, koff, &lds[0][0][0], wave, lane);
  stage_h32(A, m0 + 128, K, koff, &lds[0][1][0], wave, lane);
  stage_h32(W, n0,       K, koff, &lds[0][2][0], wave, lane);

  for (int kt = 0; kt < NT; ++kt) {
    const int p = kt & 1;
    const int k0n = koff + ((kt + 1) << 5);
    const bool more = (kt + 1 < NT);

    // stage next tile (3 loads), then counted wait: kt's 3 drain, kt+1's stay
    if (more) {
      stage_h32(A, m0,       K, k0n, &lds[p ^ 1][0][0], wave, lane);
      stage_h32(A, m0 + 128, K, k0n, &lds[p ^ 1][1][0], wave, lane);
      stage_h32(W, n0,       K, k0n, &lds[p ^ 1][2][0], wave, lane);
      asm volatile("s_waitcnt vmcnt(3)" ::: "memory");
    } else {
      asm volatile("s_waitcnt vmcnt(0)" ::: "memory");
    }
    asm volatile("s_barrier" ::: "memory");

    const char* Ahb = (const char*)&lds[p][wave >> 2][0] + arow + o;
    const char* Bhb = (const char*)&lds[p][2][0] + brow + o;
    s16x8 af[4], bf[4];
#pragma unroll
    for (int i = 0; i < 4; ++i) af[i] = *(const s16x8*)(Ahb + i * 1024);
#pragma unroll
    for (int j = 0; j < 4; ++j) bf[j] = *(const s16x8*)(Bhb + j * 1024);

    __builtin_amdgcn_s_setprio(1);
#pragma unroll
    for (int i = 0; i < 4; ++i)
#pragma unroll
      for (int j = 0; j < 4; ++j)
        acc[i][j] = __builtin_amdgcn_mfma_f32_16x16x32_bf16(af[i], bf[j], acc[i][j], 0, 0, 0);
    __builtin_amdgcn_s_setprio(0);
    __builtin_amdgcn_sched_barrier(0);
    asm volatile("s_barrier" ::: "memory");            // WAR: buf p free for kt+2 staging
  }

  if (gridDim.y > 1) {
    float* P = (float*)Cout + (size_t)z * M * N;
#pragma unroll
    for (int i = 0; i < 4; ++i)
#pragma unroll
      for (int j = 0; j < 4; ++j) {
        const int row0 = m0 + (wave >> 1) * 64 + i * 16 + g * 4;
        const int col  = n0 + (wave & 1) * 64 + j * 16 + r16;
#pragma unroll
        for (int e = 0; e < 4; ++e)
          P[(size_t)(row0 + e) * N + col] = acc[i][j][e];
      }
  } else {
#pragma unroll
    for (int i = 0; i < 4; ++i)
#pragma unroll
      for (int j = 0; j < 4; ++j) {
        const int row0 = m0 + (wave >> 1) * 64 + i * 16 + g * 4;
        const int col  = n0 + (wave & 1) * 64 + j * 16 + r16;
#pragma unroll
        for (int e = 0; e < 4; ++e) {
          float v = acc[i][j][e];
          if constexpr (BF16OUT) ((unsigned short*)Cout)[(size_t)(row0 + e) * N + col] = f2bf(v);
          else                   ((float*)Cout)[(size_t)(row0 + e) * N + col] = v;
        }
      }
  }
}

// ---------------- split-K 128x128 GEMM (dt1): f32 partials per K-chunk ----------------
__global__ __launch_bounds__(256) void gemm_g16_sk(const unsigned short* __restrict__ A,
                                                   const unsigned short* __restrict__ W,
                                                   float* __restrict__ Pout,
                                                   int M, int N, int K, int KC) {
  __shared__ alignas(16) unsigned short sA[128 * 32];
  __shared__ alignas(16) unsigned short sB[128 * 32];
  const int tid  = threadIdx.x;
  const int lane = tid & 63;
  const int wave = tid >> 6;
  const int m0 = blockIdx.y * 128, n0 = blockIdx.x * 128;
  const int z  = blockIdx.z;
  const int wr = wave >> 1, wc = wave & 1;
  const int r16 = lane & 15, g = lane >> 4;
  f32x4 acc[4][4] = {};

  for (int k0 = z * KC; k0 < z * KC + KC; k0 += 32) {
    __syncthreads();
#pragma unroll
    for (int it = 0; it < 2; ++it) {
      const int base = wave * 128 + it * 64;
      const int slot = base + lane;
      const int r = slot >> 2, c8 = slot & 3;
      const unsigned short* ga = A + (size_t)(m0 + r) * K + k0 + c8 * 8;
      const unsigned short* gb = W + (size_t)(n0 + r) * K + k0 + c8 * 8;
      __builtin_amdgcn_global_load_lds((const __attribute__((address_space(1))) void*)ga,
                                       (__attribute__((address_space(3))) void*)(sA + base * 8), 16, 0, 0);
      __builtin_amdgcn_global_load_lds((const __attribute__((address_space(1))) void*)gb,
                                       (__attribute__((address_space(3))) void*)(sB + base * 8), 16, 0, 0);
    }
    __syncthreads();

    s16x8 af[4], bfr[4];
#pragma unroll
    for (int f = 0; f < 4; ++f) {
      af[f]  = *(const s16x8*)&sA[(wr * 64 + f * 16 + r16) * 32 + g * 8];
      bfr[f] = *(const s16x8*)&sB[(wc * 64 + f * 16 + r16) * 32 + g * 8];
    }
#pragma unroll
    for (int i = 0; i < 4; ++i)
#pragma unroll
      for (int j = 0; j < 4; ++j)
        acc[i][j] = __builtin_amdgcn_mfma_f32_16x16x32_bf16(af[i], bfr[j], acc[i][j], 0, 0, 0);
  }

  float* P = Pout + (size_t)z * M * N;
#pragma unroll
  for (int i = 0; i < 4; ++i)
#pragma unroll
    for (int j = 0; j < 4; ++j) {
      const int row0 = m0 + wr * 64 + i * 16 + g * 4;
      const int col  = n0 + wc * 64 + j * 16 + r16;
#pragma unroll
      for (int e = 0; e < 4; ++e)
        P[(size_t)(row0 + e) * N + col] = acc[i][j][e];
    }
}

// ---- reduce 8 f32 partials -> bf16 ----
__global__ __launch_bounds__(256) void reduce_cast8(const float4* __restrict__ P,
                                                    ushort4* __restrict__ outb, int n4) {
  const int i = blockIdx.x * 256 + threadIdx.x;
  if (i >= n4) return;
  float4 s = P[i];
#pragma unroll
  for (int z = 1; z < 8; ++z) {
    const float4 v = P[i + (size_t)z * n4];
    s.x += v.x; s.y += v.y; s.z += v.z; s.w += v.w;
  }
  ushort4 o; o.x = f2bf(s.x); o.y = f2bf(s.y); o.z = f2bf(s.z); o.w = f2bf(s.w);
  outb[i] = o;
}

// ---- reduce 2 f32 partials -> f32 ----
__global__ __launch_bounds__(256) void reduce_add2(const float4* __restrict__ P,
                                                   float4* __restrict__ outf, int n4) {
  const int i = blockIdx.x * 256 + threadIdx.x;
  if (i >= n4) return;
  float4 a = P[i];
  const float4 b = P[i + (size_t)n4];
  a.x += b.x; a.y += b.y; a.z += b.z; a.w += b.w;
  outf[i] = a;
}

// ---------------- fallback GEMM (reg-staged, f32-or-bf16 inputs) ----------------
template<typename AT, typename WT, bool BF16OUT>
__global__ __launch_bounds__(256) void gemm_nt(const AT* __restrict__ A,
                                               const WT* __restrict__ W,
                                               void* __restrict__ Cout,
                                               int M, int N, int K) {
  __shared__ alignas(16) unsigned short sA[128 * 32];
  __shared__ alignas(16) unsigned short sB[128 * 32];
  const int tid  = threadIdx.x;
  const int lane = tid & 63;
  const int wave = tid >> 6;
  const int m0 = blockIdx.y * 128, n0 = blockIdx.x * 128;
  const int wr = wave >> 1, wc = wave & 1;
  const int r16 = lane & 15, g = lane >> 4;
  f32x4 acc[4][4] = {};

  for (int k0 = 0; k0 < K; k0 += 32) {
    __syncthreads();
    if constexpr (sizeof(AT) == 4) {
#pragma unroll
      for (int s = 0; s < 4; ++s) {
        const int slot = tid + s * 256;
        const int row = slot >> 3, c4 = slot & 7;
        const float4 v = *(const float4*)((const float*)A + (size_t)(m0 + row) * K + k0 + c4 * 4);
        ushort4 o; o.x = f2bf(v.x); o.y = f2bf(v.y); o.z = f2bf(v.z); o.w = f2bf(v.w);
        *(ushort4*)&sA[row * 32 + c4 * 4] = o;
      }
    } else {
#pragma unroll
      for (int s = 0; s < 2; ++s) {
        const int slot = tid + s * 256;
        const int row = slot >> 2, c8 = slot & 3;
        *(s16x8*)&sA[row * 32 + c8 * 8] =
            *(const s16x8*)((const unsigned short*)A + (size_t)(m0 + row) * K + k0 + c8 * 8);
      }
    }
    if constexpr (sizeof(WT) == 4) {
#pragma unroll
      for (int s = 0; s < 4; ++s) {
        const int slot = tid + s * 256;
        const int row = slot >> 3, c4 = slot & 7;
        const float4 v = *(const float4*)((const float*)W + (size_t)(n0 + row) * K + k0 + c4 * 4);
        ushort4 o; o.x = f2bf(v.x); o.y = f2bf(v.y); o.z = f2bf(v.z); o.w = f2bf(v.w);
        *(ushort4*)&sB[row * 32 + c4 * 4] = o;
      }
    } else {
#pragma unroll
      for (int s = 0; s < 2; ++s) {
        const int slot = tid + s * 256;
        const int row = slot >> 2, c8 = slot & 3;
        *(s16x8*)&sB[row * 32 + c8 * 8] =
            *(const s16x8*)((const unsigned short*)W + (size_t)(n0 + row) * K + k0 + c8 * 8);
      }
    }
    __syncthreads();

    s16x8 af[4], bfr[4];
#pragma unroll
    for (int f = 0; f < 4; ++f) {
      af[f]  = *(const s16x8*)&sA[(wr * 64 + f * 16 + r16) * 32 + g * 8];
      bfr[f] = *(const s16x8*)&sB[(wc * 64 + f * 16 + r16) * 32 + g * 8];
    }
#pragma unroll
    for (int i = 0; i < 4; ++i)
#pragma unroll
      for (int j = 0; j < 4; ++j)
        acc[i][j] = __builtin_amdgcn_mfma_f32_16x16x32_bf16(af[i], bfr[j], acc[i][j], 0, 0, 0);
  }

#pragma unroll
  for (int i = 0; i < 4; ++i)
#pragma unroll
    for (int j = 0; j < 4; ++j) {
      const int row0 = m0 + wr * 64 + i * 16 + g * 4;
      const int col  = n0 + wc * 64 + j * 16 + r16;
#pragma unroll
      for (int e = 0; e < 4; ++e) {
        float v = acc[i][j][e];
        if constexpr (BF16OUT) ((unsigned short*)Cout)[(size_t)(row0 + e) * N + col] = f2bf(v);
        else                   ((float*)Cout)[(size_t)(row0 + e) * N + col] = v;
      }
    }
}

// ================= chunked selective scan =================

__global__ __launch_bounds__(256) void scan_p1(const unsigned short* __restrict__ zxbc,
                                               const unsigned short* __restrict__ dtw,
                                               const float* __restrict__ dt_b,
                                               const float* __restrict__ conv_w,
                                               const float* __restrict__ conv_b,
                                               const float* __restrict__ A_log,
                                               float* __restrict__ Sws,
                                               float* __restrict__ Bws) {
  const int d = blockIdx.x * 256 + threadIdx.x;
  const int c = blockIdx.y;
  const int b = blockIdx.z;
  const int h = d >> 4, p = d & 15;

  const float bias = dt_b[d];
  const float cw0 = conv_w[d*4+0], cw1 = conv_w[d*4+1], cw2 = conv_w[d*4+2], cw3 = conv_w[d*4+3];
  const float cb  = conv_b[d];
  float nacK[16];
#pragma unroll
  for (int n = 0; n < 16; ++n) nacK[n] = -fexp(A_log[d * SN + n]) * LOG2E;

  const unsigned short* rp  = zxbc + (size_t)b * L_ * NZ;
  const unsigned short* pdt = dtw  + (size_t)b * L_ * DI + d;
  const int ox = DI + ((h >> 2) << 4) + p;
  const int oB = DI + DXB + ((h >> 2) << 4);
  const int t0 = c * TCH;

  float xm1 = (t0 >= 1) ? bf2f(rp[(size_t)(t0-1)*NZ + ox]) : 0.f;
  float xm2 = (t0 >= 2) ? bf2f(rp[(size_t)(t0-2)*NZ + ox]) : 0.f;
  float xm3 = (t0 >= 3) ? bf2f(rp[(size_t)(t0-3)*NZ + ox]) : 0.f;

  float S = 0.f;
  float Bacc[16] = {};

  for (int t = t0; t < t0 + TCH; ++t) {
    const size_t row = (size_t)t * NZ;
    const float xv = bf2f(rp[row + ox]);
    const s16x8 bv0 = *(const s16x8*)&rp[row + oB];
    const s16x8 bv1 = *(const s16x8*)&rp[row + oB + 8];
    const float dr = bf2f(pdt[(size_t)t * DI]);

    const float cs  = cb + cw0*xm3 + cw1*xm2 + cw2*xm1 + cw3*xv;
    const float xa  = fsilu(cs);
    const float dtv = fsoftplus(dr + bias);
    S += dtv;
    const float g = dtv * xa;
#pragma unroll
    for (int n = 0; n < 16; ++n) {
      const float Bn = bf2f((unsigned short)(n < 8 ? bv0[n] : bv1[n-8]));
      const float a  = __builtin_amdgcn_exp2f(dtv * nacK[n]);
      Bacc[n] = Bacc[n] * a + g * Bn;
    }
    xm3 = xm2; xm2 = xm1; xm1 = xv;
  }

  Sws[((size_t)b * CCH + c) * DI + d] = S;
  float* Bo = Bws + (((size_t)b * CCH + c) * DI + d) * 16;
#pragma unroll
  for (int q = 0; q < 4; ++q)
    *(float4*)&Bo[q*4] = make_float4(Bacc[q*4], Bacc[q*4+1], Bacc[q*4+2], Bacc[q*4+3]);
}

__global__ __launch_bounds__(256) void scan_comb(const float* __restrict__ Sws,
                                                 float* __restrict__ Bws,
                                                 const float* __restrict__ A_log) {
  const int idx = blockIdx.x * 256 + threadIdx.x;
  const int b = blockIdx.y;
  const int d = idx >> 4;
  const float nacK = -fexp(A_log[idx]) * LOG2E;
  float hcur = 0.f;
  for (int c = 0; c < CCH; ++c) {
    const size_t cell = ((size_t)b * CCH + c) * DI;
    const size_t bi = (cell + d) * 16 + (idx & 15);
    const float S  = Sws[cell + d];
    const float Ba = Bws[bi];
    Bws[bi] = hcur;
    hcur = hcur * __builtin_amdgcn_exp2f(S * nacK) + Ba;
  }
}

__global__ __launch_bounds__(256) void scan_p2(const unsigned short* __restrict__ zxbc,
                                               const unsigned short* __restrict__ dtw,
                                               const float* __restrict__ dt_b,
                                               const float* __restrict__ conv_w,
                                               const float* __restrict__ conv_b,
                                               const float* __restrict__ A_log,
                                               const float* __restrict__ Dv,
                                               const float* __restrict__ Hin,
                                               unsigned short* __restrict__ yf) {
  const int d = blockIdx.x * 256 + threadIdx.x;
  const int c = blockIdx.y;
  const int b = blockIdx.z;
  const int h = d >> 4, p = d & 15;

  const float bias = dt_b[d];
  const float Dd   = Dv[d];
  const float cw0 = conv_w[d*4+0], cw1 = conv_w[d*4+1], cw2 = conv_w[d*4+2], cw3 = conv_w[d*4+3];
  const float cb  = conv_b[d];
  float nacK[16];
#pragma unroll
  for (int n = 0; n < 16; ++n) nacK[n] = -fexp(A_log[d * SN + n]) * LOG2E;

  float hst[16];
  const float* Hi = Hin + (((size_t)b * CCH + c) * DI + d) * 16;
#pragma unroll
  for (int q = 0; q < 4; ++q) {
    const float4 v = *(const float4*)&Hi[q*4];
    hst[q*4] = v.x; hst[q*4+1] = v.y; hst[q*4+2] = v.z; hst[q*4+3] = v.w;
  }

  const unsigned short* rp  = zxbc + (size_t)b * L_ * NZ;
  const unsigned short* pdt = dtw  + (size_t)b * L_ * DI + d;
  unsigned short* py = yf + (size_t)b * L_ * DI + d;
  const int oz = d;
  const int ox = DI + ((h >> 2) << 4) + p;
  const int oB = DI + DXB + ((h >> 2) << 4);
  const int oC = DI + 2*DXB + (h << 4);
  const int t0 = c * TCH;

  float xm1 = (t0 >= 1) ? bf2f(rp[(size_t)(t0-1)*NZ + ox]) : 0.f;
  float xm2 = (t0 >= 2) ? bf2f(rp[(size_t)(t0-2)*NZ + ox]) : 0.f;
  float xm3 = (t0 >= 3) ? bf2f(rp[(size_t)(t0-3)*NZ + ox]) : 0.f;

  for (int t = t0; t < t0 + TCH; ++t) {
    const size_t row = (size_t)t * NZ;
    const float xv = bf2f(rp[row + ox]);
    const float zv = bf2f(rp[row + oz]);
    const s16x8 bv0 = *(const s16x8*)&rp[row + oB];
    const s16x8 bv1 = *(const s16x8*)&rp[row + oB + 8];
    const s16x8 cv0 = *(const s16x8*)&rp[row + oC];
    const s16x8 cv1 = *(const s16x8*)&rp[row + oC + 8];
    const float dr = bf2f(pdt[(size_t)t * DI]);

    const float cs  = cb + cw0*xm3 + cw1*xm2 + cw2*xm1 + cw3*xv;
    const float xa  = fsilu(cs);
    const float dtv = fsoftplus(dr + bias);
    const float g = dtv * xa;
    float y = 0.f;
#pragma unroll
    for (int n = 0; n < 16; ++n) {
      const float Bn = bf2f((unsigned short)(n < 8 ? bv0[n] : bv1[n-8]));
      const float Cn = bf2f((unsigned short)(n < 8 ? cv0[n] : cv1[n-8]));
      const float a  = __builtin_amdgcn_exp2f(dtv * nacK[n]);
      hst[n] = hst[n] * a + g * Bn;
      y += hst[n] * Cn;
    }
    py[(size_t)t * DI] = f2bf((y + Dd * xa) * fsilu(zv));
    xm3 = xm2; xm2 = xm1; xm1 = xv;
  }
}

// ---------------- launch ----------------
extern "C" void kernel_launch(void* const* d_in, const int* in_sizes, int n_in,
                              void* d_out, int out_size, void* d_ws, size_t ws_size,
                              hipStream_t stream) {
  const float* hs     = (const float*)d_in[0];
  const float* w_in   = (const float*)d_in[1];
  const float* w_dti  = (const float*)d_in[2];
  const float* w_dtp  = (const float*)d_in[3];
  const float* dt_b   = (const float*)d_in[4];
  const float* conv_w = (const float*)d_in[5];
  const float* conv_b = (const float*)d_in[6];
  const float* A_log  = (const float*)d_in[7];
  const float* Dv     = (const float*)d_in[8];
  const float* w_out  = (const float*)d_in[9];
  float* out = (float*)d_out;

  char* ws = (char*)d_ws;
  size_t off = 0;
  auto take = [&](size_t bytes) -> void* {
    void* p = ws + off;
    off += (bytes + 255) & ~(size_t)255;
    return p;
  };
  // ---- shared intermediates ----
  unsigned short* zxbc  = (unsigned short*)take((size_t)MT * NZ * 2);   // 84 MB; reused as out_proj f32 partials after scan
  unsigned short* t1b   = (unsigned short*)take((size_t)MT * DTR * 2);
  unsigned short* dtraw = (unsigned short*)take((size_t)MT * DI * 2);
  unsigned short* yfb   = (unsigned short*)take((size_t)MT * DI * 2);
  float*          Sws   = (float*)take((size_t)B_ * CCH * DI * 4);
  float*          Bws   = (float*)take((size_t)B_ * CCH * DI * 16 * 4);

  // ---- bf16 operand copies + split-K partials (fast path) ----
  unsigned short* hsb   = (unsigned short*)take((size_t)MT * DM * 2);
  unsigned short* w1b   = (unsigned short*)take((size_t)NZ * DM * 2);   // later reused for w_out bf16
  unsigned short* wdtib = (unsigned short*)take((size_t)DTR * DM * 2);
  unsigned short* wdtpb = (unsigned short*)take((size_t)DI * DTR * 2);
  float*          t1p   = (float*)take((size_t)8 * MT * DTR * 4);       // 16.8 MB partials
  const bool fast = (off <= ws_size);

  auto cast = [&](const float* src, unsigned short* dst, size_t n) {
    int n4 = (int)(n / 4);
    int blocks = (n4 + 255) / 256;
    if (blocks > 2048) blocks = 2048;
    cast_kernel<<<dim3(blocks), dim3(256), 0, stream>>>((const float4*)src, (ushort4*)dst, n4);
  };

  if (fast) {
    cast(hs,    hsb,   (size_t)MT * DM);
    cast(w_in,  w1b,   (size_t)NZ * DM);
    cast(w_dti, wdtib, (size_t)DTR * DM);
    cast(w_dtp, wdtpb, (size_t)DI * DTR);
    // zxbc = hs @ in_proj_w.T   (4096 x 10240, K=2048) [256x128 tiles, 1280 blk, 2/CU]
    gemm8p<true><<<dim3((MT / 256) * (NZ / 128), 1), 512, 0, stream>>>(hsb, w1b, zxbc, MT, NZ, DM, DM);
    // t1 = hs @ dt_in_proj_w.T  (4096 x 128, K=2048) [split-K x8 -> f32 partials -> bf16]
    gemm_g16_sk<<<dim3(DTR / 128, MT / 128, 8), 256, 0, stream>>>(hsb, wdtib, t1p, MT, DTR, DM, DM / 8);
    reduce_cast8<<<dim3((MT * DTR / 4 + 255) / 256), 256, 0, stream>>>((const float4*)t1p, (ushort4*)t1b, MT * DTR / 4);
    // dtraw = t1 @ dt_proj_w.T  (4096 x 4096, K=128) [512 blk = 1 round at 2/CU]
    gemm8p<true><<<dim3((MT / 256) * (DI / 128), 1), 512, 0, stream>>>(t1b, wdtpb, dtraw, MT, DI, DTR, DTR);
    // w1b dead now: cast w_out into its region
    cast(w_out, w1b, (size_t)DM * DI);
  } else {
    gemm_nt<float, float, true><<<dim3(NZ / 128, MT / 128), 256, 0, stream>>>(hs, w_in, zxbc, MT, NZ, DM);
    gemm_nt<float, float, true><<<dim3(DTR / 128, MT / 128), 256, 0, stream>>>(hs, w_dti, t1b, MT, DTR, DM);
    gemm_nt<unsigned short, float, true><<<dim3(DI / 128, MT / 128), 256, 0, stream>>>(t1b, w_dtp, dtraw, MT, DI, DTR);
  }

  // chunked selective scan (conv fused, recomputed in both passes)
  scan_p1  <<<dim3(DI/256, CCH, B_), 256, 0, stream>>>(zxbc, dtraw, dt_b, conv_w, conv_b, A_log, Sws, Bws);
  scan_comb<<<dim3(DI*SN/256, B_),  256, 0, stream>>>(Sws, Bws, A_log);
  scan_p2  <<<dim3(DI/256, CCH, B_), 256, 0, stream>>>(zxbc, dtraw, dt_b, conv_w, conv_b, A_log, Dv, Bws, yfb);

  // out = yf @ out_proj_w.T   (4096 x 2048, K=4096) [split-K x2, 512 blk = 1 round]
  if (fast) {
    float* outp = (float*)zxbc;
    gemm8p<false><<<dim3((MT / 256) * (DM / 128), 2), 512, 0, stream>>>(yfb, w1b, outp, MT, DM, DI, DI / 2);
    reduce_add2<<<dim3((MT * DM / 4 + 255) / 256), 256, 0, stream>>>((const float4*)outp, (float4*)out, MT * DM / 4);
  } else {
    gemm_nt<unsigned short, float, false><<<dim3(DM / 128, MT / 128), 256, 0, stream>>>(yfb, w_out, out, MT, DM, DI);
  }
}